// Round 1
// baseline (422.887 us; speedup 1.0000x reference)
//
#include <hip/hip_runtime.h>
#include <cstdint>
#include <cstddef>

// ---------------------------------------------------------------------------
// CausalSelfAttention: y = proj(softmax_causal(QK^T/sqrt(HD)) V), QKV = x@W_attn+b
// B=2 T=2048 C=2048 H=16 HD=128. All I/O fp32; internal compute bf16 MFMA.
// ---------------------------------------------------------------------------

typedef __bf16 bf16x8 __attribute__((ext_vector_type(8)));
typedef float  f32x4  __attribute__((ext_vector_type(4)));
typedef unsigned short u16x4 __attribute__((ext_vector_type(4)));
typedef unsigned short u16x8 __attribute__((ext_vector_type(8)));

__device__ __forceinline__ unsigned short f2bf(float f) {
  unsigned int u = __builtin_bit_cast(unsigned int, f);
  u += 0x7fffu + ((u >> 16) & 1u);       // round-to-nearest-even
  return (unsigned short)(u >> 16);
}

__device__ __forceinline__ void gld16(void* lds, const void* g) {
  // async global->LDS, 16B per lane; LDS dest is wave-uniform base + lane*16
  __builtin_amdgcn_global_load_lds(
      (const __attribute__((address_space(1))) void*)g,
      (__attribute__((address_space(3))) void*)lds, 16, 0, 0);
}

// ---------------------------------------------------------------------------
// fp32 -> bf16 elementwise (x conversion)
// ---------------------------------------------------------------------------
__global__ void cvt_f32_bf16_k(const float* __restrict__ in,
                               unsigned short* __restrict__ out, int n4) {
  int i = blockIdx.x * blockDim.x + threadIdx.x;
  int stride = gridDim.x * blockDim.x;
  for (; i < n4; i += stride) {
    float4 v = ((const float4*)in)[i];
    ushort4 o;
    o.x = f2bf(v.x); o.y = f2bf(v.y); o.z = f2bf(v.z); o.w = f2bf(v.w);
    ((ushort4*)out)[i] = o;
  }
}

// ---------------------------------------------------------------------------
// fp32 (R,C) -> bf16 transposed (C,R). 64x64 tile, float4 reads, 16B writes.
// ---------------------------------------------------------------------------
__global__ __launch_bounds__(256) void transpose_f32_bf16(
    const float* __restrict__ in, unsigned short* __restrict__ out,
    int R, int C) {
  __shared__ float tile[64][65];
  int c0 = blockIdx.x * 64, r0 = blockIdx.y * 64;
  int t = threadIdx.x;
  int lr = t >> 4, lc = (t & 15) * 4;
#pragma unroll
  for (int i = 0; i < 4; i++) {
    int row = lr + i * 16;
    float4 v = *(const float4*)&in[(size_t)(r0 + row) * C + c0 + lc];
    tile[row][lc] = v.x; tile[row][lc + 1] = v.y;
    tile[row][lc + 2] = v.z; tile[row][lc + 3] = v.w;
  }
  __syncthreads();
  int wr = t >> 3, wc = (t & 7) * 8;
#pragma unroll
  for (int i = 0; i < 2; i++) {
    int crow = wr + i * 32;
    u16x8 o;
#pragma unroll
    for (int j = 0; j < 8; j++) o[j] = f2bf(tile[wc + j][crow]);
    *(u16x8*)&out[(size_t)(c0 + crow) * R + r0 + wc] = o;
  }
}

// ---------------------------------------------------------------------------
// extract V^T (B,H,HD,T) bf16 from qkv (B*T, 3C) bf16. 64t x 64d tile.
// ---------------------------------------------------------------------------
__global__ __launch_bounds__(256) void extract_vT_k(
    const unsigned short* __restrict__ qkv, unsigned short* __restrict__ vT) {
  __shared__ unsigned int tile32[64][33];   // [d][t&31] packs (t, t+32)
  int bh = blockIdx.z, b = bh >> 4, h = bh & 15;
  int t0 = blockIdx.x * 64, d0 = blockIdx.y * 64;
  int t = threadIdx.x;
  int lr = t >> 3, lc = (t & 7) * 8;
  const unsigned short* src = qkv + (size_t)(b * 2048) * 6144 + 4096 + h * 128;
#pragma unroll
  for (int i = 0; i < 2; i++) {
    int row = lr + i * 32;
    u16x8 v = *(const u16x8*)&src[(size_t)(t0 + row) * 6144 + d0 + lc];
#pragma unroll
    for (int j = 0; j < 8; j++) {
      unsigned short* p = (unsigned short*)&tile32[lc + j][row & 31];
      p[row >> 5] = v[j];
    }
  }
  __syncthreads();
  int dr = t >> 2, tc = (t & 3) * 8;
  u16x8 lo, hi;
#pragma unroll
  for (int j = 0; j < 8; j++) {
    unsigned int u = tile32[dr][tc + j];
    lo[j] = (unsigned short)(u & 0xffffu);
    hi[j] = (unsigned short)(u >> 16);
  }
  unsigned short* dst = vT + (size_t)bh * 128 * 2048 + (size_t)(d0 + dr) * 2048 + t0;
  *(u16x8*)&dst[tc] = lo;
  *(u16x8*)&dst[tc + 32] = hi;
}

// ---------------------------------------------------------------------------
// GEMM (legacy 128x128, BK=64, 4 waves): kept for the proj GEMM, where the
// 256^2 grid would be only 128 WGs (half the chip).
// ---------------------------------------------------------------------------
template <int OUT_BF16>
__global__ __launch_bounds__(256) void gemm_bt(
    const unsigned short* __restrict__ A, const unsigned short* __restrict__ BT,
    const float* __restrict__ bias, void* __restrict__ Cout,
    int M, int N, int K) {
  __shared__ __align__(16) unsigned short sA[128 * 64];
  __shared__ __align__(16) unsigned short sB[128 * 64];

  const int tid = threadIdx.x, w = tid >> 6, lane = tid & 63;
  const int quad = lane >> 4, l16 = lane & 15;
  const int m0 = blockIdx.y * 128, n0 = blockIdx.x * 128;
  const int wr = w >> 1, wc = w & 1;

  const unsigned short* gA[4];
  const unsigned short* gB[4];
  unsigned short* lA[4];
  unsigned short* lB[4];
#pragma unroll
  for (int i = 0; i < 4; i++) {
    int c = w * 256 + i * 64 + lane;
    int row = c >> 3, scol = (c & 7) ^ (row & 7);
    gA[i] = A + (size_t)(m0 + row) * K + scol * 8;
    gB[i] = BT + (size_t)(n0 + row) * K + scol * 8;
    lA[i] = sA + (size_t)(w * 256 + i * 64) * 8;
    lB[i] = sB + (size_t)(w * 256 + i * 64) * 8;
  }

  f32x4 acc[4][4] = {};

  for (int k0 = 0; k0 < K; k0 += 64) {
#pragma unroll
    for (int i = 0; i < 4; i++) {
      gld16(lA[i], gA[i]); gld16(lB[i], gB[i]);
      gA[i] += 64; gB[i] += 64;
    }
    __syncthreads();

#pragma unroll
    for (int kk = 0; kk < 2; kk++) {
      const int cc = (kk * 4 + quad) ^ (l16 & 7);
      bf16x8 af[4], bfr[4];
#pragma unroll
      for (int mi = 0; mi < 4; mi++)
        af[mi] = *(const bf16x8*)&sA[(wr * 64 + mi * 16 + l16) * 64 + cc * 8];
#pragma unroll
      for (int ni = 0; ni < 4; ni++)
        bfr[ni] = *(const bf16x8*)&sB[(wc * 64 + ni * 16 + l16) * 64 + cc * 8];
#pragma unroll
      for (int mi = 0; mi < 4; mi++)
#pragma unroll
        for (int ni = 0; ni < 4; ni++)
          acc[mi][ni] = __builtin_amdgcn_mfma_f32_16x16x32_bf16(
              af[mi], bfr[ni], acc[mi][ni], 0, 0, 0);
    }
    __syncthreads();
  }

#pragma unroll
  for (int mi = 0; mi < 4; mi++) {
    int row = m0 + wr * 64 + mi * 16 + quad * 4;
#pragma unroll
    for (int ni = 0; ni < 4; ni++) {
      int col = n0 + wc * 64 + ni * 16 + l16;
      float bv = bias[col];
#pragma unroll
      for (int r = 0; r < 4; r++) {
        float v = acc[mi][ni][r] + bv;
        if (OUT_BF16)
          ((unsigned short*)Cout)[(size_t)(row + r) * N + col] = f2bf(v);
        else
          ((float*)Cout)[(size_t)(row + r) * N + col] = v;
      }
    }
  }
}

// ---------------------------------------------------------------------------
// GEMM 256x256 8-phase (m201 template, plain HIP). BK=64, 8 waves (2Mx4N),
// 512 threads, 128 KiB LDS (2 dbuf x (A 256x64 + B 256x64) bf16).
// Per iteration: 2 K-tiles; 8 phases each {ds_read subtile | stage 1 half-tile
// (global_load_lds w16, chunk-XOR swizzled) | barrier | lgkmcnt(0) |
// setprio(1) 16xMFMA setprio(0) | barrier}. Counted vmcnt(2) at phases 3/7
// (never 0 in steady state; drain vmcnt(0) only last iteration).
//
// Stage schedule (tile t0=2i->buf0 computed ph0-3, t1=2i+1->buf1 ph4-7):
//   ph0: Bhi(t1)  ph1: Alo(t1)  ph2: Ahi(t1)            [tail of t1 staging]
//   ph3: Blo(t0+2) ph4: Bhi(t0+2) ph5: Alo(t0+2) ph6: Ahi(t0+2)
//   ph7: Blo(t1+2)
// WAR safety: each region's last ds_read completes >=1 end-barrier before its
// replacement load issues (B of buf0 last read ph2 -> staged ph3+; A-lo/hi of
// buf0 last read ph3 -> staged ph5/6; buf1 symmetric). RAW safety: vmcnt(2) at
// ph3 leaves only ph3's own stage (buf0, first read next-iter ph0 after ph7's
// vmcnt) in flight; ph7 symmetric.
// ---------------------------------------------------------------------------
#define BARRIER8 __builtin_amdgcn_s_barrier()
#define WAIT_LGKM0 asm volatile("s_waitcnt lgkmcnt(0)" ::: "memory")
#define WAIT_VM2 asm volatile("s_waitcnt vmcnt(2)" ::: "memory")
#define WAIT_VM0 asm volatile("s_waitcnt vmcnt(0)" ::: "memory")

#define STAGE_A(buf, h, t)                                                   \
  do {                                                                       \
    gld16(&sA[buf][((h) * 1024 + w * 64) * 8],                               \
          gA0 + (size_t)(h) * 128 * K + (size_t)(t) * 64);                   \
    gld16(&sA[buf][((h) * 1024 + 512 + w * 64) * 8],                         \
          gA1 + (size_t)(h) * 128 * K + (size_t)(t) * 64);                   \
  } while (0)

#define STAGE_B(buf, h, t)                                                   \
  do {                                                                       \
    gld16(&sB[buf][((h) * 1024 + w * 64) * 8],                               \
          gB0 + (size_t)(h) * 128 * K + (size_t)(t) * 64);                   \
    gld16(&sB[buf][((h) * 1024 + 512 + w * 64) * 8],                         \
          gB1 + (size_t)(h) * 128 * K + (size_t)(t) * 64);                   \
  } while (0)

#define LDA4(buf, mh, kk)                                                    \
  do {                                                                       \
    const int cc_ = ((kk) * 4 + quad) ^ (l16 & 7);                           \
    _Pragma("unroll") for (int i_ = 0; i_ < 4; ++i_) {                       \
      const int rr_ = wr * 128 + (mh) * 64 + i_ * 16 + l16;                  \
      a_[i_] = *(const bf16x8*)&sA[buf][rr_ * 64 + cc_ * 8];                 \
    }                                                                        \
  } while (0)

#define LDB4(buf, kk)                                                        \
  do {                                                                       \
    const int cc_ = ((kk) * 4 + quad) ^ (l16 & 7);                           \
    _Pragma("unroll") for (int i_ = 0; i_ < 4; ++i_) {                       \
      const int rr_ = wc * 64 + i_ * 16 + l16;                               \
      b_[i_] = *(const bf16x8*)&sB[buf][rr_ * 64 + cc_ * 8];                 \
    }                                                                        \
  } while (0)

#define MM16(mh)                                                             \
  do {                                                                       \
    __builtin_amdgcn_s_setprio(1);                                           \
    _Pragma("unroll") for (int i_ = 0; i_ < 4; ++i_)                         \
    _Pragma("unroll") for (int n_ = 0; n_ < 4; ++n_)                         \
        acc[(mh) * 4 + i_][n_] = __builtin_amdgcn_mfma_f32_16x16x32_bf16(    \
            a_[i_], b_[n_], acc[(mh) * 4 + i_][n_], 0, 0, 0);                \
    __builtin_amdgcn_s_setprio(0);                                           \
  } while (0)

template <int OUT_BF16>
__global__ __launch_bounds__(512, 2) void gemm_bt8(
    const unsigned short* __restrict__ A, const unsigned short* __restrict__ BT,
    const float* __restrict__ bias, void* __restrict__ Cout,
    int M, int N, int K) {
  __shared__ __align__(16) unsigned short sA[2][256 * 64];
  __shared__ __align__(16) unsigned short sB[2][256 * 64];
  (void)M;

  const int tid = threadIdx.x, w = tid >> 6, lane = tid & 63;
  const int quad = lane >> 4, l16 = lane & 15;
  const int wr = w >> 2, wc = w & 3;   // wave -> (2M x 4N) grid; C sub = 128x64

  // bijective XCD-aware block swizzle (m204 variant)
  const int nwgx = gridDim.x;
  const int nwg = nwgx * gridDim.y;
  const int wg = blockIdx.y * nwgx + blockIdx.x;
  const int q8 = nwg >> 3, r8 = nwg & 7;
  const int xcd = wg & 7, loc = wg >> 3;
  const int swz =
      (xcd < r8 ? xcd * (q8 + 1) : r8 * (q8 + 1) + (xcd - r8) * q8) + loc;
  const int m0 = (swz / nwgx) * 256;
  const int n0 = (swz % nwgx) * 256;

  // staging: half-tile = 128 rows x 64 cols bf16 = 1024 16B chunks;
  // thread owns chunks tid and tid+512. Slot s holds global chunk
  // (row=s>>3, col=(s&7)^(row&7)) -> pre-swizzled global source, linear LDS.
  const int c0 = tid, c1 = tid + 512;
  const int r0c = c0 >> 3, s0c = (c0 & 7) ^ (r0c & 7);
  const int r1c = c1 >> 3, s1c = (c1 & 7) ^ (r1c & 7);
  const unsigned short* gA0 = A + (size_t)(m0 + r0c) * K + s0c * 8;
  const unsigned short* gA1 = A + (size_t)(m0 + r1c) * K + s1c * 8;
  const unsigned short* gB0 = BT + (size_t)(n0 + r0c) * K + s0c * 8;
  const unsigned short* gB1 = BT + (size_t)(n0 + r1c) * K + s1c * 8;

  f32x4 acc[8][4] = {};
  bf16x8 a_[4], b_[4];

  const int NT = K >> 6;   // K-tiles (BK=64); must be even
  const int NI = NT >> 1;  // iterations (2 tiles each)

  // prologue: tile0 -> buf0 complete, tile1 B-lo -> buf1; confirm tile0.
  STAGE_B(0, 0, 0); STAGE_B(0, 1, 0);
  STAGE_A(0, 0, 0); STAGE_A(0, 1, 0);
  STAGE_B(1, 0, 1);
  WAIT_VM2;
  BARRIER8;

  for (int i = 0; i < NI; ++i) {
    const int t1 = 2 * i + 1;
    const int tn0 = 2 * i + 2, tn1 = 2 * i + 3;
    const bool last = (i == NI - 1);

    // ph0: buf0 (mh0,kk0) | stage t1 B-hi
    LDB4(0, 0); LDA4(0, 0, 0);
    STAGE_B(1, 1, t1);
    BARRIER8; WAIT_LGKM0; MM16(0); BARRIER8;

    // ph1: buf0 (mh1,kk0) | stage t1 A-lo
    LDA4(0, 1, 0);
    STAGE_A(1, 0, t1);
    BARRIER8; WAIT_LGKM0; MM16(1); BARRIER8;

    // ph2: buf0 (mh0,kk1) | stage t1 A-hi
    LDB4(0, 1); LDA4(0, 0, 1);
    STAGE_A(1, 1, t1);
    BARRIER8; WAIT_LGKM0; MM16(0); BARRIER8;

    // ph3: buf0 (mh1,kk1) | stage tn0 B-lo | confirm buf1(t1)
    LDA4(0, 1, 1);
    if (!last) STAGE_B(0, 0, tn0);
    if (last) { WAIT_VM0; } else { WAIT_VM2; }
    BARRIER8; WAIT_LGKM0; MM16(1); BARRIER8;

    // ph4: buf1 (mh0,kk0) | stage tn0 B-hi
    LDB4(1, 0); LDA4(1, 0, 0);
    if (!last) STAGE_B(0, 1, tn0);
    BARRIER8; WAIT_LGKM0; MM16(0); BARRIER8;

    // ph5: buf1 (mh1,kk0) | stage tn0 A-lo
    LDA4(1, 1, 0);
    if (!last) STAGE_A(0, 0, tn0);
    BARRIER8; WAIT_LGKM0; MM16(1); BARRIER8;

    // ph6: buf1 (mh0,kk1) | stage tn0 A-hi
    LDB4(1, 1); LDA4(1, 0, 1);
    if (!last) STAGE_A(0, 1, tn0);
    BARRIER8; WAIT_LGKM0; MM16(0); BARRIER8;

    // ph7: buf1 (mh1,kk1) | stage tn1 B-lo | confirm buf0(tn0)
    LDA4(1, 1, 1);
    if (!last) STAGE_B(1, 0, tn1);
    if (!last) { WAIT_VM2; }
    BARRIER8; WAIT_LGKM0; MM16(1); BARRIER8;
  }

  // epilogue: C/D layout row = quad*4+reg, col = l16
#pragma unroll
  for (int mi = 0; mi < 8; ++mi) {
    int row = m0 + wr * 128 + mi * 16 + quad * 4;
#pragma unroll
    for (int ni = 0; ni < 4; ++ni) {
      int col = n0 + wc * 64 + ni * 16 + l16;
      float bv = bias[col];
#pragma unroll
      for (int rr = 0; rr < 4; ++rr) {
        float v = acc[mi][ni][rr] + bv;
        if (OUT_BF16)
          ((unsigned short*)Cout)[(size_t)(row + rr) * N + col] = f2bf(v);
        else
          ((float*)Cout)[(size_t)(row + rr) * N + col] = v;
      }
    }
  }
}

#undef STAGE_A
#undef STAGE_B
#undef LDA4
#undef LDB4
#undef MM16

// ---------------------------------------------------------------------------
// Flash attention (causal), S^T formulation. (unchanged)
// ---------------------------------------------------------------------------
__global__ __launch_bounds__(256) void flash_attn(
    const unsigned short* __restrict__ qkv, const unsigned short* __restrict__ vT,
    unsigned short* __restrict__ yout) {
  __shared__ __align__(16) unsigned short sK[2][64 * 128];    // [t_k][d], swizzle &15
  __shared__ __align__(16) unsigned short sVT[2][128 * 64];   // [d][t_k], swizzle &7
  __shared__ __align__(16) unsigned short sP[4 * 16 * 64];    // per-wave P[q][k], chunk swizzle &7

  const int tid = threadIdx.x, w = tid >> 6, lane = tid & 63;
  const int quad = lane >> 4, l16 = lane & 15;
  const int id = blockIdx.x;
  const int g = id & 31;           // (b,h) group -> XCD g%8
  const int qp = id >> 5;          // 0..15
  const int b = g >> 4, h = g & 15;
  const int T = 2048, CC = 6144, HD = 128;
  const float qscale = 0.12753257252f;  // (1/sqrt(128)) * log2(e)

  const unsigned short* gK = qkv + (size_t)(b * T) * CC + 2048 + h * HD;
  const unsigned short* gV = vT + (size_t)(b * 16 + h) * HD * T;
  unsigned short* pw = sP + w * 16 * 64;

  const unsigned short* kSrc[4];
  const unsigned short* vSrc[4];
  unsigned short* kDst[4];
  unsigned short* vDst[4];
#pragma unroll
  for (int i = 0; i < 4; i++) {
    int c = w * 256 + i * 64 + lane;
    int kR = c >> 4, kC = (c & 15) ^ (kR & 15);
    int vR = c >> 3, vC = (c & 7) ^ (vR & 7);
    kSrc[i] = gK + (size_t)kR * CC + kC * 8;
    vSrc[i] = gV + (size_t)vR * T + vC * 8;
    kDst[i] = (unsigned short*)sK + (size_t)(w * 256 + i * 64) * 8;
    vDst[i] = (unsigned short*)sVT + (size_t)(w * 256 + i * 64) * 8;
  }
  const int KBUF = 64 * 128, VBUF = 128 * 64;

  const int qtA = qp, qtB = 31 - qp;
  int qt = qtA, kt = 0;

  bf16x8 qf[4];
  float m_old, l_sum;
  f32x4 o[8] = {};
  {
    const size_t qrow = (size_t)(b * T + qt * 64 + w * 16 + l16) * CC + h * HD;
#pragma unroll
    for (int kb = 0; kb < 4; kb++) {
      bf16x8 raw = *(const bf16x8*)&qkv[qrow + kb * 32 + quad * 8];
      bf16x8 sc;
#pragma unroll
      for (int j = 0; j < 8; j++) sc[j] = (__bf16)((float)raw[j] * qscale);
      qf[kb] = sc;
    }
  }
  m_old = -1e30f; l_sum = 0.f;

#pragma unroll
  for (int i = 0; i < 4; i++) {
    gld16(kDst[i], kSrc[i]);
    gld16(vDst[i], vSrc[i]);
  }

  const int total = qtA + qtB + 2;   // = 33
  for (int it = 0; it < total; ++it) {
    __syncthreads();
    const int cur = it & 1;
    const bool segEnd = (kt == qt);

    if (it + 1 < total) {
      const int nkt = segEnd ? 0 : kt + 1;
      const int nb_ = (it + 1) & 1;
      const size_t kOff = (size_t)nkt * 64 * CC;
      const int vOff = nkt * 64;
#pragma unroll
      for (int i = 0; i < 4; i++) {
        gld16(kDst[i] + (size_t)nb_ * KBUF, kSrc[i] + kOff);
        gld16(vDst[i] + (size_t)nb_ * VBUF, vSrc[i] + vOff);
      }
    }

    const unsigned short* sKc = (const unsigned short*)sK + (size_t)cur * KBUF;
    const unsigned short* sVc = (const unsigned short*)sVT + (size_t)cur * VBUF;

    f32x4 s4[4] = {};
#pragma unroll
    for (int dc = 0; dc < 4; dc++) {
#pragma unroll
      for (int kb = 0; kb < 4; kb++) {
        int rr = kb * 16 + l16;
        int cc = (dc * 4 + quad) ^ l16;
        bf16x8 kf = *(const bf16x8*)&sKc[rr * 128 + cc * 8];
        s4[kb] = __builtin_amdgcn_mfma_f32_16x16x32_bf16(kf, qf[dc], s4[kb], 0, 0, 0);
      }
    }

    float sv[4][4];
#pragma unroll
    for (int kb = 0; kb < 4; kb++)
#pragma unroll
      for (int r = 0; r < 4; r++) {
        float v = s4[kb][r];
        if (segEnd) {
          if (kb * 16 + quad * 4 + r > w * 16 + l16) v = -1e30f;
        }
        sv[kb][r] = v;
      }

    float mx = sv[0][0];
#pragma unroll
    for (int kb = 0; kb < 4; kb++)
#pragma unroll
      for (int r = 0; r < 4; r++) mx = fmaxf(mx, sv[kb][r]);
    mx = fmaxf(mx, __shfl_xor(mx, 16));
    mx = fmaxf(mx, __shfl_xor(mx, 32));
    float m_new = fmaxf(m_old, mx);
    float a = exp2f(m_old - m_new);
    float ssum = 0.f;
#pragma unroll
    for (int kb = 0; kb < 4; kb++)
#pragma unroll
      for (int r = 0; r < 4; r++) {
        float p = exp2f(sv[kb][r] - m_new);
        sv[kb][r] = p;
        ssum += p;
      }
    ssum += __shfl_xor(ssum, 16);
    ssum += __shfl_xor(ssum, 32);
    l_sum = l_sum * a + ssum;
    m_old = m_new;

    float ar[4];
#pragma unroll
    for (int r = 0; r < 4; r++)
      ar[r] = __shfl(a, (lane & 48) + quad * 4 + r);
#pragma unroll
    for (int nb = 0; nb < 8; nb++)
#pragma unroll
      for (int r = 0; r < 4; r++) o[nb][r] *= ar[r];

#pragma unroll
    for (int kb = 0; kb < 4; kb++) {
      u16x4 pk;
#pragma unroll
      for (int r = 0; r < 4; r++) pk[r] = f2bf(sv[kb][r]);
      int c = kb * 2 + (quad >> 1);
      int cp = c ^ (l16 & 7);
      *(u16x4*)&pw[l16 * 64 + cp * 8 + (quad & 1) * 4] = pk;
    }

#pragma unroll
    for (int kb2 = 0; kb2 < 2; kb2++) {
      int pcc = (kb2 * 4 + quad) ^ (l16 & 7);
      bf16x8 pf = *(const bf16x8*)&pw[l16 * 64 + pcc * 8];
#pragma unroll
      for (int nb = 0; nb < 8; nb++) {
        int rr = nb * 16 + l16;
        int cc = (kb2 * 4 + quad) ^ (rr & 7);
        bf16x8 vf = *(const bf16x8*)&sVc[rr * 64 + cc * 8];
        o[nb] = __builtin_amdgcn_mfma_f32_16x16x32_bf16(pf, vf, o[nb], 0, 0, 0);
      }
    }

    if (segEnd) {
      float linv = 1.0f / l_sum;
#pragma unroll
      for (int r = 0; r < 4; r++) {
        float ir = __shfl(linv, (lane & 48) + quad * 4 + r);
        size_t orow = (size_t)(b * T + qt * 64 + w * 16 + quad * 4 + r) * 2048 + h * HD;
#pragma unroll
        for (int nb = 0; nb < 8; nb++)
          yout[orow + nb * 16 + l16] = f2bf(o[nb][r] * ir);
      }
      if (it + 1 < total) {
        qt = qtB;
        const size_t qrow = (size_t)(b * T + qt * 64 + w * 16 + l16) * CC + h * HD;
#pragma unroll
        for (int kb = 0; kb < 4; kb++) {
          bf16x8 raw = *(const bf16x8*)&qkv[qrow + kb * 32 + quad * 8];
          bf16x8 sc;
#pragma unroll
          for (int j = 0; j < 8; j++) sc[j] = (__bf16)((float)raw[j] * qscale);
          qf[kb] = sc;
        }
        m_old = -1e30f; l_sum = 0.f;
#pragma unroll
        for (int nb = 0; nb < 8; nb++) o[nb] = (f32x4){0.f, 0.f, 0.f, 0.f};
      }
      kt = 0;
    } else {
      kt++;
    }
  }
}

// ---------------------------------------------------------------------------
extern "C" void kernel_launch(void* const* d_in, const int* in_sizes, int n_in,
                              void* d_out, int out_size, void* d_ws, size_t ws_size,
                              hipStream_t stream) {
  const float* x      = (const float*)d_in[0];   // (2,2048,2048)
  const float* W_attn = (const float*)d_in[1];   // (2048,6144)
  const float* b_attn = (const float*)d_in[2];   // (6144,)
  const float* W_proj = (const float*)d_in[3];   // (2048,2048)
  const float* b_proj = (const float*)d_in[4];   // (2048,)
  float* out = (float*)d_out;                    // (2,2048,2048) fp32

  char* ws = (char*)d_ws;
  unsigned short* x_bf  = (unsigned short*)(ws);              // 16 MiB
  unsigned short* WaT   = (unsigned short*)(ws + 16777216);   // 24 MiB
  unsigned short* WpT   = (unsigned short*)(ws + 41943040);   // 8 MiB
  unsigned short* qkv   = (unsigned short*)(ws + 50331648);   // 48 MiB
  unsigned short* vT    = (unsigned short*)(ws + 100663296);  // 16 MiB
  unsigned short* y_att = (unsigned short*)(ws + 117440512);  // 16 MiB
  // total 128 MiB

  cvt_f32_bf16_k<<<1024, 256, 0, stream>>>(x, x_bf, 8388608 / 4);
  transpose_f32_bf16<<<dim3(96, 32), 256, 0, stream>>>(W_attn, WaT, 2048, 6144);
  transpose_f32_bf16<<<dim3(32, 32), 256, 0, stream>>>(W_proj, WpT, 2048, 2048);
  // QKV GEMM: 256^2 8-phase template, grid 24x16 = 384 WGs (%8==0)
  gemm_bt8<1><<<dim3(24, 16), 512, 0, stream>>>(x_bf, WaT, b_attn, qkv, 4096, 6144, 2048);
  extract_vT_k<<<dim3(32, 2, 32), 256, 0, stream>>>(qkv, vT);
  flash_attn<<<dim3(512), 256, 0, stream>>>(qkv, vT, y_att);
  gemm_bt<0><<<dim3(16, 32), 256, 0, stream>>>(y_att, WpT, b_proj, out, 4096, 2048, 2048);
}

// Round 2
// 402.154 us; speedup vs baseline: 1.0516x; 1.0516x over previous
//
#include <hip/hip_runtime.h>
#include <cstdint>
#include <cstddef>

// ---------------------------------------------------------------------------
// CausalSelfAttention: y = proj(softmax_causal(QK^T/sqrt(HD)) V), QKV = x@W_attn+b
// B=2 T=2048 C=2048 H=16 HD=128. All I/O fp32; internal compute bf16 MFMA.
// ---------------------------------------------------------------------------

typedef __bf16 bf16x8 __attribute__((ext_vector_type(8)));
typedef float  f32x4  __attribute__((ext_vector_type(4)));
typedef unsigned short u16x4 __attribute__((ext_vector_type(4)));
typedef unsigned short u16x8 __attribute__((ext_vector_type(8)));

__device__ __forceinline__ unsigned short f2bf(float f) {
  unsigned int u = __builtin_bit_cast(unsigned int, f);
  u += 0x7fffu + ((u >> 16) & 1u);       // round-to-nearest-even
  return (unsigned short)(u >> 16);
}

__device__ __forceinline__ void gld16(void* lds, const void* g) {
  // async global->LDS, 16B per lane; LDS dest is wave-uniform base + lane*16
  __builtin_amdgcn_global_load_lds(
      (const __attribute__((address_space(1))) void*)g,
      (__attribute__((address_space(3))) void*)lds, 16, 0, 0);
}

// ---------------------------------------------------------------------------
// fp32 -> bf16 elementwise (x conversion)
// ---------------------------------------------------------------------------
__global__ void cvt_f32_bf16_k(const float* __restrict__ in,
                               unsigned short* __restrict__ out, int n4) {
  int i = blockIdx.x * blockDim.x + threadIdx.x;
  int stride = gridDim.x * blockDim.x;
  for (; i < n4; i += stride) {
    float4 v = ((const float4*)in)[i];
    ushort4 o;
    o.x = f2bf(v.x); o.y = f2bf(v.y); o.z = f2bf(v.z); o.w = f2bf(v.w);
    ((ushort4*)out)[i] = o;
  }
}

// ---------------------------------------------------------------------------
// fp32 (R,C) -> bf16 transposed (C,R). 64x64 tile, float4 reads, 16B writes.
// ---------------------------------------------------------------------------
__global__ __launch_bounds__(256) void transpose_f32_bf16(
    const float* __restrict__ in, unsigned short* __restrict__ out,
    int R, int C) {
  __shared__ float tile[64][65];
  int c0 = blockIdx.x * 64, r0 = blockIdx.y * 64;
  int t = threadIdx.x;
  int lr = t >> 4, lc = (t & 15) * 4;
#pragma unroll
  for (int i = 0; i < 4; i++) {
    int row = lr + i * 16;
    float4 v = *(const float4*)&in[(size_t)(r0 + row) * C + c0 + lc];
    tile[row][lc] = v.x; tile[row][lc + 1] = v.y;
    tile[row][lc + 2] = v.z; tile[row][lc + 3] = v.w;
  }
  __syncthreads();
  int wr = t >> 3, wc = (t & 7) * 8;
#pragma unroll
  for (int i = 0; i < 2; i++) {
    int crow = wr + i * 32;
    u16x8 o;
#pragma unroll
    for (int j = 0; j < 8; j++) o[j] = f2bf(tile[wc + j][crow]);
    *(u16x8*)&out[(size_t)(c0 + crow) * R + r0 + wc] = o;
  }
}

// ---------------------------------------------------------------------------
// extract V^T (B,H,HD,T) bf16 from qkv (B*T, 3C) bf16. 64t x 64d tile.
// ---------------------------------------------------------------------------
__global__ __launch_bounds__(256) void extract_vT_k(
    const unsigned short* __restrict__ qkv, unsigned short* __restrict__ vT) {
  __shared__ unsigned int tile32[64][33];   // [d][t&31] packs (t, t+32)
  int bh = blockIdx.z, b = bh >> 4, h = bh & 15;
  int t0 = blockIdx.x * 64, d0 = blockIdx.y * 64;
  int t = threadIdx.x;
  int lr = t >> 3, lc = (t & 7) * 8;
  const unsigned short* src = qkv + (size_t)(b * 2048) * 6144 + 4096 + h * 128;
#pragma unroll
  for (int i = 0; i < 2; i++) {
    int row = lr + i * 32;
    u16x8 v = *(const u16x8*)&src[(size_t)(t0 + row) * 6144 + d0 + lc];
#pragma unroll
    for (int j = 0; j < 8; j++) {
      unsigned short* p = (unsigned short*)&tile32[lc + j][row & 31];
      p[row >> 5] = v[j];
    }
  }
  __syncthreads();
  int dr = t >> 2, tc = (t & 3) * 8;
  u16x8 lo, hi;
#pragma unroll
  for (int j = 0; j < 8; j++) {
    unsigned int u = tile32[dr][tc + j];
    lo[j] = (unsigned short)(u & 0xffffu);
    hi[j] = (unsigned short)(u >> 16);
  }
  unsigned short* dst = vT + (size_t)bh * 128 * 2048 + (size_t)(d0 + dr) * 2048 + t0;
  *(u16x8*)&dst[tc] = lo;
  *(u16x8*)&dst[tc + 32] = hi;
}

// ---------------------------------------------------------------------------
// GEMM (legacy 128x128, BK=64, 4 waves): kept for the proj GEMM, where the
// 256^2 grid would be only 128 WGs (half the chip).
// ---------------------------------------------------------------------------
template <int OUT_BF16>
__global__ __launch_bounds__(256) void gemm_bt(
    const unsigned short* __restrict__ A, const unsigned short* __restrict__ BT,
    const float* __restrict__ bias, void* __restrict__ Cout,
    int M, int N, int K) {
  __shared__ __align__(16) unsigned short sA[128 * 64];
  __shared__ __align__(16) unsigned short sB[128 * 64];

  const int tid = threadIdx.x, w = tid >> 6, lane = tid & 63;
  const int quad = lane >> 4, l16 = lane & 15;
  const int m0 = blockIdx.y * 128, n0 = blockIdx.x * 128;
  const int wr = w >> 1, wc = w & 1;

  const unsigned short* gA[4];
  const unsigned short* gB[4];
  unsigned short* lA[4];
  unsigned short* lB[4];
#pragma unroll
  for (int i = 0; i < 4; i++) {
    int c = w * 256 + i * 64 + lane;
    int row = c >> 3, scol = (c & 7) ^ (row & 7);
    gA[i] = A + (size_t)(m0 + row) * K + scol * 8;
    gB[i] = BT + (size_t)(n0 + row) * K + scol * 8;
    lA[i] = sA + (size_t)(w * 256 + i * 64) * 8;
    lB[i] = sB + (size_t)(w * 256 + i * 64) * 8;
  }

  f32x4 acc[4][4] = {};

  for (int k0 = 0; k0 < K; k0 += 64) {
#pragma unroll
    for (int i = 0; i < 4; i++) {
      gld16(lA[i], gA[i]); gld16(lB[i], gB[i]);
      gA[i] += 64; gB[i] += 64;
    }
    __syncthreads();

#pragma unroll
    for (int kk = 0; kk < 2; kk++) {
      const int cc = (kk * 4 + quad) ^ (l16 & 7);
      bf16x8 af[4], bfr[4];
#pragma unroll
      for (int mi = 0; mi < 4; mi++)
        af[mi] = *(const bf16x8*)&sA[(wr * 64 + mi * 16 + l16) * 64 + cc * 8];
#pragma unroll
      for (int ni = 0; ni < 4; ni++)
        bfr[ni] = *(const bf16x8*)&sB[(wc * 64 + ni * 16 + l16) * 64 + cc * 8];
#pragma unroll
      for (int mi = 0; mi < 4; mi++)
#pragma unroll
        for (int ni = 0; ni < 4; ni++)
          acc[mi][ni] = __builtin_amdgcn_mfma_f32_16x16x32_bf16(
              af[mi], bfr[ni], acc[mi][ni], 0, 0, 0);
    }
    __syncthreads();
  }

#pragma unroll
  for (int mi = 0; mi < 4; mi++) {
    int row = m0 + wr * 64 + mi * 16 + quad * 4;
#pragma unroll
    for (int ni = 0; ni < 4; ni++) {
      int col = n0 + wc * 64 + ni * 16 + l16;
      float bv = bias[col];
#pragma unroll
      for (int r = 0; r < 4; r++) {
        float v = acc[mi][ni][r] + bv;
        if (OUT_BF16)
          ((unsigned short*)Cout)[(size_t)(row + r) * N + col] = f2bf(v);
        else
          ((float*)Cout)[(size_t)(row + r) * N + col] = v;
      }
    }
  }
}

// ---------------------------------------------------------------------------
// GEMM 256x256 8-phase (m201 template, plain HIP). BK=64, 8 waves (2Mx4N),
// 512 threads, 128 KiB LDS (2 dbuf x (A 256x64 + B 256x64) bf16).
//
// R1 fix: deep staging lead. A sub-tile mapping rr = mh*128 + wr*64 + ...
// means phase (mh,kk) reads ONLY A-half mh; B/A-lo of a tile die at its ph2,
// A-hi at ph3. Pieces of tile t+2 are staged at phases 3 and 4 of tile t's
// window (4-5 phase lead, ~3000 cyc > HBM latency), confirmed by vmcnt(4)
// at ph3/ph7 only -- every confirmed load was issued 3.5-4.5 phases earlier,
// never a recent one. Steady state: 12 loads (3 piece-pairs) in flight.
//
// Schedule (iteration i: t0=2i in buf0 phases 0-3, t1=2i+1 in buf1 phases 4-7):
//   ph0: stage Bhi(t1),Ahi(t1)      [their regions died prev ph6/ph7]
//   ph3: stage Blo(tn0),Alo(tn0); vmcnt(4) confirms t1's 4 pieces
//   ph4: stage Bhi(tn0),Ahi(tn0)    [buf0 B/A-hi died ph2/ph3]
//   ph7: stage Blo(tn1),Alo(tn1); vmcnt(4) confirms tn0's 4 pieces
// WAR: every overwritten region's last ds_read completed before the prior
// barrier pair (lgkmcnt(0) precedes each MFMA; stages issue after barriers).
// ---------------------------------------------------------------------------
#define BARRIER8 __builtin_amdgcn_s_barrier()
#define WAIT_LGKM0 asm volatile("s_waitcnt lgkmcnt(0)" ::: "memory")
#define WAIT_VM4 asm volatile("s_waitcnt vmcnt(4)" ::: "memory")
#define WAIT_VM0 asm volatile("s_waitcnt vmcnt(0)" ::: "memory")

#define STAGE_A(buf, h, t)                                                   \
  do {                                                                       \
    gld16(&sA[buf][((h) * 1024 + w * 64) * 8],                               \
          gA0 + (size_t)(h) * 128 * K + (size_t)(t) * 64);                   \
    gld16(&sA[buf][((h) * 1024 + 512 + w * 64) * 8],                         \
          gA1 + (size_t)(h) * 128 * K + (size_t)(t) * 64);                   \
  } while (0)

#define STAGE_B(buf, h, t)                                                   \
  do {                                                                       \
    gld16(&sB[buf][((h) * 1024 + w * 64) * 8],                               \
          gB0 + (size_t)(h) * 128 * K + (size_t)(t) * 64);                   \
    gld16(&sB[buf][((h) * 1024 + 512 + w * 64) * 8],                         \
          gB1 + (size_t)(h) * 128 * K + (size_t)(t) * 64);                   \
  } while (0)

// A sub-tile for phase (mh, kk): rows mh*128 + wr*64 + [0,64) -> only half mh
#define LDA4(buf, mh, kk)                                                    \
  do {                                                                       \
    const int cc_ = ((kk) * 4 + quad) ^ (l16 & 7);                           \
    _Pragma("unroll") for (int i_ = 0; i_ < 4; ++i_) {                       \
      const int rr_ = (mh) * 128 + wr * 64 + i_ * 16 + l16;                  \
      a_[i_] = *(const bf16x8*)&sA[buf][rr_ * 64 + cc_ * 8];                 \
    }                                                                        \
  } while (0)

#define LDB4(buf, kk)                                                        \
  do {                                                                       \
    const int cc_ = ((kk) * 4 + quad) ^ (l16 & 7);                           \
    _Pragma("unroll") for (int i_ = 0; i_ < 4; ++i_) {                       \
      const int rr_ = wc * 64 + i_ * 16 + l16;                               \
      b_[i_] = *(const bf16x8*)&sB[buf][rr_ * 64 + cc_ * 8];                 \
    }                                                                        \
  } while (0)

#define MM16(mh)                                                             \
  do {                                                                       \
    __builtin_amdgcn_s_setprio(1);                                           \
    _Pragma("unroll") for (int i_ = 0; i_ < 4; ++i_)                         \
    _Pragma("unroll") for (int n_ = 0; n_ < 4; ++n_)                         \
        acc[(mh) * 4 + i_][n_] = __builtin_amdgcn_mfma_f32_16x16x32_bf16(    \
            a_[i_], b_[n_], acc[(mh) * 4 + i_][n_], 0, 0, 0);                \
    __builtin_amdgcn_s_setprio(0);                                           \
  } while (0)

template <int OUT_BF16>
__global__ __launch_bounds__(512, 2) void gemm_bt8(
    const unsigned short* __restrict__ A, const unsigned short* __restrict__ BT,
    const float* __restrict__ bias, void* __restrict__ Cout,
    int M, int N, int K) {
  __shared__ __align__(16) unsigned short sA[2][256 * 64];
  __shared__ __align__(16) unsigned short sB[2][256 * 64];
  (void)M;

  const int tid = threadIdx.x, w = tid >> 6, lane = tid & 63;
  const int quad = lane >> 4, l16 = lane & 15;
  const int wr = w >> 2, wc = w & 3;   // wave -> (2M x 4N) grid

  // bijective XCD-aware block swizzle (m204 variant)
  const int nwgx = gridDim.x;
  const int nwg = nwgx * gridDim.y;
  const int wg = blockIdx.y * nwgx + blockIdx.x;
  const int q8 = nwg >> 3, r8 = nwg & 7;
  const int xcd = wg & 7, loc = wg >> 3;
  const int swz =
      (xcd < r8 ? xcd * (q8 + 1) : r8 * (q8 + 1) + (xcd - r8) * q8) + loc;
  const int m0 = (swz / nwgx) * 256;
  const int n0 = (swz % nwgx) * 256;

  // staging: half-tile = 128 rows x 64 cols bf16 = 1024 16B chunks;
  // thread owns chunks tid and tid+512. Slot s holds global chunk
  // (row=s>>3, col=(s&7)^(row&7)) -> pre-swizzled global source, linear LDS.
  const int c0 = tid, c1 = tid + 512;
  const int r0c = c0 >> 3, s0c = (c0 & 7) ^ (r0c & 7);
  const int r1c = c1 >> 3, s1c = (c1 & 7) ^ (r1c & 7);
  const unsigned short* gA0 = A + (size_t)(m0 + r0c) * K + s0c * 8;
  const unsigned short* gA1 = A + (size_t)(m0 + r1c) * K + s1c * 8;
  const unsigned short* gB0 = BT + (size_t)(n0 + r0c) * K + s0c * 8;
  const unsigned short* gB1 = BT + (size_t)(n0 + r1c) * K + s1c * 8;

  f32x4 acc[8][4] = {};
  bf16x8 a_[4], b_[4];

  const int NT = K >> 6;   // K-tiles (BK=64); must be even
  const int NI = NT >> 1;  // iterations (2 tiles each)

  // prologue: tile0 full -> buf0; tile1 {B-lo,A-lo} -> buf1; confirm tile0.
  STAGE_B(0, 0, 0); STAGE_A(0, 0, 0);
  STAGE_B(0, 1, 0); STAGE_A(0, 1, 0);
  STAGE_B(1, 0, 1); STAGE_A(1, 0, 1);
  WAIT_VM4;
  BARRIER8;

  for (int i = 0; i < NI; ++i) {
    const int t1 = 2 * i + 1;
    const int tn0 = 2 * i + 2, tn1 = 2 * i + 3;
    const bool last = (i == NI - 1);

    // ph0: buf0 (mh0,kk0) | stage t1 B-hi,A-hi
    LDB4(0, 0); LDA4(0, 0, 0);
    STAGE_B(1, 1, t1); STAGE_A(1, 1, t1);
    BARRIER8; WAIT_LGKM0; MM16(0); BARRIER8;

    // ph1: buf0 (mh1,kk0)
    LDA4(0, 1, 0);
    BARRIER8; WAIT_LGKM0; MM16(1); BARRIER8;

    // ph2: buf0 (mh0,kk1)
    LDB4(0, 1); LDA4(0, 0, 1);
    BARRIER8; WAIT_LGKM0; MM16(0); BARRIER8;

    // ph3: buf0 (mh1,kk1) | stage tn0 B-lo,A-lo | confirm buf1 (t1)
    LDA4(0, 1, 1);
    if (!last) {
      STAGE_B(0, 0, tn0); STAGE_A(0, 0, tn0);
      WAIT_VM4;
    } else {
      WAIT_VM0;
    }
    BARRIER8; WAIT_LGKM0; MM16(1); BARRIER8;

    // ph4: buf1 (mh0,kk0) | stage tn0 B-hi,A-hi
    LDB4(1, 0); LDA4(1, 0, 0);
    if (!last) { STAGE_B(0, 1, tn0); STAGE_A(0, 1, tn0); }
    BARRIER8; WAIT_LGKM0; MM16(0); BARRIER8;

    // ph5: buf1 (mh1,kk0)
    LDA4(1, 1, 0);
    BARRIER8; WAIT_LGKM0; MM16(1); BARRIER8;

    // ph6: buf1 (mh0,kk1)
    LDB4(1, 1); LDA4(1, 0, 1);
    BARRIER8; WAIT_LGKM0; MM16(0); BARRIER8;

    // ph7: buf1 (mh1,kk1) | stage tn1 B-lo,A-lo | confirm buf0 (tn0)
    LDA4(1, 1, 1);
    if (!last) {
      STAGE_B(1, 0, tn1); STAGE_A(1, 0, tn1);
      WAIT_VM4;
    }
    BARRIER8; WAIT_LGKM0; MM16(1); BARRIER8;
  }

  // epilogue: C/D layout row = quad*4+reg, col = l16; A-half mh at +mh*128
#pragma unroll
  for (int mi = 0; mi < 8; ++mi) {
    const int mh = mi >> 2, i2 = mi & 3;
    int row = m0 + mh * 128 + wr * 64 + i2 * 16 + quad * 4;
#pragma unroll
    for (int ni = 0; ni < 4; ++ni) {
      int col = n0 + wc * 64 + ni * 16 + l16;
      float bv = bias[col];
#pragma unroll
      for (int rr = 0; rr < 4; ++rr) {
        float v = acc[mi][ni][rr] + bv;
        if (OUT_BF16)
          ((unsigned short*)Cout)[(size_t)(row + rr) * N + col] = f2bf(v);
        else
          ((float*)Cout)[(size_t)(row + rr) * N + col] = v;
      }
    }
  }
}

#undef STAGE_A
#undef STAGE_B
#undef LDA4
#undef LDB4
#undef MM16

// ---------------------------------------------------------------------------
// Flash attention (causal), S^T formulation. (unchanged)
// ---------------------------------------------------------------------------
__global__ __launch_bounds__(256) void flash_attn(
    const unsigned short* __restrict__ qkv, const unsigned short* __restrict__ vT,
    unsigned short* __restrict__ yout) {
  __shared__ __align__(16) unsigned short sK[2][64 * 128];    // [t_k][d], swizzle &15
  __shared__ __align__(16) unsigned short sVT[2][128 * 64];   // [d][t_k], swizzle &7
  __shared__ __align__(16) unsigned short sP[4 * 16 * 64];    // per-wave P[q][k], chunk swizzle &7

  const int tid = threadIdx.x, w = tid >> 6, lane = tid & 63;
  const int quad = lane >> 4, l16 = lane & 15;
  const int id = blockIdx.x;
  const int g = id & 31;           // (b,h) group -> XCD g%8
  const int qp = id >> 5;          // 0..15
  const int b = g >> 4, h = g & 15;
  const int T = 2048, CC = 6144, HD = 128;
  const float qscale = 0.12753257252f;  // (1/sqrt(128)) * log2(e)

  const unsigned short* gK = qkv + (size_t)(b * T) * CC + 2048 + h * HD;
  const unsigned short* gV = vT + (size_t)(b * 16 + h) * HD * T;
  unsigned short* pw = sP + w * 16 * 64;

  const unsigned short* kSrc[4];
  const unsigned short* vSrc[4];
  unsigned short* kDst[4];
  unsigned short* vDst[4];
#pragma unroll
  for (int i = 0; i < 4; i++) {
    int c = w * 256 + i * 64 + lane;
    int kR = c >> 4, kC = (c & 15) ^ (kR & 15);
    int vR = c >> 3, vC = (c & 7) ^ (vR & 7);
    kSrc[i] = gK + (size_t)kR * CC + kC * 8;
    vSrc[i] = gV + (size_t)vR * T + vC * 8;
    kDst[i] = (unsigned short*)sK + (size_t)(w * 256 + i * 64) * 8;
    vDst[i] = (unsigned short*)sVT + (size_t)(w * 256 + i * 64) * 8;
  }
  const int KBUF = 64 * 128, VBUF = 128 * 64;

  const int qtA = qp, qtB = 31 - qp;
  int qt = qtA, kt = 0;

  bf16x8 qf[4];
  float m_old, l_sum;
  f32x4 o[8] = {};
  {
    const size_t qrow = (size_t)(b * T + qt * 64 + w * 16 + l16) * CC + h * HD;
#pragma unroll
    for (int kb = 0; kb < 4; kb++) {
      bf16x8 raw = *(const bf16x8*)&qkv[qrow + kb * 32 + quad * 8];
      bf16x8 sc;
#pragma unroll
      for (int j = 0; j < 8; j++) sc[j] = (__bf16)((float)raw[j] * qscale);
      qf[kb] = sc;
    }
  }
  m_old = -1e30f; l_sum = 0.f;

#pragma unroll
  for (int i = 0; i < 4; i++) {
    gld16(kDst[i], kSrc[i]);
    gld16(vDst[i], vSrc[i]);
  }

  const int total = qtA + qtB + 2;   // = 33
  for (int it = 0; it < total; ++it) {
    __syncthreads();
    const int cur = it & 1;
    const bool segEnd = (kt == qt);

    if (it + 1 < total) {
      const int nkt = segEnd ? 0 : kt + 1;
      const int nb_ = (it + 1) & 1;
      const size_t kOff = (size_t)nkt * 64 * CC;
      const int vOff = nkt * 64;
#pragma unroll
      for (int i = 0; i < 4; i++) {
        gld16(kDst[i] + (size_t)nb_ * KBUF, kSrc[i] + kOff);
        gld16(vDst[i] + (size_t)nb_ * VBUF, vSrc[i] + vOff);
      }
    }

    const unsigned short* sKc = (const unsigned short*)sK + (size_t)cur * KBUF;
    const unsigned short* sVc = (const unsigned short*)sVT + (size_t)cur * VBUF;

    f32x4 s4[4] = {};
#pragma unroll
    for (int dc = 0; dc < 4; dc++) {
#pragma unroll
      for (int kb = 0; kb < 4; kb++) {
        int rr = kb * 16 + l16;
        int cc = (dc * 4 + quad) ^ l16;
        bf16x8 kf = *(const bf16x8*)&sKc[rr * 128 + cc * 8];
        s4[kb] = __builtin_amdgcn_mfma_f32_16x16x32_bf16(kf, qf[dc], s4[kb], 0, 0, 0);
      }
    }

    float sv[4][4];
#pragma unroll
    for (int kb = 0; kb < 4; kb++)
#pragma unroll
      for (int r = 0; r < 4; r++) {
        float v = s4[kb][r];
        if (segEnd) {
          if (kb * 16 + quad * 4 + r > w * 16 + l16) v = -1e30f;
        }
        sv[kb][r] = v;
      }

    float mx = sv[0][0];
#pragma unroll
    for (int kb = 0; kb < 4; kb++)
#pragma unroll
      for (int r = 0; r < 4; r++) mx = fmaxf(mx, sv[kb][r]);
    mx = fmaxf(mx, __shfl_xor(mx, 16));
    mx = fmaxf(mx, __shfl_xor(mx, 32));
    float m_new = fmaxf(m_old, mx);
    float a = exp2f(m_old - m_new);
    float ssum = 0.f;
#pragma unroll
    for (int kb = 0; kb < 4; kb++)
#pragma unroll
      for (int r = 0; r < 4; r++) {
        float p = exp2f(sv[kb][r] - m_new);
        sv[kb][r] = p;
        ssum += p;
      }
    ssum += __shfl_xor(ssum, 16);
    ssum += __shfl_xor(ssum, 32);
    l_sum = l_sum * a + ssum;
    m_old = m_new;

    float ar[4];
#pragma unroll
    for (int r = 0; r < 4; r++)
      ar[r] = __shfl(a, (lane & 48) + quad * 4 + r);
#pragma unroll
    for (int nb = 0; nb < 8; nb++)
#pragma unroll
      for (int r = 0; r < 4; r++) o[nb][r] *= ar[r];

#pragma unroll
    for (int kb = 0; kb < 4; kb++) {
      u16x4 pk;
#pragma unroll
      for (int r = 0; r < 4; r++) pk[r] = f2bf(sv[kb][r]);
      int c = kb * 2 + (quad >> 1);
      int cp = c ^ (l16 & 7);
      *(u16x4*)&pw[l16 * 64 + cp * 8 + (quad & 1) * 4] = pk;
    }

#pragma unroll
    for (int kb2 = 0; kb2 < 2; kb2++) {
      int pcc = (kb2 * 4 + quad) ^ (l16 & 7);
      bf16x8 pf = *(const bf16x8*)&pw[l16 * 64 + pcc * 8];
#pragma unroll
      for (int nb = 0; nb < 8; nb++) {
        int rr = nb * 16 + l16;
        int cc = (kb2 * 4 + quad) ^ (rr & 7);
        bf16x8 vf = *(const bf16x8*)&sVc[rr * 64 + cc * 8];
        o[nb] = __builtin_amdgcn_mfma_f32_16x16x32_bf16(pf, vf, o[nb], 0, 0, 0);
      }
    }

    if (segEnd) {
      float linv = 1.0f / l_sum;
#pragma unroll
      for (int r = 0; r < 4; r++) {
        float ir = __shfl(linv, (lane & 48) + quad * 4 + r);
        size_t orow = (size_t)(b * T + qt * 64 + w * 16 + quad * 4 + r) * 2048 + h * HD;
#pragma unroll
        for (int nb = 0; nb < 8; nb++)
          yout[orow + nb * 16 + l16] = f2bf(o[nb][r] * ir);
      }
      if (it + 1 < total) {
        qt = qtB;
        const size_t qrow = (size_t)(b * T + qt * 64 + w * 16 + l16) * CC + h * HD;
#pragma unroll
        for (int kb = 0; kb < 4; kb++) {
          bf16x8 raw = *(const bf16x8*)&qkv[qrow + kb * 32 + quad * 8];
          bf16x8 sc;
#pragma unroll
          for (int j = 0; j < 8; j++) sc[j] = (__bf16)((float)raw[j] * qscale);
          qf[kb] = sc;
        }
        m_old = -1e30f; l_sum = 0.f;
#pragma unroll
        for (int nb = 0; nb < 8; nb++) o[nb] = (f32x4){0.f, 0.f, 0.f, 0.f};
      }
      kt = 0;
    } else {
      kt++;
    }
  }
}

// ---------------------------------------------------------------------------
extern "C" void kernel_launch(void* const* d_in, const int* in_sizes, int n_in,
                              void* d_out, int out_size, void* d_ws, size_t ws_size,
                              hipStream_t stream) {
  const float* x      = (const float*)d_in[0];   // (2,2048,2048)
  const float* W_attn = (const float*)d_in[1];   // (2048,6144)
  const float* b_attn = (const float*)d_in[2];   // (6144,)
  const float* W_proj = (const float*)d_in[3];   // (2048,2048)
  const float* b_proj = (const float*)d_in[4];   // (2048,)
  float* out = (float*)d_out;                    // (2,2048,2048) fp32

  char* ws = (char*)d_ws;
  unsigned short* x_bf  = (unsigned short*)(ws);              // 16 MiB
  unsigned short* WaT   = (unsigned short*)(ws + 16777216);   // 24 MiB
  unsigned short* WpT   = (unsigned short*)(ws + 41943040);   // 8 MiB
  unsigned short* qkv   = (unsigned short*)(ws + 50331648);   // 48 MiB
  unsigned short* vT    = (unsigned short*)(ws + 100663296);  // 16 MiB
  unsigned short* y_att = (unsigned short*)(ws + 117440512);  // 16 MiB
  // total 128 MiB

  cvt_f32_bf16_k<<<1024, 256, 0, stream>>>(x, x_bf, 8388608 / 4);
  transpose_f32_bf16<<<dim3(96, 32), 256, 0, stream>>>(W_attn, WaT, 2048, 6144);
  transpose_f32_bf16<<<dim3(32, 32), 256, 0, stream>>>(W_proj, WpT, 2048, 2048);
  // QKV GEMM: 256^2 8-phase template, grid 24x16 = 384 WGs (%8==0)
  gemm_bt8<1><<<dim3(24, 16), 512, 0, stream>>>(x_bf, WaT, b_attn, qkv, 4096, 6144, 2048);
  extract_vT_k<<<dim3(32, 2, 32), 256, 0, stream>>>(qkv, vT);
  flash_attn<<<dim3(512), 256, 0, stream>>>(qkv, vT, y_att);
  gemm_bt<0><<<dim3(16, 32), 256, 0, stream>>>(y_att, WpT, b_proj, out, 4096, 2048, 2048);
}

// Round 3
// 388.856 us; speedup vs baseline: 1.0875x; 1.0342x over previous
//
#include <hip/hip_runtime.h>
#include <cstdint>
#include <cstddef>

// ---------------------------------------------------------------------------
// CausalSelfAttention: y = proj(softmax_causal(QK^T/sqrt(HD)) V), QKV = x@W_attn+b
// B=2 T=2048 C=2048 H=16 HD=128. All I/O fp32; internal compute bf16 MFMA.
// ---------------------------------------------------------------------------

typedef __bf16 bf16x8 __attribute__((ext_vector_type(8)));
typedef float  f32x4  __attribute__((ext_vector_type(4)));
typedef unsigned short u16x4 __attribute__((ext_vector_type(4)));
typedef unsigned short u16x8 __attribute__((ext_vector_type(8)));

__device__ __forceinline__ unsigned short f2bf(float f) {
  unsigned int u = __builtin_bit_cast(unsigned int, f);
  u += 0x7fffu + ((u >> 16) & 1u);       // round-to-nearest-even
  return (unsigned short)(u >> 16);
}

__device__ __forceinline__ void gld16(void* lds, const void* g) {
  // async global->LDS, 16B per lane; LDS dest is wave-uniform base + lane*16
  __builtin_amdgcn_global_load_lds(
      (const __attribute__((address_space(1))) void*)g,
      (__attribute__((address_space(3))) void*)lds, 16, 0, 0);
}

// 32-bit LDS byte address from a generic __shared__ pointer
__device__ __forceinline__ unsigned lds_addr(const void* p) {
  return (unsigned)(size_t)(const __attribute__((address_space(3))) void*)p;
}

// inline-asm ds_read_b128: opaque to SIInsertWaitcnts, so no compiler-inserted
// vmcnt drain vs outstanding global_load_lds. Caller MUST pair with manual
// s_waitcnt lgkmcnt(0) + sched_barrier(0) before consuming (rule #18).
__device__ __forceinline__ bf16x8 ds_read16(unsigned addr) {
  bf16x8 r;
  asm volatile("ds_read_b128 %0, %1" : "=v"(r) : "v"(addr));
  return r;
}

// ---------------------------------------------------------------------------
// fp32 -> bf16 elementwise (x conversion)
// ---------------------------------------------------------------------------
__global__ void cvt_f32_bf16_k(const float* __restrict__ in,
                               unsigned short* __restrict__ out, int n4) {
  int i = blockIdx.x * blockDim.x + threadIdx.x;
  int stride = gridDim.x * blockDim.x;
  for (; i < n4; i += stride) {
    float4 v = ((const float4*)in)[i];
    ushort4 o;
    o.x = f2bf(v.x); o.y = f2bf(v.y); o.z = f2bf(v.z); o.w = f2bf(v.w);
    ((ushort4*)out)[i] = o;
  }
}

// ---------------------------------------------------------------------------
// fp32 (R,C) -> bf16 transposed (C,R). 64x64 tile, float4 reads, 16B writes.
// ---------------------------------------------------------------------------
__global__ __launch_bounds__(256) void transpose_f32_bf16(
    const float* __restrict__ in, unsigned short* __restrict__ out,
    int R, int C) {
  __shared__ float tile[64][65];
  int c0 = blockIdx.x * 64, r0 = blockIdx.y * 64;
  int t = threadIdx.x;
  int lr = t >> 4, lc = (t & 15) * 4;
#pragma unroll
  for (int i = 0; i < 4; i++) {
    int row = lr + i * 16;
    float4 v = *(const float4*)&in[(size_t)(r0 + row) * C + c0 + lc];
    tile[row][lc] = v.x; tile[row][lc + 1] = v.y;
    tile[row][lc + 2] = v.z; tile[row][lc + 3] = v.w;
  }
  __syncthreads();
  int wr = t >> 3, wc = (t & 7) * 8;
#pragma unroll
  for (int i = 0; i < 2; i++) {
    int crow = wr + i * 32;
    u16x8 o;
#pragma unroll
    for (int j = 0; j < 8; j++) o[j] = f2bf(tile[wc + j][crow]);
    *(u16x8*)&out[(size_t)(c0 + crow) * R + r0 + wc] = o;
  }
}

// ---------------------------------------------------------------------------
// extract V^T (B,H,HD,T) bf16 from qkv (B*T, 3C) bf16. 64t x 64d tile.
// ---------------------------------------------------------------------------
__global__ __launch_bounds__(256) void extract_vT_k(
    const unsigned short* __restrict__ qkv, unsigned short* __restrict__ vT) {
  __shared__ unsigned int tile32[64][33];   // [d][t&31] packs (t, t+32)
  int bh = blockIdx.z, b = bh >> 4, h = bh & 15;
  int t0 = blockIdx.x * 64, d0 = blockIdx.y * 64;
  int t = threadIdx.x;
  int lr = t >> 3, lc = (t & 7) * 8;
  const unsigned short* src = qkv + (size_t)(b * 2048) * 6144 + 4096 + h * 128;
#pragma unroll
  for (int i = 0; i < 2; i++) {
    int row = lr + i * 32;
    u16x8 v = *(const u16x8*)&src[(size_t)(t0 + row) * 6144 + d0 + lc];
#pragma unroll
    for (int j = 0; j < 8; j++) {
      unsigned short* p = (unsigned short*)&tile32[lc + j][row & 31];
      p[row >> 5] = v[j];
    }
  }
  __syncthreads();
  int dr = t >> 2, tc = (t & 3) * 8;
  u16x8 lo, hi;
#pragma unroll
  for (int j = 0; j < 8; j++) {
    unsigned int u = tile32[dr][tc + j];
    lo[j] = (unsigned short)(u & 0xffffu);
    hi[j] = (unsigned short)(u >> 16);
  }
  unsigned short* dst = vT + (size_t)bh * 128 * 2048 + (size_t)(d0 + dr) * 2048 + t0;
  *(u16x8*)&dst[tc] = lo;
  *(u16x8*)&dst[tc + 32] = hi;
}

// ---------------------------------------------------------------------------
// GEMM (legacy 128x128, BK=64, 4 waves): kept for the proj GEMM, where the
// 256^2 grid would be only 128 WGs (half the chip).
// ---------------------------------------------------------------------------
template <int OUT_BF16>
__global__ __launch_bounds__(256) void gemm_bt(
    const unsigned short* __restrict__ A, const unsigned short* __restrict__ BT,
    const float* __restrict__ bias, void* __restrict__ Cout,
    int M, int N, int K) {
  __shared__ __align__(16) unsigned short sA[128 * 64];
  __shared__ __align__(16) unsigned short sB[128 * 64];

  const int tid = threadIdx.x, w = tid >> 6, lane = tid & 63;
  const int quad = lane >> 4, l16 = lane & 15;
  const int m0 = blockIdx.y * 128, n0 = blockIdx.x * 128;
  const int wr = w >> 1, wc = w & 1;

  const unsigned short* gA[4];
  const unsigned short* gB[4];
  unsigned short* lA[4];
  unsigned short* lB[4];
#pragma unroll
  for (int i = 0; i < 4; i++) {
    int c = w * 256 + i * 64 + lane;
    int row = c >> 3, scol = (c & 7) ^ (row & 7);
    gA[i] = A + (size_t)(m0 + row) * K + scol * 8;
    gB[i] = BT + (size_t)(n0 + row) * K + scol * 8;
    lA[i] = sA + (size_t)(w * 256 + i * 64) * 8;
    lB[i] = sB + (size_t)(w * 256 + i * 64) * 8;
  }

  f32x4 acc[4][4] = {};

  for (int k0 = 0; k0 < K; k0 += 64) {
#pragma unroll
    for (int i = 0; i < 4; i++) {
      gld16(lA[i], gA[i]); gld16(lB[i], gB[i]);
      gA[i] += 64; gB[i] += 64;
    }
    __syncthreads();

#pragma unroll
    for (int kk = 0; kk < 2; kk++) {
      const int cc = (kk * 4 + quad) ^ (l16 & 7);
      bf16x8 af[4], bfr[4];
#pragma unroll
      for (int mi = 0; mi < 4; mi++)
        af[mi] = *(const bf16x8*)&sA[(wr * 64 + mi * 16 + l16) * 64 + cc * 8];
#pragma unroll
      for (int ni = 0; ni < 4; ni++)
        bfr[ni] = *(const bf16x8*)&sB[(wc * 64 + ni * 16 + l16) * 64 + cc * 8];
#pragma unroll
      for (int mi = 0; mi < 4; mi++)
#pragma unroll
        for (int ni = 0; ni < 4; ni++)
          acc[mi][ni] = __builtin_amdgcn_mfma_f32_16x16x32_bf16(
              af[mi], bfr[ni], acc[mi][ni], 0, 0, 0);
    }
    __syncthreads();
  }

#pragma unroll
  for (int mi = 0; mi < 4; mi++) {
    int row = m0 + wr * 64 + mi * 16 + quad * 4;
#pragma unroll
    for (int ni = 0; ni < 4; ni++) {
      int col = n0 + wc * 64 + ni * 16 + l16;
      float bv = bias[col];
#pragma unroll
      for (int r = 0; r < 4; r++) {
        float v = acc[mi][ni][r] + bv;
        if (OUT_BF16)
          ((unsigned short*)Cout)[(size_t)(row + r) * N + col] = f2bf(v);
        else
          ((float*)Cout)[(size_t)(row + r) * N + col] = v;
      }
    }
  }
}

// ---------------------------------------------------------------------------
// GEMM 256x256 8-phase (m201 template, plain HIP). BK=64, 8 waves (2Mx4N),
// 512 threads, 128 KiB LDS (2 dbuf x (A 256x64 + B 256x64) bf16).
//
// R2 schedule (deep staging lead, vmcnt(4) at ph3/ph7 only) + R3 fix:
// fragment loads are inline-asm ds_read_b128 (opaque to SIInsertWaitcnts),
// so the compiler cannot insert vmcnt drains to order them against
// outstanding global_load_lds LDS-writes -- that implicit drain (~800 cyc
// every phase) was the R2 stall. Manual lgkmcnt(0) + sched_barrier(0)
// before each MFMA cluster (rule #18: MFMA hoists past asm lgkmcnt
// without the sched fence).
//
// Schedule (iteration i: t0=2i in buf0 phases 0-3, t1=2i+1 in buf1 phases 4-7):
//   ph0: stage Bhi(t1),Ahi(t1)
//   ph3: stage Blo(tn0),Alo(tn0); vmcnt(4) confirms t1's 4 pieces
//   ph4: stage Bhi(tn0),Ahi(tn0)
//   ph7: stage Blo(tn1),Alo(tn1); vmcnt(4) confirms tn0's 4 pieces
// RAW: each confirmed piece was issued 3.5-4.5 phases earlier. WAR: each
// overwritten region's last ds_read completed >=1 barrier-pair earlier.
// ---------------------------------------------------------------------------
#define BARRIER8 __builtin_amdgcn_s_barrier()
#define WAIT_LGKM0 asm volatile("s_waitcnt lgkmcnt(0)" ::: "memory")
#define SCHED0 __builtin_amdgcn_sched_barrier(0)
#define WAIT_VM4 asm volatile("s_waitcnt vmcnt(4)" ::: "memory")
#define WAIT_VM0 asm volatile("s_waitcnt vmcnt(0)" ::: "memory")

#define STAGE_A(buf, h, t)                                                   \
  do {                                                                       \
    gld16(&sA[buf][((h) * 1024 + w * 64) * 8],                               \
          gA0 + (size_t)(h) * 128 * K + (size_t)(t) * 64);                   \
    gld16(&sA[buf][((h) * 1024 + 512 + w * 64) * 8],                         \
          gA1 + (size_t)(h) * 128 * K + (size_t)(t) * 64);                   \
  } while (0)

#define STAGE_B(buf, h, t)                                                   \
  do {                                                                       \
    gld16(&sB[buf][((h) * 1024 + w * 64) * 8],                               \
          gB0 + (size_t)(h) * 128 * K + (size_t)(t) * 64);                   \
    gld16(&sB[buf][((h) * 1024 + 512 + w * 64) * 8],                         \
          gB1 + (size_t)(h) * 128 * K + (size_t)(t) * 64);                   \
  } while (0)

// A sub-tile for phase (mh, kk): rows mh*128 + wr*64 + [0,64) -> only half mh
#define LDA4(buf, mh, kk)                                                    \
  do {                                                                       \
    const int cc_ = ((kk) * 4 + quad) ^ (l16 & 7);                           \
    _Pragma("unroll") for (int i_ = 0; i_ < 4; ++i_) {                       \
      const int rr_ = (mh) * 128 + wr * 64 + i_ * 16 + l16;                  \
      a_[i_] = ds_read16(lds_addr(&sA[buf][rr_ * 64 + cc_ * 8]));            \
    }                                                                        \
  } while (0)

#define LDB4(buf, kk)                                                        \
  do {                                                                       \
    const int cc_ = ((kk) * 4 + quad) ^ (l16 & 7);                           \
    _Pragma("unroll") for (int i_ = 0; i_ < 4; ++i_) {                       \
      const int rr_ = wc * 64 + i_ * 16 + l16;                               \
      b_[i_] = ds_read16(lds_addr(&sB[buf][rr_ * 64 + cc_ * 8]));            \
    }                                                                        \
  } while (0)

#define MM16(mh)                                                             \
  do {                                                                       \
    __builtin_amdgcn_s_setprio(1);                                           \
    _Pragma("unroll") for (int i_ = 0; i_ < 4; ++i_)                         \
    _Pragma("unroll") for (int n_ = 0; n_ < 4; ++n_)                         \
        acc[(mh) * 4 + i_][n_] = __builtin_amdgcn_mfma_f32_16x16x32_bf16(    \
            a_[i_], b_[n_], acc[(mh) * 4 + i_][n_], 0, 0, 0);                \
    __builtin_amdgcn_s_setprio(0);                                           \
  } while (0)

template <int OUT_BF16>
__global__ __launch_bounds__(512, 2) void gemm_bt8(
    const unsigned short* __restrict__ A, const unsigned short* __restrict__ BT,
    const float* __restrict__ bias, void* __restrict__ Cout,
    int M, int N, int K) {
  __shared__ __align__(16) unsigned short sA[2][256 * 64];
  __shared__ __align__(16) unsigned short sB[2][256 * 64];
  (void)M;

  const int tid = threadIdx.x, w = tid >> 6, lane = tid & 63;
  const int quad = lane >> 4, l16 = lane & 15;
  const int wr = w >> 2, wc = w & 3;   // wave -> (2M x 4N) grid

  // bijective XCD-aware block swizzle (m204 variant)
  const int nwgx = gridDim.x;
  const int nwg = nwgx * gridDim.y;
  const int wg = blockIdx.y * nwgx + blockIdx.x;
  const int q8 = nwg >> 3, r8 = nwg & 7;
  const int xcd = wg & 7, loc = wg >> 3;
  const int swz =
      (xcd < r8 ? xcd * (q8 + 1) : r8 * (q8 + 1) + (xcd - r8) * q8) + loc;
  const int m0 = (swz / nwgx) * 256;
  const int n0 = (swz % nwgx) * 256;

  // staging: half-tile = 128 rows x 64 cols bf16 = 1024 16B chunks;
  // thread owns chunks tid and tid+512. Slot s holds global chunk
  // (row=s>>3, col=(s&7)^(row&7)) -> pre-swizzled global source, linear LDS.
  const int c0 = tid, c1 = tid + 512;
  const int r0c = c0 >> 3, s0c = (c0 & 7) ^ (r0c & 7);
  const int r1c = c1 >> 3, s1c = (c1 & 7) ^ (r1c & 7);
  const unsigned short* gA0 = A + (size_t)(m0 + r0c) * K + s0c * 8;
  const unsigned short* gA1 = A + (size_t)(m0 + r1c) * K + s1c * 8;
  const unsigned short* gB0 = BT + (size_t)(n0 + r0c) * K + s0c * 8;
  const unsigned short* gB1 = BT + (size_t)(n0 + r1c) * K + s1c * 8;

  f32x4 acc[8][4] = {};
  bf16x8 a_[4], b_[4];

  const int NT = K >> 6;   // K-tiles (BK=64); must be even
  const int NI = NT >> 1;  // iterations (2 tiles each)

  // prologue: tile0 full -> buf0; tile1 {B-lo,A-lo} -> buf1; confirm tile0.
  STAGE_B(0, 0, 0); STAGE_A(0, 0, 0);
  STAGE_B(0, 1, 0); STAGE_A(0, 1, 0);
  STAGE_B(1, 0, 1); STAGE_A(1, 0, 1);
  WAIT_VM4;
  BARRIER8;

  for (int i = 0; i < NI; ++i) {
    const int t1 = 2 * i + 1;
    const int tn0 = 2 * i + 2, tn1 = 2 * i + 3;
    const bool last = (i == NI - 1);

    // ph0: buf0 (mh0,kk0) | stage t1 B-hi,A-hi
    LDB4(0, 0); LDA4(0, 0, 0);
    STAGE_B(1, 1, t1); STAGE_A(1, 1, t1);
    BARRIER8; WAIT_LGKM0; SCHED0; MM16(0); BARRIER8;

    // ph1: buf0 (mh1,kk0)
    LDA4(0, 1, 0);
    BARRIER8; WAIT_LGKM0; SCHED0; MM16(1); BARRIER8;

    // ph2: buf0 (mh0,kk1)
    LDB4(0, 1); LDA4(0, 0, 1);
    BARRIER8; WAIT_LGKM0; SCHED0; MM16(0); BARRIER8;

    // ph3: buf0 (mh1,kk1) | stage tn0 B-lo,A-lo | confirm buf1 (t1)
    LDA4(0, 1, 1);
    if (!last) {
      STAGE_B(0, 0, tn0); STAGE_A(0, 0, tn0);
      WAIT_VM4;
    } else {
      WAIT_VM0;
    }
    BARRIER8; WAIT_LGKM0; SCHED0; MM16(1); BARRIER8;

    // ph4: buf1 (mh0,kk0) | stage tn0 B-hi,A-hi
    LDB4(1, 0); LDA4(1, 0, 0);
    if (!last) { STAGE_B(0, 1, tn0); STAGE_A(0, 1, tn0); }
    BARRIER8; WAIT_LGKM0; SCHED0; MM16(0); BARRIER8;

    // ph5: buf1 (mh1,kk0)
    LDA4(1, 1, 0);
    BARRIER8; WAIT_LGKM0; SCHED0; MM16(1); BARRIER8;

    // ph6: buf1 (mh0,kk1)
    LDB4(1, 1); LDA4(1, 0, 1);
    BARRIER8; WAIT_LGKM0; SCHED0; MM16(0); BARRIER8;

    // ph7: buf1 (mh1,kk1) | stage tn1 B-lo,A-lo | confirm buf0 (tn0)
    LDA4(1, 1, 1);
    if (!last) {
      STAGE_B(1, 0, tn1); STAGE_A(1, 0, tn1);
      WAIT_VM4;
    }
    BARRIER8; WAIT_LGKM0; SCHED0; MM16(1); BARRIER8;
  }

  // epilogue: C/D layout row = quad*4+reg, col = l16; A-half mh at +mh*128
#pragma unroll
  for (int mi = 0; mi < 8; ++mi) {
    const int mh = mi >> 2, i2 = mi & 3;
    int row = m0 + mh * 128 + wr * 64 + i2 * 16 + quad * 4;
#pragma unroll
    for (int ni = 0; ni < 4; ++ni) {
      int col = n0 + wc * 64 + ni * 16 + l16;
      float bv = bias[col];
#pragma unroll
      for (int rr = 0; rr < 4; ++rr) {
        float v = acc[mi][ni][rr] + bv;
        if (OUT_BF16)
          ((unsigned short*)Cout)[(size_t)(row + rr) * N + col] = f2bf(v);
        else
          ((float*)Cout)[(size_t)(row + rr) * N + col] = v;
      }
    }
  }
}

#undef STAGE_A
#undef STAGE_B
#undef LDA4
#undef LDB4
#undef MM16

// ---------------------------------------------------------------------------
// Flash attention (causal), S^T formulation. (unchanged)
// ---------------------------------------------------------------------------
__global__ __launch_bounds__(256) void flash_attn(
    const unsigned short* __restrict__ qkv, const unsigned short* __restrict__ vT,
    unsigned short* __restrict__ yout) {
  __shared__ __align__(16) unsigned short sK[2][64 * 128];    // [t_k][d], swizzle &15
  __shared__ __align__(16) unsigned short sVT[2][128 * 64];   // [d][t_k], swizzle &7
  __shared__ __align__(16) unsigned short sP[4 * 16 * 64];    // per-wave P[q][k], chunk swizzle &7

  const int tid = threadIdx.x, w = tid >> 6, lane = tid & 63;
  const int quad = lane >> 4, l16 = lane & 15;
  const int id = blockIdx.x;
  const int g = id & 31;           // (b,h) group -> XCD g%8
  const int qp = id >> 5;          // 0..15
  const int b = g >> 4, h = g & 15;
  const int T = 2048, CC = 6144, HD = 128;
  const float qscale = 0.12753257252f;  // (1/sqrt(128)) * log2(e)

  const unsigned short* gK = qkv + (size_t)(b * T) * CC + 2048 + h * HD;
  const unsigned short* gV = vT + (size_t)(b * 16 + h) * HD * T;
  unsigned short* pw = sP + w * 16 * 64;

  const unsigned short* kSrc[4];
  const unsigned short* vSrc[4];
  unsigned short* kDst[4];
  unsigned short* vDst[4];
#pragma unroll
  for (int i = 0; i < 4; i++) {
    int c = w * 256 + i * 64 + lane;
    int kR = c >> 4, kC = (c & 15) ^ (kR & 15);
    int vR = c >> 3, vC = (c & 7) ^ (vR & 7);
    kSrc[i] = gK + (size_t)kR * CC + kC * 8;
    vSrc[i] = gV + (size_t)vR * T + vC * 8;
    kDst[i] = (unsigned short*)sK + (size_t)(w * 256 + i * 64) * 8;
    vDst[i] = (unsigned short*)sVT + (size_t)(w * 256 + i * 64) * 8;
  }
  const int KBUF = 64 * 128, VBUF = 128 * 64;

  const int qtA = qp, qtB = 31 - qp;
  int qt = qtA, kt = 0;

  bf16x8 qf[4];
  float m_old, l_sum;
  f32x4 o[8] = {};
  {
    const size_t qrow = (size_t)(b * T + qt * 64 + w * 16 + l16) * CC + h * HD;
#pragma unroll
    for (int kb = 0; kb < 4; kb++) {
      bf16x8 raw = *(const bf16x8*)&qkv[qrow + kb * 32 + quad * 8];
      bf16x8 sc;
#pragma unroll
      for (int j = 0; j < 8; j++) sc[j] = (__bf16)((float)raw[j] * qscale);
      qf[kb] = sc;
    }
  }
  m_old = -1e30f; l_sum = 0.f;

#pragma unroll
  for (int i = 0; i < 4; i++) {
    gld16(kDst[i], kSrc[i]);
    gld16(vDst[i], vSrc[i]);
  }

  const int total = qtA + qtB + 2;   // = 33
  for (int it = 0; it < total; ++it) {
    __syncthreads();
    const int cur = it & 1;
    const bool segEnd = (kt == qt);

    if (it + 1 < total) {
      const int nkt = segEnd ? 0 : kt + 1;
      const int nb_ = (it + 1) & 1;
      const size_t kOff = (size_t)nkt * 64 * CC;
      const int vOff = nkt * 64;
#pragma unroll
      for (int i = 0; i < 4; i++) {
        gld16(kDst[i] + (size_t)nb_ * KBUF, kSrc[i] + kOff);
        gld16(vDst[i] + (size_t)nb_ * VBUF, vSrc[i] + vOff);
      }
    }

    const unsigned short* sKc = (const unsigned short*)sK + (size_t)cur * KBUF;
    const unsigned short* sVc = (const unsigned short*)sVT + (size_t)cur * VBUF;

    f32x4 s4[4] = {};
#pragma unroll
    for (int dc = 0; dc < 4; dc++) {
#pragma unroll
      for (int kb = 0; kb < 4; kb++) {
        int rr = kb * 16 + l16;
        int cc = (dc * 4 + quad) ^ l16;
        bf16x8 kf = *(const bf16x8*)&sKc[rr * 128 + cc * 8];
        s4[kb] = __builtin_amdgcn_mfma_f32_16x16x32_bf16(kf, qf[dc], s4[kb], 0, 0, 0);
      }
    }

    float sv[4][4];
#pragma unroll
    for (int kb = 0; kb < 4; kb++)
#pragma unroll
      for (int r = 0; r < 4; r++) {
        float v = s4[kb][r];
        if (segEnd) {
          if (kb * 16 + quad * 4 + r > w * 16 + l16) v = -1e30f;
        }
        sv[kb][r] = v;
      }

    float mx = sv[0][0];
#pragma unroll
    for (int kb = 0; kb < 4; kb++)
#pragma unroll
      for (int r = 0; r < 4; r++) mx = fmaxf(mx, sv[kb][r]);
    mx = fmaxf(mx, __shfl_xor(mx, 16));
    mx = fmaxf(mx, __shfl_xor(mx, 32));
    float m_new = fmaxf(m_old, mx);
    float a = exp2f(m_old - m_new);
    float ssum = 0.f;
#pragma unroll
    for (int kb = 0; kb < 4; kb++)
#pragma unroll
      for (int r = 0; r < 4; r++) {
        float p = exp2f(sv[kb][r] - m_new);
        sv[kb][r] = p;
        ssum += p;
      }
    ssum += __shfl_xor(ssum, 16);
    ssum += __shfl_xor(ssum, 32);
    l_sum = l_sum * a + ssum;
    m_old = m_new;

    float ar[4];
#pragma unroll
    for (int r = 0; r < 4; r++)
      ar[r] = __shfl(a, (lane & 48) + quad * 4 + r);
#pragma unroll
    for (int nb = 0; nb < 8; nb++)
#pragma unroll
      for (int r = 0; r < 4; r++) o[nb][r] *= ar[r];

#pragma unroll
    for (int kb = 0; kb < 4; kb++) {
      u16x4 pk;
#pragma unroll
      for (int r = 0; r < 4; r++) pk[r] = f2bf(sv[kb][r]);
      int c = kb * 2 + (quad >> 1);
      int cp = c ^ (l16 & 7);
      *(u16x4*)&pw[l16 * 64 + cp * 8 + (quad & 1) * 4] = pk;
    }

#pragma unroll
    for (int kb2 = 0; kb2 < 2; kb2++) {
      int pcc = (kb2 * 4 + quad) ^ (l16 & 7);
      bf16x8 pf = *(const bf16x8*)&pw[l16 * 64 + pcc * 8];
#pragma unroll
      for (int nb = 0; nb < 8; nb++) {
        int rr = nb * 16 + l16;
        int cc = (kb2 * 4 + quad) ^ (rr & 7);
        bf16x8 vf = *(const bf16x8*)&sVc[rr * 64 + cc * 8];
        o[nb] = __builtin_amdgcn_mfma_f32_16x16x32_bf16(pf, vf, o[nb], 0, 0, 0);
      }
    }

    if (segEnd) {
      float linv = 1.0f / l_sum;
#pragma unroll
      for (int r = 0; r < 4; r++) {
        float ir = __shfl(linv, (lane & 48) + quad * 4 + r);
        size_t orow = (size_t)(b * T + qt * 64 + w * 16 + quad * 4 + r) * 2048 + h * HD;
#pragma unroll
        for (int nb = 0; nb < 8; nb++)
          yout[orow + nb * 16 + l16] = f2bf(o[nb][r] * ir);
      }
      if (it + 1 < total) {
        qt = qtB;
        const size_t qrow = (size_t)(b * T + qt * 64 + w * 16 + l16) * CC + h * HD;
#pragma unroll
        for (int kb = 0; kb < 4; kb++) {
          bf16x8 raw = *(const bf16x8*)&qkv[qrow + kb * 32 + quad * 8];
          bf16x8 sc;
#pragma unroll
          for (int j = 0; j < 8; j++) sc[j] = (__bf16)((float)raw[j] * qscale);
          qf[kb] = sc;
        }
        m_old = -1e30f; l_sum = 0.f;
#pragma unroll
        for (int nb = 0; nb < 8; nb++) o[nb] = (f32x4){0.f, 0.f, 0.f, 0.f};
      }
      kt = 0;
    } else {
      kt++;
    }
  }
}

// ---------------------------------------------------------------------------
extern "C" void kernel_launch(void* const* d_in, const int* in_sizes, int n_in,
                              void* d_out, int out_size, void* d_ws, size_t ws_size,
                              hipStream_t stream) {
  const float* x      = (const float*)d_in[0];   // (2,2048,2048)
  const float* W_attn = (const float*)d_in[1];   // (2048,6144)
  const float* b_attn = (const float*)d_in[2];   // (6144,)
  const float* W_proj = (const float*)d_in[3];   // (2048,2048)
  const float* b_proj = (const float*)d_in[4];   // (2048,)
  float* out = (float*)d_out;                    // (2,2048,2048) fp32

  char* ws = (char*)d_ws;
  unsigned short* x_bf  = (unsigned short*)(ws);              // 16 MiB
  unsigned short* WaT   = (unsigned short*)(ws + 16777216);   // 24 MiB
  unsigned short* WpT   = (unsigned short*)(ws + 41943040);   // 8 MiB
  unsigned short* qkv   = (unsigned short*)(ws + 50331648);   // 48 MiB
  unsigned short* vT    = (unsigned short*)(ws + 100663296);  // 16 MiB
  unsigned short* y_att = (unsigned short*)(ws + 117440512);  // 16 MiB
  // total 128 MiB

  cvt_f32_bf16_k<<<1024, 256, 0, stream>>>(x, x_bf, 8388608 / 4);
  transpose_f32_bf16<<<dim3(96, 32), 256, 0, stream>>>(W_attn, WaT, 2048, 6144);
  transpose_f32_bf16<<<dim3(32, 32), 256, 0, stream>>>(W_proj, WpT, 2048, 2048);
  // QKV GEMM: 256^2 8-phase template, grid 24x16 = 384 WGs (%8==0)
  gemm_bt8<1><<<dim3(24, 16), 512, 0, stream>>>(x_bf, WaT, b_attn, qkv, 4096, 6144, 2048);
  extract_vT_k<<<dim3(32, 2, 32), 256, 0, stream>>>(qkv, vT);
  flash_attn<<<dim3(512), 256, 0, stream>>>(qkv, vT, y_att);
  gemm_bt<0><<<dim3(16, 32), 256, 0, stream>>>(y_att, WpT, b_proj, out, 4096, 2048, 2048);
}

// Round 4
// 379.842 us; speedup vs baseline: 1.1133x; 1.0237x over previous
//
#include <hip/hip_runtime.h>
#include <cstdint>
#include <cstddef>

// ---------------------------------------------------------------------------
// CausalSelfAttention: y = proj(softmax_causal(QK^T/sqrt(HD)) V), QKV = x@W_attn+b
// B=2 T=2048 C=2048 H=16 HD=128. All I/O fp32; internal compute bf16 MFMA.
// ---------------------------------------------------------------------------

typedef __bf16 bf16x8 __attribute__((ext_vector_type(8)));
typedef float  f32x4  __attribute__((ext_vector_type(4)));
typedef unsigned short u16x4 __attribute__((ext_vector_type(4)));
typedef unsigned short u16x8 __attribute__((ext_vector_type(8)));

__device__ __forceinline__ unsigned short f2bf(float f) {
  unsigned int u = __builtin_bit_cast(unsigned int, f);
  u += 0x7fffu + ((u >> 16) & 1u);       // round-to-nearest-even
  return (unsigned short)(u >> 16);
}

__device__ __forceinline__ void gld16(void* lds, const void* g) {
  // async global->LDS, 16B per lane; LDS dest is wave-uniform base + lane*16
  __builtin_amdgcn_global_load_lds(
      (const __attribute__((address_space(1))) void*)g,
      (__attribute__((address_space(3))) void*)lds, 16, 0, 0);
}

// 32-bit LDS byte address from a generic __shared__ pointer
__device__ __forceinline__ unsigned lds_addr(const void* p) {
  return (unsigned)(size_t)(const __attribute__((address_space(3))) void*)p;
}

// inline-asm ds_read_b128: opaque to SIInsertWaitcnts, so no compiler-inserted
// vmcnt drain vs outstanding global_load_lds. Caller MUST pair with manual
// s_waitcnt lgkmcnt(N) + sched_barrier(0) before consuming (rule #18).
__device__ __forceinline__ bf16x8 ds_read16(unsigned addr) {
  bf16x8 r;
  asm volatile("ds_read_b128 %0, %1" : "=v"(r) : "v"(addr));
  return r;
}

// inline-asm ds_write_b64 (same rationale)
__device__ __forceinline__ void ds_write8(unsigned addr, u16x4 d) {
  unsigned long long v = __builtin_bit_cast(unsigned long long, d);
  asm volatile("ds_write_b64 %0, %1" :: "v"(addr), "v"(v));
}

// ---------------------------------------------------------------------------
// fp32 -> bf16 elementwise (x conversion)
// ---------------------------------------------------------------------------
__global__ void cvt_f32_bf16_k(const float* __restrict__ in,
                               unsigned short* __restrict__ out, int n4) {
  int i = blockIdx.x * blockDim.x + threadIdx.x;
  int stride = gridDim.x * blockDim.x;
  for (; i < n4; i += stride) {
    float4 v = ((const float4*)in)[i];
    ushort4 o;
    o.x = f2bf(v.x); o.y = f2bf(v.y); o.z = f2bf(v.z); o.w = f2bf(v.w);
    ((ushort4*)out)[i] = o;
  }
}

// ---------------------------------------------------------------------------
// fp32 (R,C) -> bf16 transposed (C,R). 64x64 tile, float4 reads, 16B writes.
// ---------------------------------------------------------------------------
__global__ __launch_bounds__(256) void transpose_f32_bf16(
    const float* __restrict__ in, unsigned short* __restrict__ out,
    int R, int C) {
  __shared__ float tile[64][65];
  int c0 = blockIdx.x * 64, r0 = blockIdx.y * 64;
  int t = threadIdx.x;
  int lr = t >> 4, lc = (t & 15) * 4;
#pragma unroll
  for (int i = 0; i < 4; i++) {
    int row = lr + i * 16;
    float4 v = *(const float4*)&in[(size_t)(r0 + row) * C + c0 + lc];
    tile[row][lc] = v.x; tile[row][lc + 1] = v.y;
    tile[row][lc + 2] = v.z; tile[row][lc + 3] = v.w;
  }
  __syncthreads();
  int wr = t >> 3, wc = (t & 7) * 8;
#pragma unroll
  for (int i = 0; i < 2; i++) {
    int crow = wr + i * 32;
    u16x8 o;
#pragma unroll
    for (int j = 0; j < 8; j++) o[j] = f2bf(tile[wc + j][crow]);
    *(u16x8*)&out[(size_t)(c0 + crow) * R + r0 + wc] = o;
  }
}

// ---------------------------------------------------------------------------
// extract V^T (B,H,HD,T) bf16 from qkv (B*T, 3C) bf16. 64t x 64d tile.
// ---------------------------------------------------------------------------
__global__ __launch_bounds__(256) void extract_vT_k(
    const unsigned short* __restrict__ qkv, unsigned short* __restrict__ vT) {
  __shared__ unsigned int tile32[64][33];   // [d][t&31] packs (t, t+32)
  int bh = blockIdx.z, b = bh >> 4, h = bh & 15;
  int t0 = blockIdx.x * 64, d0 = blockIdx.y * 64;
  int t = threadIdx.x;
  int lr = t >> 3, lc = (t & 7) * 8;
  const unsigned short* src = qkv + (size_t)(b * 2048) * 6144 + 4096 + h * 128;
#pragma unroll
  for (int i = 0; i < 2; i++) {
    int row = lr + i * 32;
    u16x8 v = *(const u16x8*)&src[(size_t)(t0 + row) * 6144 + d0 + lc];
#pragma unroll
    for (int j = 0; j < 8; j++) {
      unsigned short* p = (unsigned short*)&tile32[lc + j][row & 31];
      p[row >> 5] = v[j];
    }
  }
  __syncthreads();
  int dr = t >> 2, tc = (t & 3) * 8;
  u16x8 lo, hi;
#pragma unroll
  for (int j = 0; j < 8; j++) {
    unsigned int u = tile32[dr][tc + j];
    lo[j] = (unsigned short)(u & 0xffffu);
    hi[j] = (unsigned short)(u >> 16);
  }
  unsigned short* dst = vT + (size_t)bh * 128 * 2048 + (size_t)(d0 + dr) * 2048 + t0;
  *(u16x8*)&dst[tc] = lo;
  *(u16x8*)&dst[tc + 32] = hi;
}

// ---------------------------------------------------------------------------
// GEMM (legacy 128x128, BK=64, 4 waves): kept for the proj GEMM.
// ---------------------------------------------------------------------------
template <int OUT_BF16>
__global__ __launch_bounds__(256) void gemm_bt(
    const unsigned short* __restrict__ A, const unsigned short* __restrict__ BT,
    const float* __restrict__ bias, void* __restrict__ Cout,
    int M, int N, int K) {
  __shared__ __align__(16) unsigned short sA[128 * 64];
  __shared__ __align__(16) unsigned short sB[128 * 64];

  const int tid = threadIdx.x, w = tid >> 6, lane = tid & 63;
  const int quad = lane >> 4, l16 = lane & 15;
  const int m0 = blockIdx.y * 128, n0 = blockIdx.x * 128;
  const int wr = w >> 1, wc = w & 1;

  const unsigned short* gA[4];
  const unsigned short* gB[4];
  unsigned short* lA[4];
  unsigned short* lB[4];
#pragma unroll
  for (int i = 0; i < 4; i++) {
    int c = w * 256 + i * 64 + lane;
    int row = c >> 3, scol = (c & 7) ^ (row & 7);
    gA[i] = A + (size_t)(m0 + row) * K + scol * 8;
    gB[i] = BT + (size_t)(n0 + row) * K + scol * 8;
    lA[i] = sA + (size_t)(w * 256 + i * 64) * 8;
    lB[i] = sB + (size_t)(w * 256 + i * 64) * 8;
  }

  f32x4 acc[4][4] = {};

  for (int k0 = 0; k0 < K; k0 += 64) {
#pragma unroll
    for (int i = 0; i < 4; i++) {
      gld16(lA[i], gA[i]); gld16(lB[i], gB[i]);
      gA[i] += 64; gB[i] += 64;
    }
    __syncthreads();

#pragma unroll
    for (int kk = 0; kk < 2; kk++) {
      const int cc = (kk * 4 + quad) ^ (l16 & 7);
      bf16x8 af[4], bfr[4];
#pragma unroll
      for (int mi = 0; mi < 4; mi++)
        af[mi] = *(const bf16x8*)&sA[(wr * 64 + mi * 16 + l16) * 64 + cc * 8];
#pragma unroll
      for (int ni = 0; ni < 4; ni++)
        bfr[ni] = *(const bf16x8*)&sB[(wc * 64 + ni * 16 + l16) * 64 + cc * 8];
#pragma unroll
      for (int mi = 0; mi < 4; mi++)
#pragma unroll
        for (int ni = 0; ni < 4; ni++)
          acc[mi][ni] = __builtin_amdgcn_mfma_f32_16x16x32_bf16(
              af[mi], bfr[ni], acc[mi][ni], 0, 0, 0);
    }
    __syncthreads();
  }

#pragma unroll
  for (int mi = 0; mi < 4; mi++) {
    int row = m0 + wr * 64 + mi * 16 + quad * 4;
#pragma unroll
    for (int ni = 0; ni < 4; ni++) {
      int col = n0 + wc * 64 + ni * 16 + l16;
      float bv = bias[col];
#pragma unroll
      for (int r = 0; r < 4; r++) {
        float v = acc[mi][ni][r] + bv;
        if (OUT_BF16)
          ((unsigned short*)Cout)[(size_t)(row + r) * N + col] = f2bf(v);
        else
          ((float*)Cout)[(size_t)(row + r) * N + col] = v;
      }
    }
  }
}

// ---------------------------------------------------------------------------
// GEMM 256x256 8-phase (unchanged from R3: asm ds_read + deep staging lead).
// ---------------------------------------------------------------------------
#define BARRIER8 __builtin_amdgcn_s_barrier()
#define WAIT_LGKM0 asm volatile("s_waitcnt lgkmcnt(0)" ::: "memory")
#define WAIT_LGKM4 asm volatile("s_waitcnt lgkmcnt(4)" ::: "memory")
#define SCHED0 __builtin_amdgcn_sched_barrier(0)
#define WAIT_VM4 asm volatile("s_waitcnt vmcnt(4)" ::: "memory")
#define WAIT_VM0 asm volatile("s_waitcnt vmcnt(0)" ::: "memory")

#define STAGE_A(buf, h, t)                                                   \
  do {                                                                       \
    gld16(&sA[buf][((h) * 1024 + w * 64) * 8],                               \
          gA0 + (size_t)(h) * 128 * K + (size_t)(t) * 64);                   \
    gld16(&sA[buf][((h) * 1024 + 512 + w * 64) * 8],                         \
          gA1 + (size_t)(h) * 128 * K + (size_t)(t) * 64);                   \
  } while (0)

#define STAGE_B(buf, h, t)                                                   \
  do {                                                                       \
    gld16(&sB[buf][((h) * 1024 + w * 64) * 8],                               \
          gB0 + (size_t)(h) * 128 * K + (size_t)(t) * 64);                   \
    gld16(&sB[buf][((h) * 1024 + 512 + w * 64) * 8],                         \
          gB1 + (size_t)(h) * 128 * K + (size_t)(t) * 64);                   \
  } while (0)

// A sub-tile for phase (mh, kk): rows mh*128 + wr*64 + [0,64) -> only half mh
#define LDA4(buf, mh, kk)                                                    \
  do {                                                                       \
    const int cc_ = ((kk) * 4 + quad) ^ (l16 & 7);                           \
    _Pragma("unroll") for (int i_ = 0; i_ < 4; ++i_) {                       \
      const int rr_ = (mh) * 128 + wr * 64 + i_ * 16 + l16;                  \
      a_[i_] = ds_read16(lds_addr(&sA[buf][rr_ * 64 + cc_ * 8]));            \
    }                                                                        \
  } while (0)

#define LDB4(buf, kk)                                                        \
  do {                                                                       \
    const int cc_ = ((kk) * 4 + quad) ^ (l16 & 7);                           \
    _Pragma("unroll") for (int i_ = 0; i_ < 4; ++i_) {                       \
      const int rr_ = wc * 64 + i_ * 16 + l16;                               \
      b_[i_] = ds_read16(lds_addr(&sB[buf][rr_ * 64 + cc_ * 8]));            \
    }                                                                        \
  } while (0)

#define MM16(mh)                                                             \
  do {                                                                       \
    __builtin_amdgcn_s_setprio(1);                                           \
    _Pragma("unroll") for (int i_ = 0; i_ < 4; ++i_)                         \
    _Pragma("unroll") for (int n_ = 0; n_ < 4; ++n_)                         \
        acc[(mh) * 4 + i_][n_] = __builtin_amdgcn_mfma_f32_16x16x32_bf16(    \
            a_[i_], b_[n_], acc[(mh) * 4 + i_][n_], 0, 0, 0);                \
    __builtin_amdgcn_s_setprio(0);                                           \
  } while (0)

template <int OUT_BF16>
__global__ __launch_bounds__(512, 2) void gemm_bt8(
    const unsigned short* __restrict__ A, const unsigned short* __restrict__ BT,
    const float* __restrict__ bias, void* __restrict__ Cout,
    int M, int N, int K) {
  __shared__ __align__(16) unsigned short sA[2][256 * 64];
  __shared__ __align__(16) unsigned short sB[2][256 * 64];
  (void)M;

  const int tid = threadIdx.x, w = tid >> 6, lane = tid & 63;
  const int quad = lane >> 4, l16 = lane & 15;
  const int wr = w >> 2, wc = w & 3;   // wave -> (2M x 4N) grid

  // bijective XCD-aware block swizzle (m204 variant)
  const int nwgx = gridDim.x;
  const int nwg = nwgx * gridDim.y;
  const int wg = blockIdx.y * nwgx + blockIdx.x;
  const int q8 = nwg >> 3, r8 = nwg & 7;
  const int xcd = wg & 7, loc = wg >> 3;
  const int swz =
      (xcd < r8 ? xcd * (q8 + 1) : r8 * (q8 + 1) + (xcd - r8) * q8) + loc;
  const int m0 = (swz / nwgx) * 256;
  const int n0 = (swz % nwgx) * 256;

  const int c0 = tid, c1 = tid + 512;
  const int r0c = c0 >> 3, s0c = (c0 & 7) ^ (r0c & 7);
  const int r1c = c1 >> 3, s1c = (c1 & 7) ^ (r1c & 7);
  const unsigned short* gA0 = A + (size_t)(m0 + r0c) * K + s0c * 8;
  const unsigned short* gA1 = A + (size_t)(m0 + r1c) * K + s1c * 8;
  const unsigned short* gB0 = BT + (size_t)(n0 + r0c) * K + s0c * 8;
  const unsigned short* gB1 = BT + (size_t)(n0 + r1c) * K + s1c * 8;

  f32x4 acc[8][4] = {};
  bf16x8 a_[4], b_[4];

  const int NT = K >> 6;   // K-tiles (BK=64); must be even
  const int NI = NT >> 1;  // iterations (2 tiles each)

  // prologue: tile0 full -> buf0; tile1 {B-lo,A-lo} -> buf1; confirm tile0.
  STAGE_B(0, 0, 0); STAGE_A(0, 0, 0);
  STAGE_B(0, 1, 0); STAGE_A(0, 1, 0);
  STAGE_B(1, 0, 1); STAGE_A(1, 0, 1);
  WAIT_VM4;
  BARRIER8;

  for (int i = 0; i < NI; ++i) {
    const int t1 = 2 * i + 1;
    const int tn0 = 2 * i + 2, tn1 = 2 * i + 3;
    const bool last = (i == NI - 1);

    // ph0: buf0 (mh0,kk0) | stage t1 B-hi,A-hi
    LDB4(0, 0); LDA4(0, 0, 0);
    STAGE_B(1, 1, t1); STAGE_A(1, 1, t1);
    BARRIER8; WAIT_LGKM0; SCHED0; MM16(0); BARRIER8;

    // ph1: buf0 (mh1,kk0)
    LDA4(0, 1, 0);
    BARRIER8; WAIT_LGKM0; SCHED0; MM16(1); BARRIER8;

    // ph2: buf0 (mh0,kk1)
    LDB4(0, 1); LDA4(0, 0, 1);
    BARRIER8; WAIT_LGKM0; SCHED0; MM16(0); BARRIER8;

    // ph3: buf0 (mh1,kk1) | stage tn0 B-lo,A-lo | confirm buf1 (t1)
    LDA4(0, 1, 1);
    if (!last) {
      STAGE_B(0, 0, tn0); STAGE_A(0, 0, tn0);
      WAIT_VM4;
    } else {
      WAIT_VM0;
    }
    BARRIER8; WAIT_LGKM0; SCHED0; MM16(1); BARRIER8;

    // ph4: buf1 (mh0,kk0) | stage tn0 B-hi,A-hi
    LDB4(1, 0); LDA4(1, 0, 0);
    if (!last) { STAGE_B(0, 1, tn0); STAGE_A(0, 1, tn0); }
    BARRIER8; WAIT_LGKM0; SCHED0; MM16(0); BARRIER8;

    // ph5: buf1 (mh1,kk0)
    LDA4(1, 1, 0);
    BARRIER8; WAIT_LGKM0; SCHED0; MM16(1); BARRIER8;

    // ph6: buf1 (mh0,kk1)
    LDB4(1, 1); LDA4(1, 0, 1);
    BARRIER8; WAIT_LGKM0; SCHED0; MM16(0); BARRIER8;

    // ph7: buf1 (mh1,kk1) | stage tn1 B-lo,A-lo | confirm buf0 (tn0)
    LDA4(1, 1, 1);
    if (!last) {
      STAGE_B(1, 0, tn1); STAGE_A(1, 0, tn1);
      WAIT_VM4;
    }
    BARRIER8; WAIT_LGKM0; SCHED0; MM16(1); BARRIER8;
  }

  // epilogue: C/D layout row = quad*4+reg, col = l16; A-half mh at +mh*128
#pragma unroll
  for (int mi = 0; mi < 8; ++mi) {
    const int mh = mi >> 2, i2 = mi & 3;
    int row = m0 + mh * 128 + wr * 64 + i2 * 16 + quad * 4;
#pragma unroll
    for (int ni = 0; ni < 4; ++ni) {
      int col = n0 + wc * 64 + ni * 16 + l16;
      float bv = bias[col];
#pragma unroll
      for (int rr = 0; rr < 4; ++rr) {
        float v = acc[mi][ni][rr] + bv;
        if (OUT_BF16)
          ((unsigned short*)Cout)[(size_t)(row + rr) * N + col] = f2bf(v);
        else
          ((float*)Cout)[(size_t)(row + rr) * N + col] = v;
      }
    }
  }
}

#undef STAGE_A
#undef STAGE_B
#undef LDA4
#undef LDB4
#undef MM16

// ---------------------------------------------------------------------------
// Flash attention (causal), S^T formulation.
// R4: all LDS ops in the compute path are inline-asm (ds_read_b128 /
// ds_write_b64), so SIInsertWaitcnts cannot insert mid-iteration vmcnt drains
// against the outstanding global_load_lds prefetch -- previously the
// double-buffer never overlapped (same bug as R2's gemm_bt8). Manual counted
// lgkmcnt + sched_barrier(0) before each MFMA group (rule #18); QK^T is
// 2-deep pipelined (lgkmcnt(4)); setprio(1) around MFMA clusters (m191).
// The compiler's vmcnt(0) drain before __syncthreads() remains -- required
// for cross-wave visibility of the LDS-DMA, and by then the prefetch has had
// the whole body to complete.
// ---------------------------------------------------------------------------
__global__ __launch_bounds__(256) void flash_attn(
    const unsigned short* __restrict__ qkv, const unsigned short* __restrict__ vT,
    unsigned short* __restrict__ yout) {
  __shared__ __align__(16) unsigned short sK[2][64 * 128];    // [t_k][d], swizzle &15
  __shared__ __align__(16) unsigned short sVT[2][128 * 64];   // [d][t_k], swizzle &7
  __shared__ __align__(16) unsigned short sP[4 * 16 * 64];    // per-wave P[q][k], chunk swizzle &7

  const int tid = threadIdx.x, w = tid >> 6, lane = tid & 63;
  const int quad = lane >> 4, l16 = lane & 15;
  const int id = blockIdx.x;
  const int g = id & 31;           // (b,h) group -> XCD g%8
  const int qp = id >> 5;          // 0..15
  const int b = g >> 4, h = g & 15;
  const int T = 2048, CC = 6144, HD = 128;
  const float qscale = 0.12753257252f;  // (1/sqrt(128)) * log2(e)

  const unsigned short* gK = qkv + (size_t)(b * T) * CC + 2048 + h * HD;
  const unsigned short* gV = vT + (size_t)(b * 16 + h) * HD * T;
  unsigned short* pw = sP + w * 16 * 64;

  const unsigned short* kSrc[4];
  const unsigned short* vSrc[4];
  unsigned short* kDst[4];
  unsigned short* vDst[4];
#pragma unroll
  for (int i = 0; i < 4; i++) {
    int c = w * 256 + i * 64 + lane;
    int kR = c >> 4, kC = (c & 15) ^ (kR & 15);
    int vR = c >> 3, vC = (c & 7) ^ (vR & 7);
    kSrc[i] = gK + (size_t)kR * CC + kC * 8;
    vSrc[i] = gV + (size_t)vR * T + vC * 8;
    kDst[i] = (unsigned short*)sK + (size_t)(w * 256 + i * 64) * 8;
    vDst[i] = (unsigned short*)sVT + (size_t)(w * 256 + i * 64) * 8;
  }
  const int KBUF = 64 * 128, VBUF = 128 * 64;

  const int qtA = qp, qtB = 31 - qp;
  int qt = qtA, kt = 0;

  bf16x8 qf[4];
  float m_old, l_sum;
  f32x4 o[8] = {};
  {
    const size_t qrow = (size_t)(b * T + qt * 64 + w * 16 + l16) * CC + h * HD;
#pragma unroll
    for (int kb = 0; kb < 4; kb++) {
      bf16x8 raw = *(const bf16x8*)&qkv[qrow + kb * 32 + quad * 8];
      bf16x8 sc;
#pragma unroll
      for (int j = 0; j < 8; j++) sc[j] = (__bf16)((float)raw[j] * qscale);
      qf[kb] = sc;
    }
  }
  m_old = -1e30f; l_sum = 0.f;

#pragma unroll
  for (int i = 0; i < 4; i++) {
    gld16(kDst[i], kSrc[i]);
    gld16(vDst[i], vSrc[i]);
  }

  const int total = qtA + qtB + 2;   // = 33
  for (int it = 0; it < total; ++it) {
    __syncthreads();                 // buf[it&1] staged (vmcnt drained here)
    const int cur = it & 1;
    const bool segEnd = (kt == qt);

    // prefetch next tile into the other buffer (now truly overlapped)
    if (it + 1 < total) {
      const int nkt = segEnd ? 0 : kt + 1;
      const int nb_ = (it + 1) & 1;
      const size_t kOff = (size_t)nkt * 64 * CC;
      const int vOff = nkt * 64;
#pragma unroll
      for (int i = 0; i < 4; i++) {
        gld16(kDst[i] + (size_t)nb_ * KBUF, kSrc[i] + kOff);
        gld16(vDst[i] + (size_t)nb_ * VBUF, vSrc[i] + vOff);
      }
    }

    const unsigned short* sKc = (const unsigned short*)sK + (size_t)cur * KBUF;
    const unsigned short* sVc = (const unsigned short*)sVT + (size_t)cur * VBUF;

    // S^T = K Q^T, 2-deep lgkm-pipelined over dc (K-frag column blocks)
    f32x4 s4[4] = {};
    bf16x8 kf[4], kg[4];
#pragma unroll
    for (int kb = 0; kb < 4; kb++) {
      int rr = kb * 16 + l16;
      int cc = quad ^ l16;   // dc = 0
      kf[kb] = ds_read16(lds_addr(&sKc[rr * 128 + cc * 8]));
    }
#pragma unroll
    for (int dc = 0; dc < 4; dc++) {
      if (dc < 3) {
#pragma unroll
        for (int kb = 0; kb < 4; kb++) {
          int rr = kb * 16 + l16;
          int cc = ((dc + 1) * 4 + quad) ^ l16;
          kg[kb] = ds_read16(lds_addr(&sKc[rr * 128 + cc * 8]));
        }
        WAIT_LGKM4;
      } else {
        WAIT_LGKM0;
      }
      SCHED0;
      __builtin_amdgcn_s_setprio(1);
#pragma unroll
      for (int kb = 0; kb < 4; kb++)
        s4[kb] = __builtin_amdgcn_mfma_f32_16x16x32_bf16(kf[kb], qf[dc], s4[kb], 0, 0, 0);
      __builtin_amdgcn_s_setprio(0);
      if (dc < 3) {
#pragma unroll
        for (int kb = 0; kb < 4; kb++) kf[kb] = kg[kb];
      }
    }

    // causal mask (diagonal tile only): k_local > q_local
    float sv[4][4];
#pragma unroll
    for (int kb = 0; kb < 4; kb++)
#pragma unroll
      for (int r = 0; r < 4; r++) {
        float v = s4[kb][r];
        if (segEnd) {
          if (kb * 16 + quad * 4 + r > w * 16 + l16) v = -1e30f;
        }
        sv[kb][r] = v;
      }

    // online softmax: in-lane over 16 k-values + 2 cross-quad shuffles
    float mx = sv[0][0];
#pragma unroll
    for (int kb = 0; kb < 4; kb++)
#pragma unroll
      for (int r = 0; r < 4; r++) mx = fmaxf(mx, sv[kb][r]);
    mx = fmaxf(mx, __shfl_xor(mx, 16));
    mx = fmaxf(mx, __shfl_xor(mx, 32));
    float m_new = fmaxf(m_old, mx);
    float a = exp2f(m_old - m_new);
    float ssum = 0.f;
#pragma unroll
    for (int kb = 0; kb < 4; kb++)
#pragma unroll
      for (int r = 0; r < 4; r++) {
        float p = exp2f(sv[kb][r] - m_new);
        sv[kb][r] = p;
        ssum += p;
      }
    ssum += __shfl_xor(ssum, 16);
    ssum += __shfl_xor(ssum, 32);
    l_sum = l_sum * a + ssum;
    m_old = m_new;

    // broadcast alpha across layouts: O rows are q = quad*4+r
    float ar[4];
#pragma unroll
    for (int r = 0; r < 4; r++)
      ar[r] = __shfl(a, (lane & 48) + quad * 4 + r);
#pragma unroll
    for (int nb = 0; nb < 8; nb++)
#pragma unroll
      for (int r = 0; r < 4; r++) o[nb][r] *= ar[r];

    // P store: 4x ds_write_b64 (asm) into per-wave P[q][k]
#pragma unroll
    for (int kb = 0; kb < 4; kb++) {
      u16x4 pk;
#pragma unroll
      for (int r = 0; r < 4; r++) pk[r] = f2bf(sv[kb][r]);
      int c = kb * 2 + (quad >> 1);
      int cp = c ^ (l16 & 7);
      ds_write8(lds_addr(&pw[l16 * 64 + cp * 8 + (quad & 1) * 4]), pk);
    }
    WAIT_LGKM0;   // P writes complete (per-wave region; no barrier needed)
    SCHED0;

    // O += P V (4-read groups to cap VGPR)
#pragma unroll
    for (int kb2 = 0; kb2 < 2; kb2++) {
      int pcc = (kb2 * 4 + quad) ^ (l16 & 7);
      bf16x8 pf = ds_read16(lds_addr(&pw[l16 * 64 + pcc * 8]));
#pragma unroll
      for (int half = 0; half < 2; half++) {
        bf16x8 vf[4];
#pragma unroll
        for (int j = 0; j < 4; j++) {
          int nb = half * 4 + j;
          int rr = nb * 16 + l16;
          int cc = (kb2 * 4 + quad) ^ (rr & 7);
          vf[j] = ds_read16(lds_addr(&sVc[rr * 64 + cc * 8]));
        }
        WAIT_LGKM0;
        SCHED0;
        __builtin_amdgcn_s_setprio(1);
#pragma unroll
        for (int j = 0; j < 4; j++)
          o[half * 4 + j] = __builtin_amdgcn_mfma_f32_16x16x32_bf16(
              pf, vf[j], o[half * 4 + j], 0, 0, 0);
        __builtin_amdgcn_s_setprio(0);
      }
    }

    if (segEnd) {
      // epilogue: inv l_sum broadcast like alpha; O rows q = quad*4+r
      float linv = 1.0f / l_sum;
#pragma unroll
      for (int r = 0; r < 4; r++) {
        float ir = __shfl(linv, (lane & 48) + quad * 4 + r);
        size_t orow = (size_t)(b * T + qt * 64 + w * 16 + quad * 4 + r) * 2048 + h * HD;
#pragma unroll
        for (int nb = 0; nb < 8; nb++)
          yout[orow + nb * 16 + l16] = f2bf(o[nb][r] * ir);
      }
      if (it + 1 < total) {
        qt = qtB;
        const size_t qrow = (size_t)(b * T + qt * 64 + w * 16 + l16) * CC + h * HD;
#pragma unroll
        for (int kb = 0; kb < 4; kb++) {
          bf16x8 raw = *(const bf16x8*)&qkv[qrow + kb * 32 + quad * 8];
          bf16x8 sc;
#pragma unroll
          for (int j = 0; j < 8; j++) sc[j] = (__bf16)((float)raw[j] * qscale);
          qf[kb] = sc;
        }
        m_old = -1e30f; l_sum = 0.f;
#pragma unroll
        for (int nb = 0; nb < 8; nb++) o[nb] = (f32x4){0.f, 0.f, 0.f, 0.f};
      }
      kt = 0;
    } else {
      kt++;
    }
  }
}

// ---------------------------------------------------------------------------
extern "C" void kernel_launch(void* const* d_in, const int* in_sizes, int n_in,
                              void* d_out, int out_size, void* d_ws, size_t ws_size,
                              hipStream_t stream) {
  const float* x      = (const float*)d_in[0];   // (2,2048,2048)
  const float* W_attn = (const float*)d_in[1];   // (2048,6144)
  const float* b_attn = (const float*)d_in[2];   // (6144,)
  const float* W_proj = (const float*)d_in[3];   // (2048,2048)
  const float* b_proj = (const float*)d_in[4];   // (2048,)
  float* out = (float*)d_out;                    // (2,2048,2048) fp32

  char* ws = (char*)d_ws;
  unsigned short* x_bf  = (unsigned short*)(ws);              // 16 MiB
  unsigned short* WaT   = (unsigned short*)(ws + 16777216);   // 24 MiB
  unsigned short* WpT   = (unsigned short*)(ws + 41943040);   // 8 MiB
  unsigned short* qkv   = (unsigned short*)(ws + 50331648);   // 48 MiB
  unsigned short* vT    = (unsigned short*)(ws + 100663296);  // 16 MiB
  unsigned short* y_att = (unsigned short*)(ws + 117440512);  // 16 MiB
  // total 128 MiB

  cvt_f32_bf16_k<<<1024, 256, 0, stream>>>(x, x_bf, 8388608 / 4);
  transpose_f32_bf16<<<dim3(96, 32), 256, 0, stream>>>(W_attn, WaT, 2048, 6144);
  transpose_f32_bf16<<<dim3(32, 32), 256, 0, stream>>>(W_proj, WpT, 2048, 2048);
  // QKV GEMM: 256^2 8-phase template, grid 24x16 = 384 WGs (%8==0)
  gemm_bt8<1><<<dim3(24, 16), 512, 0, stream>>>(x_bf, WaT, b_attn, qkv, 4096, 6144, 2048);
  extract_vT_k<<<dim3(32, 2, 32), 256, 0, stream>>>(qkv, vT);
  flash_attn<<<dim3(512), 256, 0, stream>>>(qkv, vT, y_att);
  gemm_bt<0><<<dim3(16, 32), 256, 0, stream>>>(y_att, WpT, b_proj, out, 4096, 2048, 2048);
}

// Round 5
// 374.597 us; speedup vs baseline: 1.1289x; 1.0140x over previous
//
#include <hip/hip_runtime.h>
#include <cstdint>
#include <cstddef>

// ---------------------------------------------------------------------------
// CausalSelfAttention: y = proj(softmax_causal(QK^T/sqrt(HD)) V), QKV = x@W_attn+b
// B=2 T=2048 C=2048 H=16 HD=128. All I/O fp32; internal compute bf16 MFMA.
// ---------------------------------------------------------------------------

typedef __bf16 bf16x8 __attribute__((ext_vector_type(8)));
typedef float  f32x4  __attribute__((ext_vector_type(4)));
typedef unsigned short u16x4 __attribute__((ext_vector_type(4)));
typedef unsigned short u16x8 __attribute__((ext_vector_type(8)));

__device__ __forceinline__ unsigned short f2bf(float f) {
  unsigned int u = __builtin_bit_cast(unsigned int, f);
  u += 0x7fffu + ((u >> 16) & 1u);       // round-to-nearest-even
  return (unsigned short)(u >> 16);
}

__device__ __forceinline__ void gld16(void* lds, const void* g) {
  // async global->LDS, 16B per lane; LDS dest is wave-uniform base + lane*16
  __builtin_amdgcn_global_load_lds(
      (const __attribute__((address_space(1))) void*)g,
      (__attribute__((address_space(3))) void*)lds, 16, 0, 0);
}

// 32-bit LDS byte address from a generic __shared__ pointer
__device__ __forceinline__ unsigned lds_addr(const void* p) {
  return (unsigned)(size_t)(const __attribute__((address_space(3))) void*)p;
}

// inline-asm ds_read_b128: opaque to SIInsertWaitcnts, so no compiler-inserted
// vmcnt drain vs outstanding global_load_lds. Caller MUST pair with manual
// s_waitcnt lgkmcnt(N) + sched_barrier(0) before consuming (rule #18).
__device__ __forceinline__ bf16x8 ds_read16(unsigned addr) {
  bf16x8 r;
  asm volatile("ds_read_b128 %0, %1" : "=v"(r) : "v"(addr));
  return r;
}

// inline-asm ds_write_b64 (same rationale)
__device__ __forceinline__ void ds_write8(unsigned addr, u16x4 d) {
  unsigned long long v = __builtin_bit_cast(unsigned long long, d);
  asm volatile("ds_write_b64 %0, %1" :: "v"(addr), "v"(v));
}

// ---------------------------------------------------------------------------
// fp32 -> bf16 elementwise (x conversion)
// ---------------------------------------------------------------------------
__global__ void cvt_f32_bf16_k(const float* __restrict__ in,
                               unsigned short* __restrict__ out, int n4) {
  int i = blockIdx.x * blockDim.x + threadIdx.x;
  int stride = gridDim.x * blockDim.x;
  for (; i < n4; i += stride) {
    float4 v = ((const float4*)in)[i];
    ushort4 o;
    o.x = f2bf(v.x); o.y = f2bf(v.y); o.z = f2bf(v.z); o.w = f2bf(v.w);
    ((ushort4*)out)[i] = o;
  }
}

// ---------------------------------------------------------------------------
// fp32 (R,C) -> bf16 transposed (C,R). 64x64 tile, float4 reads, 16B writes.
// ---------------------------------------------------------------------------
__global__ __launch_bounds__(256) void transpose_f32_bf16(
    const float* __restrict__ in, unsigned short* __restrict__ out,
    int R, int C) {
  __shared__ float tile[64][65];
  int c0 = blockIdx.x * 64, r0 = blockIdx.y * 64;
  int t = threadIdx.x;
  int lr = t >> 4, lc = (t & 15) * 4;
#pragma unroll
  for (int i = 0; i < 4; i++) {
    int row = lr + i * 16;
    float4 v = *(const float4*)&in[(size_t)(r0 + row) * C + c0 + lc];
    tile[row][lc] = v.x; tile[row][lc + 1] = v.y;
    tile[row][lc + 2] = v.z; tile[row][lc + 3] = v.w;
  }
  __syncthreads();
  int wr = t >> 3, wc = (t & 7) * 8;
#pragma unroll
  for (int i = 0; i < 2; i++) {
    int crow = wr + i * 32;
    u16x8 o;
#pragma unroll
    for (int j = 0; j < 8; j++) o[j] = f2bf(tile[wc + j][crow]);
    *(u16x8*)&out[(size_t)(c0 + crow) * R + r0 + wc] = o;
  }
}

// ---------------------------------------------------------------------------
// extract V^T (B,H,HD,T) bf16 from qkv (B*T, 3C) bf16. 64t x 64d tile.
// ---------------------------------------------------------------------------
__global__ __launch_bounds__(256) void extract_vT_k(
    const unsigned short* __restrict__ qkv, unsigned short* __restrict__ vT) {
  __shared__ unsigned int tile32[64][33];   // [d][t&31] packs (t, t+32)
  int bh = blockIdx.z, b = bh >> 4, h = bh & 15;
  int t0 = blockIdx.x * 64, d0 = blockIdx.y * 64;
  int t = threadIdx.x;
  int lr = t >> 3, lc = (t & 7) * 8;
  const unsigned short* src = qkv + (size_t)(b * 2048) * 6144 + 4096 + h * 128;
#pragma unroll
  for (int i = 0; i < 2; i++) {
    int row = lr + i * 32;
    u16x8 v = *(const u16x8*)&src[(size_t)(t0 + row) * 6144 + d0 + lc];
#pragma unroll
    for (int j = 0; j < 8; j++) {
      unsigned short* p = (unsigned short*)&tile32[lc + j][row & 31];
      p[row >> 5] = v[j];
    }
  }
  __syncthreads();
  int dr = t >> 2, tc = (t & 3) * 8;
  u16x8 lo, hi;
#pragma unroll
  for (int j = 0; j < 8; j++) {
    unsigned int u = tile32[dr][tc + j];
    lo[j] = (unsigned short)(u & 0xffffu);
    hi[j] = (unsigned short)(u >> 16);
  }
  unsigned short* dst = vT + (size_t)bh * 128 * 2048 + (size_t)(d0 + dr) * 2048 + t0;
  *(u16x8*)&dst[tc] = lo;
  *(u16x8*)&dst[tc + 32] = hi;
}

// ---------------------------------------------------------------------------
// Shared sync/wait macros for the 8-phase GEMMs
// ---------------------------------------------------------------------------
#define BARRIER8 __builtin_amdgcn_s_barrier()
#define WAIT_LGKM0 asm volatile("s_waitcnt lgkmcnt(0)" ::: "memory")
#define WAIT_LGKM4 asm volatile("s_waitcnt lgkmcnt(4)" ::: "memory")
#define WAIT_LGKM5 asm volatile("s_waitcnt lgkmcnt(5)" ::: "memory")
#define SCHED0 __builtin_amdgcn_sched_barrier(0)
#define WAIT_VM4 asm volatile("s_waitcnt vmcnt(4)" ::: "memory")
#define WAIT_VM0 asm volatile("s_waitcnt vmcnt(0)" ::: "memory")

// ---------------------------------------------------------------------------
// GEMM 256x256 8-phase (QKV). BK=64, 8 waves (2Mx4N), 512 threads, 128 KiB LDS.
// asm ds_read + deep staging lead + counted vmcnt(4) at ph3/ph7 (R3 version).
// ---------------------------------------------------------------------------
#define STAGE_A(buf, h, t)                                                   \
  do {                                                                       \
    gld16(&sA[buf][((h) * 1024 + w * 64) * 8],                               \
          gA0 + (size_t)(h) * 128 * K + (size_t)(t) * 64);                   \
    gld16(&sA[buf][((h) * 1024 + 512 + w * 64) * 8],                         \
          gA1 + (size_t)(h) * 128 * K + (size_t)(t) * 64);                   \
  } while (0)

#define STAGE_B(buf, h, t)                                                   \
  do {                                                                       \
    gld16(&sB[buf][((h) * 1024 + w * 64) * 8],                               \
          gB0 + (size_t)(h) * 128 * K + (size_t)(t) * 64);                   \
    gld16(&sB[buf][((h) * 1024 + 512 + w * 64) * 8],                         \
          gB1 + (size_t)(h) * 128 * K + (size_t)(t) * 64);                   \
  } while (0)

// A sub-tile for phase (mh, kk): rows mh*128 + wr*64 + [0,64) -> only half mh
#define LDA4(buf, mh, kk)                                                    \
  do {                                                                       \
    const int cc_ = ((kk) * 4 + quad) ^ (l16 & 7);                           \
    _Pragma("unroll") for (int i_ = 0; i_ < 4; ++i_) {                       \
      const int rr_ = (mh) * 128 + wr * 64 + i_ * 16 + l16;                  \
      a_[i_] = ds_read16(lds_addr(&sA[buf][rr_ * 64 + cc_ * 8]));            \
    }                                                                        \
  } while (0)

#define LDB4(buf, kk)                                                        \
  do {                                                                       \
    const int cc_ = ((kk) * 4 + quad) ^ (l16 & 7);                           \
    _Pragma("unroll") for (int i_ = 0; i_ < 4; ++i_) {                       \
      const int rr_ = wc * 64 + i_ * 16 + l16;                               \
      b_[i_] = ds_read16(lds_addr(&sB[buf][rr_ * 64 + cc_ * 8]));            \
    }                                                                        \
  } while (0)

#define MM16(mh)                                                             \
  do {                                                                       \
    __builtin_amdgcn_s_setprio(1);                                           \
    _Pragma("unroll") for (int i_ = 0; i_ < 4; ++i_)                         \
    _Pragma("unroll") for (int n_ = 0; n_ < 4; ++n_)                         \
        acc[(mh) * 4 + i_][n_] = __builtin_amdgcn_mfma_f32_16x16x32_bf16(    \
            a_[i_], b_[n_], acc[(mh) * 4 + i_][n_], 0, 0, 0);                \
    __builtin_amdgcn_s_setprio(0);                                           \
  } while (0)

template <int OUT_BF16>
__global__ __launch_bounds__(512, 2) void gemm_bt8(
    const unsigned short* __restrict__ A, const unsigned short* __restrict__ BT,
    const float* __restrict__ bias, void* __restrict__ Cout,
    int M, int N, int K) {
  __shared__ __align__(16) unsigned short sA[2][256 * 64];
  __shared__ __align__(16) unsigned short sB[2][256 * 64];
  (void)M;

  const int tid = threadIdx.x, w = tid >> 6, lane = tid & 63;
  const int quad = lane >> 4, l16 = lane & 15;
  const int wr = w >> 2, wc = w & 3;   // wave -> (2M x 4N) grid

  // bijective XCD-aware block swizzle (m204 variant)
  const int nwgx = gridDim.x;
  const int nwg = nwgx * gridDim.y;
  const int wg = blockIdx.y * nwgx + blockIdx.x;
  const int q8 = nwg >> 3, r8 = nwg & 7;
  const int xcd = wg & 7, loc = wg >> 3;
  const int swz =
      (xcd < r8 ? xcd * (q8 + 1) : r8 * (q8 + 1) + (xcd - r8) * q8) + loc;
  const int m0 = (swz / nwgx) * 256;
  const int n0 = (swz % nwgx) * 256;

  const int c0 = tid, c1 = tid + 512;
  const int r0c = c0 >> 3, s0c = (c0 & 7) ^ (r0c & 7);
  const int r1c = c1 >> 3, s1c = (c1 & 7) ^ (r1c & 7);
  const unsigned short* gA0 = A + (size_t)(m0 + r0c) * K + s0c * 8;
  const unsigned short* gA1 = A + (size_t)(m0 + r1c) * K + s1c * 8;
  const unsigned short* gB0 = BT + (size_t)(n0 + r0c) * K + s0c * 8;
  const unsigned short* gB1 = BT + (size_t)(n0 + r1c) * K + s1c * 8;

  f32x4 acc[8][4] = {};
  bf16x8 a_[4], b_[4];

  const int NT = K >> 6;   // K-tiles (BK=64); must be even
  const int NI = NT >> 1;  // iterations (2 tiles each)

  // prologue: tile0 full -> buf0; tile1 {B-lo,A-lo} -> buf1; confirm tile0.
  STAGE_B(0, 0, 0); STAGE_A(0, 0, 0);
  STAGE_B(0, 1, 0); STAGE_A(0, 1, 0);
  STAGE_B(1, 0, 1); STAGE_A(1, 0, 1);
  WAIT_VM4;
  BARRIER8;

  for (int i = 0; i < NI; ++i) {
    const int t1 = 2 * i + 1;
    const int tn0 = 2 * i + 2, tn1 = 2 * i + 3;
    const bool last = (i == NI - 1);

    // ph0: buf0 (mh0,kk0) | stage t1 B-hi,A-hi
    LDB4(0, 0); LDA4(0, 0, 0);
    STAGE_B(1, 1, t1); STAGE_A(1, 1, t1);
    BARRIER8; WAIT_LGKM0; SCHED0; MM16(0); BARRIER8;

    // ph1: buf0 (mh1,kk0)
    LDA4(0, 1, 0);
    BARRIER8; WAIT_LGKM0; SCHED0; MM16(1); BARRIER8;

    // ph2: buf0 (mh0,kk1)
    LDB4(0, 1); LDA4(0, 0, 1);
    BARRIER8; WAIT_LGKM0; SCHED0; MM16(0); BARRIER8;

    // ph3: buf0 (mh1,kk1) | stage tn0 B-lo,A-lo | confirm buf1 (t1)
    LDA4(0, 1, 1);
    if (!last) {
      STAGE_B(0, 0, tn0); STAGE_A(0, 0, tn0);
      WAIT_VM4;
    } else {
      WAIT_VM0;
    }
    BARRIER8; WAIT_LGKM0; SCHED0; MM16(1); BARRIER8;

    // ph4: buf1 (mh0,kk0) | stage tn0 B-hi,A-hi
    LDB4(1, 0); LDA4(1, 0, 0);
    if (!last) { STAGE_B(0, 1, tn0); STAGE_A(0, 1, tn0); }
    BARRIER8; WAIT_LGKM0; SCHED0; MM16(0); BARRIER8;

    // ph5: buf1 (mh1,kk0)
    LDA4(1, 1, 0);
    BARRIER8; WAIT_LGKM0; SCHED0; MM16(1); BARRIER8;

    // ph6: buf1 (mh0,kk1)
    LDB4(1, 1); LDA4(1, 0, 1);
    BARRIER8; WAIT_LGKM0; SCHED0; MM16(0); BARRIER8;

    // ph7: buf1 (mh1,kk1) | stage tn1 B-lo,A-lo | confirm buf0 (tn0)
    LDA4(1, 1, 1);
    if (!last) {
      STAGE_B(1, 0, tn1); STAGE_A(1, 0, tn1);
      WAIT_VM4;
    }
    BARRIER8; WAIT_LGKM0; SCHED0; MM16(1); BARRIER8;
  }

  // epilogue: C/D layout row = quad*4+reg, col = l16; A-half mh at +mh*128
#pragma unroll
  for (int mi = 0; mi < 8; ++mi) {
    const int mh = mi >> 2, i2 = mi & 3;
    int row = m0 + mh * 128 + wr * 64 + i2 * 16 + quad * 4;
#pragma unroll
    for (int ni = 0; ni < 4; ++ni) {
      int col = n0 + wc * 64 + ni * 16 + l16;
      float bv = bias[col];
#pragma unroll
      for (int rr = 0; rr < 4; ++rr) {
        float v = acc[mi][ni][rr] + bv;
        if (OUT_BF16)
          ((unsigned short*)Cout)[(size_t)(row + rr) * N + col] = f2bf(v);
        else
          ((float*)Cout)[(size_t)(row + rr) * N + col] = v;
      }
    }
  }
}

#undef STAGE_A
#undef STAGE_B
#undef LDA4
#undef LDB4
#undef MM16

// ---------------------------------------------------------------------------
// GEMM 256x128 8-phase (proj). BK=64, 8 waves as 4Mx2N (64x64 out/wave),
// 512 threads, 96 KiB LDS (sA 2x256x64, sB 2x128x64). Grid 16x16 = 256 WGs =
// exactly 1/CU -> zero tail (vs QKV's 384/256). 8 phases of 8 MFMA per iter
// (2 K-tiles). Pieces per tile: {A-lo, A-hi, B} (2 loads/thread each).
//
// Stage schedule (iter i: t0=2i buf0 ph0-3, t1=2i+1 buf1 ph4-7):
//   ph0: B(t1)            [buf1 B dead since ph6 prev]
//   ph3: A-lo,A-hi(tn0); vmcnt(4) confirms {A(t1) from prev ph7, B(t1)}
//   ph4: B(tn0)           [buf0 B dead since ph2]
//   ph7: A-lo,A-hi(tn1); vmcnt(4) confirms {A(tn0), B(tn0)}
// Leads: A 4-5 phases, B 3-4 phases. Last iter: ph3 -> vmcnt(0), no stages.
// ---------------------------------------------------------------------------
#define STAGE_Ab(buf, h, t)                                                  \
  do {                                                                       \
    gld16(&sA[buf][((h) * 1024 + w * 64) * 8],                               \
          gA0 + (size_t)(h) * 128 * K + (size_t)(t) * 64);                   \
    gld16(&sA[buf][((h) * 1024 + 512 + w * 64) * 8],                         \
          gA1 + (size_t)(h) * 128 * K + (size_t)(t) * 64);                   \
  } while (0)

#define STAGE_Bb(buf, t)                                                     \
  do {                                                                       \
    gld16(&sB[buf][(w * 64) * 8], gB0 + (size_t)(t) * 64);                   \
    gld16(&sB[buf][(512 + w * 64) * 8], gB1 + (size_t)(t) * 64);             \
  } while (0)

// A frags for phase (mh2, kk): mi = mh2*2 + {0,1}; rows wr*64 + mi*16 + l16
#define LDA2b(buf, mh2, kk)                                                  \
  do {                                                                       \
    const int cc_ = ((kk) * 4 + quad) ^ (l16 & 7);                           \
    _Pragma("unroll") for (int i_ = 0; i_ < 2; ++i_) {                       \
      const int rr_ = wr * 64 + ((mh2) * 2 + i_) * 16 + l16;                 \
      a_[i_] = ds_read16(lds_addr(&sA[buf][rr_ * 64 + cc_ * 8]));            \
    }                                                                        \
  } while (0)

#define LDB4b(buf, kk)                                                       \
  do {                                                                       \
    const int cc_ = ((kk) * 4 + quad) ^ (l16 & 7);                           \
    _Pragma("unroll") for (int i_ = 0; i_ < 4; ++i_) {                       \
      const int rr_ = wc * 64 + i_ * 16 + l16;                               \
      b_[i_] = ds_read16(lds_addr(&sB[buf][rr_ * 64 + cc_ * 8]));            \
    }                                                                        \
  } while (0)

#define MM8b(mh2)                                                            \
  do {                                                                       \
    __builtin_amdgcn_s_setprio(1);                                           \
    _Pragma("unroll") for (int i_ = 0; i_ < 2; ++i_)                         \
    _Pragma("unroll") for (int n_ = 0; n_ < 4; ++n_)                         \
        acc[(mh2) * 2 + i_][n_] = __builtin_amdgcn_mfma_f32_16x16x32_bf16(   \
            a_[i_], b_[n_], acc[(mh2) * 2 + i_][n_], 0, 0, 0);               \
    __builtin_amdgcn_s_setprio(0);                                           \
  } while (0)

template <int OUT_BF16>
__global__ __launch_bounds__(512, 2) void gemm_bt8b(
    const unsigned short* __restrict__ A, const unsigned short* __restrict__ BT,
    const float* __restrict__ bias, void* __restrict__ Cout,
    int M, int N, int K) {
  __shared__ __align__(16) unsigned short sA[2][256 * 64];
  __shared__ __align__(16) unsigned short sB[2][128 * 64];
  (void)M;

  const int tid = threadIdx.x, w = tid >> 6, lane = tid & 63;
  const int quad = lane >> 4, l16 = lane & 15;
  const int wr = w >> 1, wc = w & 1;   // wave -> (4M x 2N) grid; 64x64 out

  // bijective XCD-aware block swizzle
  const int nwgx = gridDim.x;
  const int nwg = nwgx * gridDim.y;
  const int wg = blockIdx.y * nwgx + blockIdx.x;
  const int q8 = nwg >> 3, r8 = nwg & 7;
  const int xcd = wg & 7, loc = wg >> 3;
  const int swz =
      (xcd < r8 ? xcd * (q8 + 1) : r8 * (q8 + 1) + (xcd - r8) * q8) + loc;
  const int m0 = (swz / nwgx) * 256;
  const int n0 = (swz % nwgx) * 128;

  const int c0 = tid, c1 = tid + 512;
  const int r0c = c0 >> 3, s0c = (c0 & 7) ^ (r0c & 7);
  const int r1c = c1 >> 3, s1c = (c1 & 7) ^ (r1c & 7);
  const unsigned short* gA0 = A + (size_t)(m0 + r0c) * K + s0c * 8;
  const unsigned short* gA1 = A + (size_t)(m0 + r1c) * K + s1c * 8;
  const unsigned short* gB0 = BT + (size_t)(n0 + r0c) * K + s0c * 8;
  const unsigned short* gB1 = BT + (size_t)(n0 + r1c) * K + s1c * 8;

  f32x4 acc[4][4] = {};
  bf16x8 a_[2], b_[4];

  const int NT = K >> 6;
  const int NI = NT >> 1;

  // prologue: t0 full -> buf0 (6 loads); t1 A -> buf1 (4); confirm t0.
  STAGE_Ab(0, 0, 0); STAGE_Ab(0, 1, 0); STAGE_Bb(0, 0);
  STAGE_Ab(1, 0, 1); STAGE_Ab(1, 1, 1);
  WAIT_VM4;
  BARRIER8;

  for (int i = 0; i < NI; ++i) {
    const int t1 = 2 * i + 1;
    const int tn0 = 2 * i + 2, tn1 = 2 * i + 3;
    const bool last = (i == NI - 1);

    // ph0: buf0 kk0 mi01 | stage B(t1)
    LDB4b(0, 0); LDA2b(0, 0, 0);
    if (!last) STAGE_Bb(1, t1); else STAGE_Bb(1, t1);
    BARRIER8; WAIT_LGKM0; SCHED0; MM8b(0); BARRIER8;

    // ph1: buf0 kk0 mi23
    LDA2b(0, 1, 0);
    BARRIER8; WAIT_LGKM0; SCHED0; MM8b(1); BARRIER8;

    // ph2: buf0 kk1 mi01
    LDB4b(0, 1); LDA2b(0, 0, 1);
    BARRIER8; WAIT_LGKM0; SCHED0; MM8b(0); BARRIER8;

    // ph3: buf0 kk1 mi23 | stage A(tn0) | confirm t1 {A,B}
    LDA2b(0, 1, 1);
    if (!last) {
      STAGE_Ab(0, 0, tn0); STAGE_Ab(0, 1, tn0);
      WAIT_VM4;
    } else {
      WAIT_VM0;
    }
    BARRIER8; WAIT_LGKM0; SCHED0; MM8b(1); BARRIER8;

    // ph4: buf1 kk0 mi01 | stage B(tn0)
    LDB4b(1, 0); LDA2b(1, 0, 0);
    if (!last) STAGE_Bb(0, tn0);
    BARRIER8; WAIT_LGKM0; SCHED0; MM8b(0); BARRIER8;

    // ph5: buf1 kk0 mi23
    LDA2b(1, 1, 0);
    BARRIER8; WAIT_LGKM0; SCHED0; MM8b(1); BARRIER8;

    // ph6: buf1 kk1 mi01
    LDB4b(1, 1); LDA2b(1, 0, 1);
    BARRIER8; WAIT_LGKM0; SCHED0; MM8b(0); BARRIER8;

    // ph7: buf1 kk1 mi23 | stage A(tn1) | confirm tn0 {A,B}
    LDA2b(1, 1, 1);
    if (!last) {
      STAGE_Ab(1, 0, tn1); STAGE_Ab(1, 1, tn1);
      WAIT_VM4;
    }
    BARRIER8; WAIT_LGKM0; SCHED0; MM8b(1); BARRIER8;
  }

  // epilogue
#pragma unroll
  for (int mi = 0; mi < 4; ++mi) {
    int row = m0 + wr * 64 + mi * 16 + quad * 4;
#pragma unroll
    for (int ni = 0; ni < 4; ++ni) {
      int col = n0 + wc * 64 + ni * 16 + l16;
      float bv = bias[col];
#pragma unroll
      for (int rr = 0; rr < 4; ++rr) {
        float v = acc[mi][ni][rr] + bv;
        if (OUT_BF16)
          ((unsigned short*)Cout)[(size_t)(row + rr) * N + col] = f2bf(v);
        else
          ((float*)Cout)[(size_t)(row + rr) * N + col] = v;
      }
    }
  }
}

#undef STAGE_Ab
#undef STAGE_Bb
#undef LDA2b
#undef LDB4b
#undef MM8b

// ---------------------------------------------------------------------------
// Flash attention (causal), S^T formulation. R5: defer-max (T13, THR=8 in
// log2 domain -> P bounded by 2^8, bf16-safe) skips the O-rescale + alpha
// broadcasts on tiles where no q-col's max grew; PV is 2-deep
// counted-lgkmcnt pipelined (DS ops retire in order).
// ---------------------------------------------------------------------------
__global__ __launch_bounds__(256) void flash_attn(
    const unsigned short* __restrict__ qkv, const unsigned short* __restrict__ vT,
    unsigned short* __restrict__ yout) {
  __shared__ __align__(16) unsigned short sK[2][64 * 128];    // [t_k][d], swizzle &15
  __shared__ __align__(16) unsigned short sVT[2][128 * 64];   // [d][t_k], swizzle &7
  __shared__ __align__(16) unsigned short sP[4 * 16 * 64];    // per-wave P[q][k], chunk swizzle &7

  const int tid = threadIdx.x, w = tid >> 6, lane = tid & 63;
  const int quad = lane >> 4, l16 = lane & 15;
  const int id = blockIdx.x;
  const int g = id & 31;           // (b,h) group -> XCD g%8
  const int qp = id >> 5;          // 0..15
  const int b = g >> 4, h = g & 15;
  const int T = 2048, CC = 6144, HD = 128;
  const float qscale = 0.12753257252f;  // (1/sqrt(128)) * log2(e)

  const unsigned short* gK = qkv + (size_t)(b * T) * CC + 2048 + h * HD;
  const unsigned short* gV = vT + (size_t)(b * 16 + h) * HD * T;
  unsigned short* pw = sP + w * 16 * 64;

  const unsigned short* kSrc[4];
  const unsigned short* vSrc[4];
  unsigned short* kDst[4];
  unsigned short* vDst[4];
#pragma unroll
  for (int i = 0; i < 4; i++) {
    int c = w * 256 + i * 64 + lane;
    int kR = c >> 4, kC = (c & 15) ^ (kR & 15);
    int vR = c >> 3, vC = (c & 7) ^ (vR & 7);
    kSrc[i] = gK + (size_t)kR * CC + kC * 8;
    vSrc[i] = gV + (size_t)vR * T + vC * 8;
    kDst[i] = (unsigned short*)sK + (size_t)(w * 256 + i * 64) * 8;
    vDst[i] = (unsigned short*)sVT + (size_t)(w * 256 + i * 64) * 8;
  }
  const int KBUF = 64 * 128, VBUF = 128 * 64;

  const int qtA = qp, qtB = 31 - qp;
  int qt = qtA, kt = 0;

  bf16x8 qf[4];
  float m_old, l_sum;
  f32x4 o[8] = {};
  {
    const size_t qrow = (size_t)(b * T + qt * 64 + w * 16 + l16) * CC + h * HD;
#pragma unroll
    for (int kb = 0; kb < 4; kb++) {
      bf16x8 raw = *(const bf16x8*)&qkv[qrow + kb * 32 + quad * 8];
      bf16x8 sc;
#pragma unroll
      for (int j = 0; j < 8; j++) sc[j] = (__bf16)((float)raw[j] * qscale);
      qf[kb] = sc;
    }
  }
  m_old = -1e30f; l_sum = 0.f;

#pragma unroll
  for (int i = 0; i < 4; i++) {
    gld16(kDst[i], kSrc[i]);
    gld16(vDst[i], vSrc[i]);
  }

  const int total = qtA + qtB + 2;   // = 33
  for (int it = 0; it < total; ++it) {
    __syncthreads();                 // buf[it&1] staged (vmcnt drained here)
    const int cur = it & 1;
    const bool segEnd = (kt == qt);

    // prefetch next tile into the other buffer (overlapped)
    if (it + 1 < total) {
      const int nkt = segEnd ? 0 : kt + 1;
      const int nb_ = (it + 1) & 1;
      const size_t kOff = (size_t)nkt * 64 * CC;
      const int vOff = nkt * 64;
#pragma unroll
      for (int i = 0; i < 4; i++) {
        gld16(kDst[i] + (size_t)nb_ * KBUF, kSrc[i] + kOff);
        gld16(vDst[i] + (size_t)nb_ * VBUF, vSrc[i] + vOff);
      }
    }

    const unsigned short* sKc = (const unsigned short*)sK + (size_t)cur * KBUF;
    const unsigned short* sVc = (const unsigned short*)sVT + (size_t)cur * VBUF;

    // S^T = K Q^T, 2-deep lgkm-pipelined over dc (K-frag column blocks)
    f32x4 s4[4] = {};
    bf16x8 kf[4], kg[4];
#pragma unroll
    for (int kb = 0; kb < 4; kb++) {
      int rr = kb * 16 + l16;
      int cc = quad ^ l16;   // dc = 0
      kf[kb] = ds_read16(lds_addr(&sKc[rr * 128 + cc * 8]));
    }
#pragma unroll
    for (int dc = 0; dc < 4; dc++) {
      if (dc < 3) {
#pragma unroll
        for (int kb = 0; kb < 4; kb++) {
          int rr = kb * 16 + l16;
          int cc = ((dc + 1) * 4 + quad) ^ l16;
          kg[kb] = ds_read16(lds_addr(&sKc[rr * 128 + cc * 8]));
        }
        WAIT_LGKM4;
      } else {
        WAIT_LGKM0;
      }
      SCHED0;
      __builtin_amdgcn_s_setprio(1);
#pragma unroll
      for (int kb = 0; kb < 4; kb++)
        s4[kb] = __builtin_amdgcn_mfma_f32_16x16x32_bf16(kf[kb], qf[dc], s4[kb], 0, 0, 0);
      __builtin_amdgcn_s_setprio(0);
      if (dc < 3) {
#pragma unroll
        for (int kb = 0; kb < 4; kb++) kf[kb] = kg[kb];
      }
    }

    // causal mask (diagonal tile only): k_local > q_local
    float sv[4][4];
#pragma unroll
    for (int kb = 0; kb < 4; kb++)
#pragma unroll
      for (int r = 0; r < 4; r++) {
        float v = s4[kb][r];
        if (segEnd) {
          if (kb * 16 + quad * 4 + r > w * 16 + l16) v = -1e30f;
        }
        sv[kb][r] = v;
      }

    // online softmax with defer-max (T13): skip O-rescale when no growth > 8
    float mx = sv[0][0];
#pragma unroll
    for (int kb = 0; kb < 4; kb++)
#pragma unroll
      for (int r = 0; r < 4; r++) mx = fmaxf(mx, sv[kb][r]);
    mx = fmaxf(mx, __shfl_xor(mx, 16));
    mx = fmaxf(mx, __shfl_xor(mx, 32));
    float m_new = fmaxf(m_old, mx);
    const bool nogrow = (__all(mx <= m_old + 8.0f) != 0);
    if (nogrow) m_new = m_old;
    float ssum = 0.f;
#pragma unroll
    for (int kb = 0; kb < 4; kb++)
#pragma unroll
      for (int r = 0; r < 4; r++) {
        float p = exp2f(sv[kb][r] - m_new);
        sv[kb][r] = p;
        ssum += p;
      }
    ssum += __shfl_xor(ssum, 16);
    ssum += __shfl_xor(ssum, 32);
    if (nogrow) {
      l_sum += ssum;
    } else {
      float a = exp2f(m_old - m_new);
      float ar[4];
#pragma unroll
      for (int r = 0; r < 4; r++)
        ar[r] = __shfl(a, (lane & 48) + quad * 4 + r);
#pragma unroll
      for (int nb = 0; nb < 8; nb++)
#pragma unroll
        for (int r = 0; r < 4; r++) o[nb][r] *= ar[r];
      l_sum = l_sum * a + ssum;
    }
    m_old = m_new;

    // P store: 4x ds_write_b64 (asm) into per-wave P[q][k]
#pragma unroll
    for (int kb = 0; kb < 4; kb++) {
      u16x4 pk;
#pragma unroll
      for (int r = 0; r < 4; r++) pk[r] = f2bf(sv[kb][r]);
      int c = kb * 2 + (quad >> 1);
      int cp = c ^ (l16 & 7);
      ds_write8(lds_addr(&pw[l16 * 64 + cp * 8 + (quad & 1) * 4]), pk);
    }
    WAIT_LGKM0;   // P writes complete (per-wave region; no barrier needed)
    SCHED0;

    // O += P V, 2-deep counted-lgkmcnt pipeline (DS retires in order)
    {
      const int x7 = l16 & 7;
      const int ccP0 = quad ^ x7, ccP1 = (4 + quad) ^ x7;
      bf16x8 pf0, pf1, vA[4], vB[4];
      pf0 = ds_read16(lds_addr(&pw[l16 * 64 + ccP0 * 8]));
#pragma unroll
      for (int j = 0; j < 4; j++) {
        int rr = j * 16 + l16;
        vA[j] = ds_read16(lds_addr(&sVc[rr * 64 + ccP0 * 8]));
      }
#pragma unroll
      for (int j = 0; j < 4; j++) {
        int rr = (4 + j) * 16 + l16;
        vB[j] = ds_read16(lds_addr(&sVc[rr * 64 + ccP0 * 8]));
      }
      WAIT_LGKM4; SCHED0;           // pf0+vA done; vB(4) in flight
      __builtin_amdgcn_s_setprio(1);
#pragma unroll
      for (int j = 0; j < 4; j++)
        o[j] = __builtin_amdgcn_mfma_f32_16x16x32_bf16(pf0, vA[j], o[j], 0, 0, 0);
      __builtin_amdgcn_s_setprio(0);
      pf1 = ds_read16(lds_addr(&pw[l16 * 64 + ccP1 * 8]));
#pragma unroll
      for (int j = 0; j < 4; j++) {
        int rr = j * 16 + l16;
        vA[j] = ds_read16(lds_addr(&sVc[rr * 64 + ccP1 * 8]));
      }
      WAIT_LGKM5; SCHED0;           // vB done; pf1+vA(5) in flight
      __builtin_amdgcn_s_setprio(1);
#pragma unroll
      for (int j = 0; j < 4; j++)
        o[4 + j] = __builtin_amdgcn_mfma_f32_16x16x32_bf16(pf0, vB[j], o[4 + j], 0, 0, 0);
      __builtin_amdgcn_s_setprio(0);
#pragma unroll
      for (int j = 0; j < 4; j++) {
        int rr = (4 + j) * 16 + l16;
        vB[j] = ds_read16(lds_addr(&sVc[rr * 64 + ccP1 * 8]));
      }
      WAIT_LGKM4; SCHED0;           // pf1+vA done; vB(4) in flight
      __builtin_amdgcn_s_setprio(1);
#pragma unroll
      for (int j = 0; j < 4; j++)
        o[j] = __builtin_amdgcn_mfma_f32_16x16x32_bf16(pf1, vA[j], o[j], 0, 0, 0);
      __builtin_amdgcn_s_setprio(0);
      WAIT_LGKM0; SCHED0;
      __builtin_amdgcn_s_setprio(1);
#pragma unroll
      for (int j = 0; j < 4; j++)
        o[4 + j] = __builtin_amdgcn_mfma_f32_16x16x32_bf16(pf1, vB[j], o[4 + j], 0, 0, 0);
      __builtin_amdgcn_s_setprio(0);
    }

    if (segEnd) {
      // epilogue: inv l_sum broadcast like alpha; O rows q = quad*4+r
      float linv = 1.0f / l_sum;
#pragma unroll
      for (int r = 0; r < 4; r++) {
        float ir = __shfl(linv, (lane & 48) + quad * 4 + r);
        size_t orow = (size_t)(b * T + qt * 64 + w * 16 + quad * 4 + r) * 2048 + h * HD;
#pragma unroll
        for (int nb = 0; nb < 8; nb++)
          yout[orow + nb * 16 + l16] = f2bf(o[nb][r] * ir);
      }
      if (it + 1 < total) {
        qt = qtB;
        const size_t qrow = (size_t)(b * T + qt * 64 + w * 16 + l16) * CC + h * HD;
#pragma unroll
        for (int kb = 0; kb < 4; kb++) {
          bf16x8 raw = *(const bf16x8*)&qkv[qrow + kb * 32 + quad * 8];
          bf16x8 sc;
#pragma unroll
          for (int j = 0; j < 8; j++) sc[j] = (__bf16)((float)raw[j] * qscale);
          qf[kb] = sc;
        }
        m_old = -1e30f; l_sum = 0.f;
#pragma unroll
        for (int nb = 0; nb < 8; nb++) o[nb] = (f32x4){0.f, 0.f, 0.f, 0.f};
      }
      kt = 0;
    } else {
      kt++;
    }
  }
}

// ---------------------------------------------------------------------------
extern "C" void kernel_launch(void* const* d_in, const int* in_sizes, int n_in,
                              void* d_out, int out_size, void* d_ws, size_t ws_size,
                              hipStream_t stream) {
  const float* x      = (const float*)d_in[0];   // (2,2048,2048)
  const float* W_attn = (const float*)d_in[1];   // (2048,6144)
  const float* b_attn = (const float*)d_in[2];   // (6144,)
  const float* W_proj = (const float*)d_in[3];   // (2048,2048)
  const float* b_proj = (const float*)d_in[4];   // (2048,)
  float* out = (float*)d_out;                    // (2,2048,2048) fp32

  char* ws = (char*)d_ws;
  unsigned short* x_bf  = (unsigned short*)(ws);              // 16 MiB
  unsigned short* WaT   = (unsigned short*)(ws + 16777216);   // 24 MiB
  unsigned short* WpT   = (unsigned short*)(ws + 41943040);   // 8 MiB
  unsigned short* qkv   = (unsigned short*)(ws + 50331648);   // 48 MiB
  unsigned short* vT    = (unsigned short*)(ws + 100663296);  // 16 MiB
  unsigned short* y_att = (unsigned short*)(ws + 117440512);  // 16 MiB
  // total 128 MiB

  cvt_f32_bf16_k<<<1024, 256, 0, stream>>>(x, x_bf, 8388608 / 4);
  transpose_f32_bf16<<<dim3(96, 32), 256, 0, stream>>>(W_attn, WaT, 2048, 6144);
  transpose_f32_bf16<<<dim3(32, 32), 256, 0, stream>>>(W_proj, WpT, 2048, 2048);
  // QKV GEMM: 256^2 8-phase, grid 24x16 = 384 WGs
  gemm_bt8<1><<<dim3(24, 16), 512, 0, stream>>>(x_bf, WaT, b_attn, qkv, 4096, 6144, 2048);
  extract_vT_k<<<dim3(32, 2, 32), 256, 0, stream>>>(qkv, vT);
  flash_attn<<<dim3(512), 256, 0, stream>>>(qkv, vT, y_att);
  // proj GEMM: 256x128 8-phase, grid 16x16 = 256 WGs = 1/CU (zero tail)
  gemm_bt8b<0><<<dim3(16, 16), 512, 0, stream>>>(y_att, WpT, b_proj, out, 4096, 2048, 2048);
}

// Round 6
// 369.899 us; speedup vs baseline: 1.1433x; 1.0127x over previous
//
#include <hip/hip_runtime.h>
#include <cstdint>
#include <cstddef>

// ---------------------------------------------------------------------------
// CausalSelfAttention: y = proj(softmax_causal(QK^T/sqrt(HD)) V), QKV = x@W_attn+b
// B=2 T=2048 C=2048 H=16 HD=128. All I/O fp32; internal compute bf16 MFMA.
// ---------------------------------------------------------------------------

typedef __bf16 bf16x8 __attribute__((ext_vector_type(8)));
typedef float  f32x4  __attribute__((ext_vector_type(4)));
typedef unsigned short u16x4 __attribute__((ext_vector_type(4)));
typedef unsigned short u16x8 __attribute__((ext_vector_type(8)));

__device__ __forceinline__ unsigned short f2bf(float f) {
  unsigned int u = __builtin_bit_cast(unsigned int, f);
  u += 0x7fffu + ((u >> 16) & 1u);       // round-to-nearest-even
  return (unsigned short)(u >> 16);
}

__device__ __forceinline__ void gld16(void* lds, const void* g) {
  // async global->LDS, 16B per lane; LDS dest is wave-uniform base + lane*16
  __builtin_amdgcn_global_load_lds(
      (const __attribute__((address_space(1))) void*)g,
      (__attribute__((address_space(3))) void*)lds, 16, 0, 0);
}

// 32-bit LDS byte address from a generic __shared__ pointer
__device__ __forceinline__ unsigned lds_addr(const void* p) {
  return (unsigned)(size_t)(const __attribute__((address_space(3))) void*)p;
}

// inline-asm ds_read_b128: opaque to SIInsertWaitcnts, so no compiler-inserted
// vmcnt drain vs outstanding global_load_lds. Caller MUST pair with manual
// s_waitcnt lgkmcnt(N) + sched_barrier(0) before consuming (rule #18).
__device__ __forceinline__ bf16x8 ds_read16(unsigned addr) {
  bf16x8 r;
  asm volatile("ds_read_b128 %0, %1" : "=v"(r) : "v"(addr));
  return r;
}

// inline-asm ds_write_b64 (same rationale)
__device__ __forceinline__ void ds_write8(unsigned addr, u16x4 d) {
  unsigned long long v = __builtin_bit_cast(unsigned long long, d);
  asm volatile("ds_write_b64 %0, %1" :: "v"(addr), "v"(v));
}

// ---------------------------------------------------------------------------
// Fused preprocessing: one launch replaces {cvt_f32_bf16, transpose(W_attn),
// transpose(W_proj)} -- saves 2 kernel launches' overhead + drain gaps.
// Block ranges: [0,3072) trA tiles, [3072,4096) trP tiles, [4096,5120) cvt.
// ---------------------------------------------------------------------------
__device__ __forceinline__ void transpose_tile_64(
    const float* __restrict__ in, unsigned short* __restrict__ out,
    int R, int C, int c0, int r0, int t, float tile[64][65]) {
  int lr = t >> 4, lc = (t & 15) * 4;
#pragma unroll
  for (int i = 0; i < 4; i++) {
    int row = lr + i * 16;
    float4 v = *(const float4*)&in[(size_t)(r0 + row) * C + c0 + lc];
    tile[row][lc] = v.x; tile[row][lc + 1] = v.y;
    tile[row][lc + 2] = v.z; tile[row][lc + 3] = v.w;
  }
  __syncthreads();
  int wr = t >> 3, wc = (t & 7) * 8;
#pragma unroll
  for (int i = 0; i < 2; i++) {
    int crow = wr + i * 32;
    u16x8 o;
#pragma unroll
    for (int j = 0; j < 8; j++) o[j] = f2bf(tile[wc + j][crow]);
    *(u16x8*)&out[(size_t)(c0 + crow) * R + r0 + wc] = o;
  }
}

__global__ __launch_bounds__(256) void prep_k(
    const float* __restrict__ x, const float* __restrict__ W_attn,
    const float* __restrict__ W_proj, unsigned short* __restrict__ x_bf,
    unsigned short* __restrict__ WaT, unsigned short* __restrict__ WpT) {
  __shared__ float tile[64][65];
  const int bid = blockIdx.x, t = threadIdx.x;
  if (bid < 3072) {
    // W_attn (2048,6144) -> WaT (6144,2048): 96 x 32 tiles
    int bx = bid % 96, by = bid / 96;
    transpose_tile_64(W_attn, WaT, 2048, 6144, bx * 64, by * 64, t, tile);
  } else if (bid < 4096) {
    // W_proj (2048,2048) -> WpT: 32 x 32 tiles
    int id = bid - 3072, bx = id & 31, by = id >> 5;
    transpose_tile_64(W_proj, WpT, 2048, 2048, bx * 64, by * 64, t, tile);
  } else {
    // x fp32 -> bf16, grid-stride over 2M float4
    const int n4 = 8388608 / 4;
    int i = (bid - 4096) * 256 + t;
    for (; i < n4; i += 1024 * 256) {
      float4 v = ((const float4*)x)[i];
      ushort4 o;
      o.x = f2bf(v.x); o.y = f2bf(v.y); o.z = f2bf(v.z); o.w = f2bf(v.w);
      ((ushort4*)x_bf)[i] = o;
    }
  }
}

// ---------------------------------------------------------------------------
// extract V^T (B,H,HD,T) bf16 from qkv (B*T, 3C) bf16. 64t x 64d tile.
// ---------------------------------------------------------------------------
__global__ __launch_bounds__(256) void extract_vT_k(
    const unsigned short* __restrict__ qkv, unsigned short* __restrict__ vT) {
  __shared__ unsigned int tile32[64][33];   // [d][t&31] packs (t, t+32)
  int bh = blockIdx.z, b = bh >> 4, h = bh & 15;
  int t0 = blockIdx.x * 64, d0 = blockIdx.y * 64;
  int t = threadIdx.x;
  int lr = t >> 3, lc = (t & 7) * 8;
  const unsigned short* src = qkv + (size_t)(b * 2048) * 6144 + 4096 + h * 128;
#pragma unroll
  for (int i = 0; i < 2; i++) {
    int row = lr + i * 32;
    u16x8 v = *(const u16x8*)&src[(size_t)(t0 + row) * 6144 + d0 + lc];
#pragma unroll
    for (int j = 0; j < 8; j++) {
      unsigned short* p = (unsigned short*)&tile32[lc + j][row & 31];
      p[row >> 5] = v[j];
    }
  }
  __syncthreads();
  int dr = t >> 2, tc = (t & 3) * 8;
  u16x8 lo, hi;
#pragma unroll
  for (int j = 0; j < 8; j++) {
    unsigned int u = tile32[dr][tc + j];
    lo[j] = (unsigned short)(u & 0xffffu);
    hi[j] = (unsigned short)(u >> 16);
  }
  unsigned short* dst = vT + (size_t)bh * 128 * 2048 + (size_t)(d0 + dr) * 2048 + t0;
  *(u16x8*)&dst[tc] = lo;
  *(u16x8*)&dst[tc + 32] = hi;
}

// ---------------------------------------------------------------------------
// GEMM (legacy 128x128, BK=64, 4 waves, 88 VGPR -> ~3 blocks/CU): restored for
// the proj GEMM. R5's gemm_bt8b (8 MFMA/phase) halved MFMA-per-barrier density
// and ran ~80us; this one is ~45-55us at 512 WGs = 2/CU exact.
// ---------------------------------------------------------------------------
template <int OUT_BF16>
__global__ __launch_bounds__(256) void gemm_bt(
    const unsigned short* __restrict__ A, const unsigned short* __restrict__ BT,
    const float* __restrict__ bias, void* __restrict__ Cout,
    int M, int N, int K) {
  __shared__ __align__(16) unsigned short sA[128 * 64];
  __shared__ __align__(16) unsigned short sB[128 * 64];

  const int tid = threadIdx.x, w = tid >> 6, lane = tid & 63;
  const int quad = lane >> 4, l16 = lane & 15;
  const int m0 = blockIdx.y * 128, n0 = blockIdx.x * 128;
  const int wr = w >> 1, wc = w & 1;

  const unsigned short* gA[4];
  const unsigned short* gB[4];
  unsigned short* lA[4];
  unsigned short* lB[4];
#pragma unroll
  for (int i = 0; i < 4; i++) {
    int c = w * 256 + i * 64 + lane;
    int row = c >> 3, scol = (c & 7) ^ (row & 7);
    gA[i] = A + (size_t)(m0 + row) * K + scol * 8;
    gB[i] = BT + (size_t)(n0 + row) * K + scol * 8;
    lA[i] = sA + (size_t)(w * 256 + i * 64) * 8;
    lB[i] = sB + (size_t)(w * 256 + i * 64) * 8;
  }

  f32x4 acc[4][4] = {};

  for (int k0 = 0; k0 < K; k0 += 64) {
#pragma unroll
    for (int i = 0; i < 4; i++) {
      gld16(lA[i], gA[i]); gld16(lB[i], gB[i]);
      gA[i] += 64; gB[i] += 64;
    }
    __syncthreads();

#pragma unroll
    for (int kk = 0; kk < 2; kk++) {
      const int cc = (kk * 4 + quad) ^ (l16 & 7);
      bf16x8 af[4], bfr[4];
#pragma unroll
      for (int mi = 0; mi < 4; mi++)
        af[mi] = *(const bf16x8*)&sA[(wr * 64 + mi * 16 + l16) * 64 + cc * 8];
#pragma unroll
      for (int ni = 0; ni < 4; ni++)
        bfr[ni] = *(const bf16x8*)&sB[(wc * 64 + ni * 16 + l16) * 64 + cc * 8];
#pragma unroll
      for (int mi = 0; mi < 4; mi++)
#pragma unroll
        for (int ni = 0; ni < 4; ni++)
          acc[mi][ni] = __builtin_amdgcn_mfma_f32_16x16x32_bf16(
              af[mi], bfr[ni], acc[mi][ni], 0, 0, 0);
    }
    __syncthreads();
  }

#pragma unroll
  for (int mi = 0; mi < 4; mi++) {
    int row = m0 + wr * 64 + mi * 16 + quad * 4;
#pragma unroll
    for (int ni = 0; ni < 4; ni++) {
      int col = n0 + wc * 64 + ni * 16 + l16;
      float bv = bias[col];
#pragma unroll
      for (int r = 0; r < 4; r++) {
        float v = acc[mi][ni][r] + bv;
        if (OUT_BF16)
          ((unsigned short*)Cout)[(size_t)(row + r) * N + col] = f2bf(v);
        else
          ((float*)Cout)[(size_t)(row + r) * N + col] = v;
      }
    }
  }
}

// ---------------------------------------------------------------------------
// Shared sync/wait macros for the 8-phase GEMM and flash
// ---------------------------------------------------------------------------
#define BARRIER8 __builtin_amdgcn_s_barrier()
#define WAIT_LGKM0 asm volatile("s_waitcnt lgkmcnt(0)" ::: "memory")
#define WAIT_LGKM4 asm volatile("s_waitcnt lgkmcnt(4)" ::: "memory")
#define WAIT_LGKM5 asm volatile("s_waitcnt lgkmcnt(5)" ::: "memory")
#define SCHED0 __builtin_amdgcn_sched_barrier(0)
#define WAIT_VM4 asm volatile("s_waitcnt vmcnt(4)" ::: "memory")
#define WAIT_VM0 asm volatile("s_waitcnt vmcnt(0)" ::: "memory")

// ---------------------------------------------------------------------------
// GEMM 256x256 8-phase (QKV). BK=64, 8 waves (2Mx4N), 512 threads, 128 KiB LDS.
// asm ds_read + deep staging lead + counted vmcnt(4) at ph3/ph7 (R3 version).
// ---------------------------------------------------------------------------
#define STAGE_A(buf, h, t)                                                   \
  do {                                                                       \
    gld16(&sA[buf][((h) * 1024 + w * 64) * 8],                               \
          gA0 + (size_t)(h) * 128 * K + (size_t)(t) * 64);                   \
    gld16(&sA[buf][((h) * 1024 + 512 + w * 64) * 8],                         \
          gA1 + (size_t)(h) * 128 * K + (size_t)(t) * 64);                   \
  } while (0)

#define STAGE_B(buf, h, t)                                                   \
  do {                                                                       \
    gld16(&sB[buf][((h) * 1024 + w * 64) * 8],                               \
          gB0 + (size_t)(h) * 128 * K + (size_t)(t) * 64);                   \
    gld16(&sB[buf][((h) * 1024 + 512 + w * 64) * 8],                         \
          gB1 + (size_t)(h) * 128 * K + (size_t)(t) * 64);                   \
  } while (0)

// A sub-tile for phase (mh, kk): rows mh*128 + wr*64 + [0,64) -> only half mh
#define LDA4(buf, mh, kk)                                                    \
  do {                                                                       \
    const int cc_ = ((kk) * 4 + quad) ^ (l16 & 7);                           \
    _Pragma("unroll") for (int i_ = 0; i_ < 4; ++i_) {                       \
      const int rr_ = (mh) * 128 + wr * 64 + i_ * 16 + l16;                  \
      a_[i_] = ds_read16(lds_addr(&sA[buf][rr_ * 64 + cc_ * 8]));            \
    }                                                                        \
  } while (0)

#define LDB4(buf, kk)                                                        \
  do {                                                                       \
    const int cc_ = ((kk) * 4 + quad) ^ (l16 & 7);                           \
    _Pragma("unroll") for (int i_ = 0; i_ < 4; ++i_) {                       \
      const int rr_ = wc * 64 + i_ * 16 + l16;                               \
      b_[i_] = ds_read16(lds_addr(&sB[buf][rr_ * 64 + cc_ * 8]));            \
    }                                                                        \
  } while (0)

#define MM16(mh)                                                             \
  do {                                                                       \
    __builtin_amdgcn_s_setprio(1);                                           \
    _Pragma("unroll") for (int i_ = 0; i_ < 4; ++i_)                         \
    _Pragma("unroll") for (int n_ = 0; n_ < 4; ++n_)                         \
        acc[(mh) * 4 + i_][n_] = __builtin_amdgcn_mfma_f32_16x16x32_bf16(    \
            a_[i_], b_[n_], acc[(mh) * 4 + i_][n_], 0, 0, 0);                \
    __builtin_amdgcn_s_setprio(0);                                           \
  } while (0)

template <int OUT_BF16>
__global__ __launch_bounds__(512, 2) void gemm_bt8(
    const unsigned short* __restrict__ A, const unsigned short* __restrict__ BT,
    const float* __restrict__ bias, void* __restrict__ Cout,
    int M, int N, int K) {
  __shared__ __align__(16) unsigned short sA[2][256 * 64];
  __shared__ __align__(16) unsigned short sB[2][256 * 64];
  (void)M;

  const int tid = threadIdx.x, w = tid >> 6, lane = tid & 63;
  const int quad = lane >> 4, l16 = lane & 15;
  const int wr = w >> 2, wc = w & 3;   // wave -> (2M x 4N) grid

  // bijective XCD-aware block swizzle (m204 variant)
  const int nwgx = gridDim.x;
  const int nwg = nwgx * gridDim.y;
  const int wg = blockIdx.y * nwgx + blockIdx.x;
  const int q8 = nwg >> 3, r8 = nwg & 7;
  const int xcd = wg & 7, loc = wg >> 3;
  const int swz =
      (xcd < r8 ? xcd * (q8 + 1) : r8 * (q8 + 1) + (xcd - r8) * q8) + loc;
  const int m0 = (swz / nwgx) * 256;
  const int n0 = (swz % nwgx) * 256;

  const int c0 = tid, c1 = tid + 512;
  const int r0c = c0 >> 3, s0c = (c0 & 7) ^ (r0c & 7);
  const int r1c = c1 >> 3, s1c = (c1 & 7) ^ (r1c & 7);
  const unsigned short* gA0 = A + (size_t)(m0 + r0c) * K + s0c * 8;
  const unsigned short* gA1 = A + (size_t)(m0 + r1c) * K + s1c * 8;
  const unsigned short* gB0 = BT + (size_t)(n0 + r0c) * K + s0c * 8;
  const unsigned short* gB1 = BT + (size_t)(n0 + r1c) * K + s1c * 8;

  f32x4 acc[8][4] = {};
  bf16x8 a_[4], b_[4];

  const int NT = K >> 6;   // K-tiles (BK=64); must be even
  const int NI = NT >> 1;  // iterations (2 tiles each)

  // prologue: tile0 full -> buf0; tile1 {B-lo,A-lo} -> buf1; confirm tile0.
  STAGE_B(0, 0, 0); STAGE_A(0, 0, 0);
  STAGE_B(0, 1, 0); STAGE_A(0, 1, 0);
  STAGE_B(1, 0, 1); STAGE_A(1, 0, 1);
  WAIT_VM4;
  BARRIER8;

  for (int i = 0; i < NI; ++i) {
    const int t1 = 2 * i + 1;
    const int tn0 = 2 * i + 2, tn1 = 2 * i + 3;
    const bool last = (i == NI - 1);

    // ph0: buf0 (mh0,kk0) | stage t1 B-hi,A-hi
    LDB4(0, 0); LDA4(0, 0, 0);
    STAGE_B(1, 1, t1); STAGE_A(1, 1, t1);
    BARRIER8; WAIT_LGKM0; SCHED0; MM16(0); BARRIER8;

    // ph1: buf0 (mh1,kk0)
    LDA4(0, 1, 0);
    BARRIER8; WAIT_LGKM0; SCHED0; MM16(1); BARRIER8;

    // ph2: buf0 (mh0,kk1)
    LDB4(0, 1); LDA4(0, 0, 1);
    BARRIER8; WAIT_LGKM0; SCHED0; MM16(0); BARRIER8;

    // ph3: buf0 (mh1,kk1) | stage tn0 B-lo,A-lo | confirm buf1 (t1)
    LDA4(0, 1, 1);
    if (!last) {
      STAGE_B(0, 0, tn0); STAGE_A(0, 0, tn0);
      WAIT_VM4;
    } else {
      WAIT_VM0;
    }
    BARRIER8; WAIT_LGKM0; SCHED0; MM16(1); BARRIER8;

    // ph4: buf1 (mh0,kk0) | stage tn0 B-hi,A-hi
    LDB4(1, 0); LDA4(1, 0, 0);
    if (!last) { STAGE_B(0, 1, tn0); STAGE_A(0, 1, tn0); }
    BARRIER8; WAIT_LGKM0; SCHED0; MM16(0); BARRIER8;

    // ph5: buf1 (mh1,kk0)
    LDA4(1, 1, 0);
    BARRIER8; WAIT_LGKM0; SCHED0; MM16(1); BARRIER8;

    // ph6: buf1 (mh0,kk1)
    LDB4(1, 1); LDA4(1, 0, 1);
    BARRIER8; WAIT_LGKM0; SCHED0; MM16(0); BARRIER8;

    // ph7: buf1 (mh1,kk1) | stage tn1 B-lo,A-lo | confirm buf0 (tn0)
    LDA4(1, 1, 1);
    if (!last) {
      STAGE_B(1, 0, tn1); STAGE_A(1, 0, tn1);
      WAIT_VM4;
    }
    BARRIER8; WAIT_LGKM0; SCHED0; MM16(1); BARRIER8;
  }

  // epilogue: C/D layout row = quad*4+reg, col = l16; A-half mh at +mh*128
#pragma unroll
  for (int mi = 0; mi < 8; ++mi) {
    const int mh = mi >> 2, i2 = mi & 3;
    int row = m0 + mh * 128 + wr * 64 + i2 * 16 + quad * 4;
#pragma unroll
    for (int ni = 0; ni < 4; ++ni) {
      int col = n0 + wc * 64 + ni * 16 + l16;
      float bv = bias[col];
#pragma unroll
      for (int rr = 0; rr < 4; ++rr) {
        float v = acc[mi][ni][rr] + bv;
        if (OUT_BF16)
          ((unsigned short*)Cout)[(size_t)(row + rr) * N + col] = f2bf(v);
        else
          ((float*)Cout)[(size_t)(row + rr) * N + col] = v;
      }
    }
  }
}

#undef STAGE_A
#undef STAGE_B
#undef LDA4
#undef LDB4
#undef MM16

// ---------------------------------------------------------------------------
// Flash attention (causal), S^T formulation. (unchanged from R5: asm DS ops,
// 2-deep QK^T pipeline, defer-max T13, 2-deep PV pipeline, setprio.)
// ---------------------------------------------------------------------------
__global__ __launch_bounds__(256) void flash_attn(
    const unsigned short* __restrict__ qkv, const unsigned short* __restrict__ vT,
    unsigned short* __restrict__ yout) {
  __shared__ __align__(16) unsigned short sK[2][64 * 128];    // [t_k][d], swizzle &15
  __shared__ __align__(16) unsigned short sVT[2][128 * 64];   // [d][t_k], swizzle &7
  __shared__ __align__(16) unsigned short sP[4 * 16 * 64];    // per-wave P[q][k], chunk swizzle &7

  const int tid = threadIdx.x, w = tid >> 6, lane = tid & 63;
  const int quad = lane >> 4, l16 = lane & 15;
  const int id = blockIdx.x;
  const int g = id & 31;           // (b,h) group -> XCD g%8
  const int qp = id >> 5;          // 0..15
  const int b = g >> 4, h = g & 15;
  const int T = 2048, CC = 6144, HD = 128;
  const float qscale = 0.12753257252f;  // (1/sqrt(128)) * log2(e)

  const unsigned short* gK = qkv + (size_t)(b * T) * CC + 2048 + h * HD;
  const unsigned short* gV = vT + (size_t)(b * 16 + h) * HD * T;
  unsigned short* pw = sP + w * 16 * 64;

  const unsigned short* kSrc[4];
  const unsigned short* vSrc[4];
  unsigned short* kDst[4];
  unsigned short* vDst[4];
#pragma unroll
  for (int i = 0; i < 4; i++) {
    int c = w * 256 + i * 64 + lane;
    int kR = c >> 4, kC = (c & 15) ^ (kR & 15);
    int vR = c >> 3, vC = (c & 7) ^ (vR & 7);
    kSrc[i] = gK + (size_t)kR * CC + kC * 8;
    vSrc[i] = gV + (size_t)vR * T + vC * 8;
    kDst[i] = (unsigned short*)sK + (size_t)(w * 256 + i * 64) * 8;
    vDst[i] = (unsigned short*)sVT + (size_t)(w * 256 + i * 64) * 8;
  }
  const int KBUF = 64 * 128, VBUF = 128 * 64;

  const int qtA = qp, qtB = 31 - qp;
  int qt = qtA, kt = 0;

  bf16x8 qf[4];
  float m_old, l_sum;
  f32x4 o[8] = {};
  {
    const size_t qrow = (size_t)(b * T + qt * 64 + w * 16 + l16) * CC + h * HD;
#pragma unroll
    for (int kb = 0; kb < 4; kb++) {
      bf16x8 raw = *(const bf16x8*)&qkv[qrow + kb * 32 + quad * 8];
      bf16x8 sc;
#pragma unroll
      for (int j = 0; j < 8; j++) sc[j] = (__bf16)((float)raw[j] * qscale);
      qf[kb] = sc;
    }
  }
  m_old = -1e30f; l_sum = 0.f;

#pragma unroll
  for (int i = 0; i < 4; i++) {
    gld16(kDst[i], kSrc[i]);
    gld16(vDst[i], vSrc[i]);
  }

  const int total = qtA + qtB + 2;   // = 33
  for (int it = 0; it < total; ++it) {
    __syncthreads();                 // buf[it&1] staged (vmcnt drained here)
    const int cur = it & 1;
    const bool segEnd = (kt == qt);

    // prefetch next tile into the other buffer (overlapped)
    if (it + 1 < total) {
      const int nkt = segEnd ? 0 : kt + 1;
      const int nb_ = (it + 1) & 1;
      const size_t kOff = (size_t)nkt * 64 * CC;
      const int vOff = nkt * 64;
#pragma unroll
      for (int i = 0; i < 4; i++) {
        gld16(kDst[i] + (size_t)nb_ * KBUF, kSrc[i] + kOff);
        gld16(vDst[i] + (size_t)nb_ * VBUF, vSrc[i] + vOff);
      }
    }

    const unsigned short* sKc = (const unsigned short*)sK + (size_t)cur * KBUF;
    const unsigned short* sVc = (const unsigned short*)sVT + (size_t)cur * VBUF;

    // S^T = K Q^T, 2-deep lgkm-pipelined over dc (K-frag column blocks)
    f32x4 s4[4] = {};
    bf16x8 kf[4], kg[4];
#pragma unroll
    for (int kb = 0; kb < 4; kb++) {
      int rr = kb * 16 + l16;
      int cc = quad ^ l16;   // dc = 0
      kf[kb] = ds_read16(lds_addr(&sKc[rr * 128 + cc * 8]));
    }
#pragma unroll
    for (int dc = 0; dc < 4; dc++) {
      if (dc < 3) {
#pragma unroll
        for (int kb = 0; kb < 4; kb++) {
          int rr = kb * 16 + l16;
          int cc = ((dc + 1) * 4 + quad) ^ l16;
          kg[kb] = ds_read16(lds_addr(&sKc[rr * 128 + cc * 8]));
        }
        WAIT_LGKM4;
      } else {
        WAIT_LGKM0;
      }
      SCHED0;
      __builtin_amdgcn_s_setprio(1);
#pragma unroll
      for (int kb = 0; kb < 4; kb++)
        s4[kb] = __builtin_amdgcn_mfma_f32_16x16x32_bf16(kf[kb], qf[dc], s4[kb], 0, 0, 0);
      __builtin_amdgcn_s_setprio(0);
      if (dc < 3) {
#pragma unroll
        for (int kb = 0; kb < 4; kb++) kf[kb] = kg[kb];
      }
    }

    // causal mask (diagonal tile only): k_local > q_local
    float sv[4][4];
#pragma unroll
    for (int kb = 0; kb < 4; kb++)
#pragma unroll
      for (int r = 0; r < 4; r++) {
        float v = s4[kb][r];
        if (segEnd) {
          if (kb * 16 + quad * 4 + r > w * 16 + l16) v = -1e30f;
        }
        sv[kb][r] = v;
      }

    // online softmax with defer-max (T13): skip O-rescale when no growth > 8
    float mx = sv[0][0];
#pragma unroll
    for (int kb = 0; kb < 4; kb++)
#pragma unroll
      for (int r = 0; r < 4; r++) mx = fmaxf(mx, sv[kb][r]);
    mx = fmaxf(mx, __shfl_xor(mx, 16));
    mx = fmaxf(mx, __shfl_xor(mx, 32));
    float m_new = fmaxf(m_old, mx);
    const bool nogrow = (__all(mx <= m_old + 8.0f) != 0);
    if (nogrow) m_new = m_old;
    float ssum = 0.f;
#pragma unroll
    for (int kb = 0; kb < 4; kb++)
#pragma unroll
      for (int r = 0; r < 4; r++) {
        float p = exp2f(sv[kb][r] - m_new);
        sv[kb][r] = p;
        ssum += p;
      }
    ssum += __shfl_xor(ssum, 16);
    ssum += __shfl_xor(ssum, 32);
    if (nogrow) {
      l_sum += ssum;
    } else {
      float a = exp2f(m_old - m_new);
      float ar[4];
#pragma unroll
      for (int r = 0; r < 4; r++)
        ar[r] = __shfl(a, (lane & 48) + quad * 4 + r);
#pragma unroll
      for (int nb = 0; nb < 8; nb++)
#pragma unroll
        for (int r = 0; r < 4; r++) o[nb][r] *= ar[r];
      l_sum = l_sum * a + ssum;
    }
    m_old = m_new;

    // P store: 4x ds_write_b64 (asm) into per-wave P[q][k]
#pragma unroll
    for (int kb = 0; kb < 4; kb++) {
      u16x4 pk;
#pragma unroll
      for (int r = 0; r < 4; r++) pk[r] = f2bf(sv[kb][r]);
      int c = kb * 2 + (quad >> 1);
      int cp = c ^ (l16 & 7);
      ds_write8(lds_addr(&pw[l16 * 64 + cp * 8 + (quad & 1) * 4]), pk);
    }
    WAIT_LGKM0;   // P writes complete (per-wave region; no barrier needed)
    SCHED0;

    // O += P V, 2-deep counted-lgkmcnt pipeline (DS retires in order)
    {
      const int x7 = l16 & 7;
      const int ccP0 = quad ^ x7, ccP1 = (4 + quad) ^ x7;
      bf16x8 pf0, pf1, vA[4], vB[4];
      pf0 = ds_read16(lds_addr(&pw[l16 * 64 + ccP0 * 8]));
#pragma unroll
      for (int j = 0; j < 4; j++) {
        int rr = j * 16 + l16;
        vA[j] = ds_read16(lds_addr(&sVc[rr * 64 + ccP0 * 8]));
      }
#pragma unroll
      for (int j = 0; j < 4; j++) {
        int rr = (4 + j) * 16 + l16;
        vB[j] = ds_read16(lds_addr(&sVc[rr * 64 + ccP0 * 8]));
      }
      WAIT_LGKM4; SCHED0;           // pf0+vA done; vB(4) in flight
      __builtin_amdgcn_s_setprio(1);
#pragma unroll
      for (int j = 0; j < 4; j++)
        o[j] = __builtin_amdgcn_mfma_f32_16x16x32_bf16(pf0, vA[j], o[j], 0, 0, 0);
      __builtin_amdgcn_s_setprio(0);
      pf1 = ds_read16(lds_addr(&pw[l16 * 64 + ccP1 * 8]));
#pragma unroll
      for (int j = 0; j < 4; j++) {
        int rr = j * 16 + l16;
        vA[j] = ds_read16(lds_addr(&sVc[rr * 64 + ccP1 * 8]));
      }
      WAIT_LGKM5; SCHED0;           // vB done; pf1+vA(5) in flight
      __builtin_amdgcn_s_setprio(1);
#pragma unroll
      for (int j = 0; j < 4; j++)
        o[4 + j] = __builtin_amdgcn_mfma_f32_16x16x32_bf16(pf0, vB[j], o[4 + j], 0, 0, 0);
      __builtin_amdgcn_s_setprio(0);
#pragma unroll
      for (int j = 0; j < 4; j++) {
        int rr = (4 + j) * 16 + l16;
        vB[j] = ds_read16(lds_addr(&sVc[rr * 64 + ccP1 * 8]));
      }
      WAIT_LGKM4; SCHED0;           // pf1+vA done; vB(4) in flight
      __builtin_amdgcn_s_setprio(1);
#pragma unroll
      for (int j = 0; j < 4; j++)
        o[j] = __builtin_amdgcn_mfma_f32_16x16x32_bf16(pf1, vA[j], o[j], 0, 0, 0);
      __builtin_amdgcn_s_setprio(0);
      WAIT_LGKM0; SCHED0;
      __builtin_amdgcn_s_setprio(1);
#pragma unroll
      for (int j = 0; j < 4; j++)
        o[4 + j] = __builtin_amdgcn_mfma_f32_16x16x32_bf16(pf1, vB[j], o[4 + j], 0, 0, 0);
      __builtin_amdgcn_s_setprio(0);
    }

    if (segEnd) {
      // epilogue: inv l_sum broadcast like alpha; O rows q = quad*4+r
      float linv = 1.0f / l_sum;
#pragma unroll
      for (int r = 0; r < 4; r++) {
        float ir = __shfl(linv, (lane & 48) + quad * 4 + r);
        size_t orow = (size_t)(b * T + qt * 64 + w * 16 + quad * 4 + r) * 2048 + h * HD;
#pragma unroll
        for (int nb = 0; nb < 8; nb++)
          yout[orow + nb * 16 + l16] = f2bf(o[nb][r] * ir);
      }
      if (it + 1 < total) {
        qt = qtB;
        const size_t qrow = (size_t)(b * T + qt * 64 + w * 16 + l16) * CC + h * HD;
#pragma unroll
        for (int kb = 0; kb < 4; kb++) {
          bf16x8 raw = *(const bf16x8*)&qkv[qrow + kb * 32 + quad * 8];
          bf16x8 sc;
#pragma unroll
          for (int j = 0; j < 8; j++) sc[j] = (__bf16)((float)raw[j] * qscale);
          qf[kb] = sc;
        }
        m_old = -1e30f; l_sum = 0.f;
#pragma unroll
        for (int nb = 0; nb < 8; nb++) o[nb] = (f32x4){0.f, 0.f, 0.f, 0.f};
      }
      kt = 0;
    } else {
      kt++;
    }
  }
}

// ---------------------------------------------------------------------------
extern "C" void kernel_launch(void* const* d_in, const int* in_sizes, int n_in,
                              void* d_out, int out_size, void* d_ws, size_t ws_size,
                              hipStream_t stream) {
  const float* x      = (const float*)d_in[0];   // (2,2048,2048)
  const float* W_attn = (const float*)d_in[1];   // (2048,6144)
  const float* b_attn = (const float*)d_in[2];   // (6144,)
  const float* W_proj = (const float*)d_in[3];   // (2048,2048)
  const float* b_proj = (const float*)d_in[4];   // (2048,)
  float* out = (float*)d_out;                    // (2,2048,2048) fp32

  char* ws = (char*)d_ws;
  unsigned short* x_bf  = (unsigned short*)(ws);              // 16 MiB
  unsigned short* WaT   = (unsigned short*)(ws + 16777216);   // 24 MiB
  unsigned short* WpT   = (unsigned short*)(ws + 41943040);   // 8 MiB
  unsigned short* qkv   = (unsigned short*)(ws + 50331648);   // 48 MiB
  unsigned short* vT    = (unsigned short*)(ws + 100663296);  // 16 MiB
  unsigned short* y_att = (unsigned short*)(ws + 117440512);  // 16 MiB
  // total 128 MiB

  // fused preprocessing: cvt + both weight transposes in one launch
  prep_k<<<5120, 256, 0, stream>>>(x, W_attn, W_proj, x_bf, WaT, WpT);
  // QKV GEMM: 256^2 8-phase, grid 24x16 = 384 WGs
  gemm_bt8<1><<<dim3(24, 16), 512, 0, stream>>>(x_bf, WaT, b_attn, qkv, 4096, 6144, 2048);
  extract_vT_k<<<dim3(32, 2, 32), 256, 0, stream>>>(qkv, vT);
  flash_attn<<<dim3(512), 256, 0, stream>>>(qkv, vT, y_att);
  // proj GEMM: legacy 128^2, grid 16x32 = 512 WGs = 2/CU exact
  gemm_bt<0><<<dim3(16, 32), 256, 0, stream>>>(y_att, WpT, b_proj, out, 4096, 2048, 2048);
}

// Round 7
// 369.759 us; speedup vs baseline: 1.1437x; 1.0004x over previous
//
#include <hip/hip_runtime.h>
#include <cstdint>
#include <cstddef>

// ---------------------------------------------------------------------------
// CausalSelfAttention: y = proj(softmax_causal(QK^T/sqrt(HD)) V), QKV = x@W_attn+b
// B=2 T=2048 C=2048 H=16 HD=128. All I/O fp32; internal compute bf16 MFMA.
// ---------------------------------------------------------------------------

typedef __bf16 bf16x8 __attribute__((ext_vector_type(8)));
typedef float  f32x4  __attribute__((ext_vector_type(4)));
typedef unsigned short u16x4 __attribute__((ext_vector_type(4)));
typedef unsigned short u16x8 __attribute__((ext_vector_type(8)));

__device__ __forceinline__ unsigned short f2bf(float f) {
  unsigned int u = __builtin_bit_cast(unsigned int, f);
  u += 0x7fffu + ((u >> 16) & 1u);       // round-to-nearest-even
  return (unsigned short)(u >> 16);
}

__device__ __forceinline__ void gld16(void* lds, const void* g) {
  // async global->LDS, 16B per lane; LDS dest is wave-uniform base + lane*16
  __builtin_amdgcn_global_load_lds(
      (const __attribute__((address_space(1))) void*)g,
      (__attribute__((address_space(3))) void*)lds, 16, 0, 0);
}

// 32-bit LDS byte address from a generic __shared__ pointer
__device__ __forceinline__ unsigned lds_addr(const void* p) {
  return (unsigned)(size_t)(const __attribute__((address_space(3))) void*)p;
}

// inline-asm ds_read_b128: opaque to SIInsertWaitcnts, so no compiler-inserted
// vmcnt drain vs outstanding global_load_lds. Caller MUST pair with manual
// s_waitcnt lgkmcnt(N) + sched_barrier(0) before consuming (rule #18).
__device__ __forceinline__ bf16x8 ds_read16(unsigned addr) {
  bf16x8 r;
  asm volatile("ds_read_b128 %0, %1" : "=v"(r) : "v"(addr));
  return r;
}

// inline-asm ds_write_b64 (same rationale)
__device__ __forceinline__ void ds_write8(unsigned addr, u16x4 d) {
  unsigned long long v = __builtin_bit_cast(unsigned long long, d);
  asm volatile("ds_write_b64 %0, %1" :: "v"(addr), "v"(v));
}

// ---------------------------------------------------------------------------
// Shared sync/wait macros
// ---------------------------------------------------------------------------
#define BARRIER8 __builtin_amdgcn_s_barrier()
#define WAIT_LGKM0 asm volatile("s_waitcnt lgkmcnt(0)" ::: "memory")
#define WAIT_LGKM4 asm volatile("s_waitcnt lgkmcnt(4)" ::: "memory")
#define WAIT_LGKM5 asm volatile("s_waitcnt lgkmcnt(5)" ::: "memory")
#define WAIT_LGKM8 asm volatile("s_waitcnt lgkmcnt(8)" ::: "memory")
#define SCHED0 __builtin_amdgcn_sched_barrier(0)
#define WAIT_VM4 asm volatile("s_waitcnt vmcnt(4)" ::: "memory")
#define WAIT_VM8 asm volatile("s_waitcnt vmcnt(8)" ::: "memory")
#define WAIT_VM0 asm volatile("s_waitcnt vmcnt(0)" ::: "memory")

// ---------------------------------------------------------------------------
// Fused preprocessing: one launch replaces {cvt_f32_bf16, transpose(W_attn),
// transpose(W_proj)}. Block ranges: [0,3072) trA, [3072,4096) trP, [4096,5120) cvt.
// ---------------------------------------------------------------------------
__device__ __forceinline__ void transpose_tile_64(
    const float* __restrict__ in, unsigned short* __restrict__ out,
    int R, int C, int c0, int r0, int t, float tile[64][65]) {
  int lr = t >> 4, lc = (t & 15) * 4;
#pragma unroll
  for (int i = 0; i < 4; i++) {
    int row = lr + i * 16;
    float4 v = *(const float4*)&in[(size_t)(r0 + row) * C + c0 + lc];
    tile[row][lc] = v.x; tile[row][lc + 1] = v.y;
    tile[row][lc + 2] = v.z; tile[row][lc + 3] = v.w;
  }
  __syncthreads();
  int wr = t >> 3, wc = (t & 7) * 8;
#pragma unroll
  for (int i = 0; i < 2; i++) {
    int crow = wr + i * 32;
    u16x8 o;
#pragma unroll
    for (int j = 0; j < 8; j++) o[j] = f2bf(tile[wc + j][crow]);
    *(u16x8*)&out[(size_t)(c0 + crow) * R + r0 + wc] = o;
  }
}

__global__ __launch_bounds__(256) void prep_k(
    const float* __restrict__ x, const float* __restrict__ W_attn,
    const float* __restrict__ W_proj, unsigned short* __restrict__ x_bf,
    unsigned short* __restrict__ WaT, unsigned short* __restrict__ WpT) {
  __shared__ float tile[64][65];
  const int bid = blockIdx.x, t = threadIdx.x;
  if (bid < 3072) {
    int bx = bid % 96, by = bid / 96;
    transpose_tile_64(W_attn, WaT, 2048, 6144, bx * 64, by * 64, t, tile);
  } else if (bid < 4096) {
    int id = bid - 3072, bx = id & 31, by = id >> 5;
    transpose_tile_64(W_proj, WpT, 2048, 2048, bx * 64, by * 64, t, tile);
  } else {
    const int n4 = 8388608 / 4;
    int i = (bid - 4096) * 256 + t;
    for (; i < n4; i += 1024 * 256) {
      float4 v = ((const float4*)x)[i];
      ushort4 o;
      o.x = f2bf(v.x); o.y = f2bf(v.y); o.z = f2bf(v.z); o.w = f2bf(v.w);
      ((ushort4*)x_bf)[i] = o;
    }
  }
}

// ---------------------------------------------------------------------------
// GEMM 256x256 8-phase (QKV). BK=64, 8 waves (2Mx4N), 512 threads, 128 KiB LDS.
// asm ds_read + deep staging lead + counted vmcnt(4) at ph3/ph7.
// R7: V-region output tiles (n0 >= 4096) write DIRECTLY into vT[(b,h,d),t]
// (4 consecutive acc rows = 4 consecutive t = one aligned u16x4 store) --
// replaces the separate extract_vT kernel (32 MB traffic + a launch).
// ---------------------------------------------------------------------------
#define STAGE_A(buf, h, t)                                                   \
  do {                                                                       \
    gld16(&sA[buf][((h) * 1024 + w * 64) * 8],                               \
          gA0 + (size_t)(h) * 128 * K + (size_t)(t) * 64);                   \
    gld16(&sA[buf][((h) * 1024 + 512 + w * 64) * 8],                         \
          gA1 + (size_t)(h) * 128 * K + (size_t)(t) * 64);                   \
  } while (0)

#define STAGE_B(buf, h, t)                                                   \
  do {                                                                       \
    gld16(&sB[buf][((h) * 1024 + w * 64) * 8],                               \
          gB0 + (size_t)(h) * 128 * K + (size_t)(t) * 64);                   \
    gld16(&sB[buf][((h) * 1024 + 512 + w * 64) * 8],                         \
          gB1 + (size_t)(h) * 128 * K + (size_t)(t) * 64);                   \
  } while (0)

// A sub-tile for phase (mh, kk): rows mh*128 + wr*64 + [0,64) -> only half mh
#define LDA4(buf, mh, kk)                                                    \
  do {                                                                       \
    const int cc_ = ((kk) * 4 + quad) ^ (l16 & 7);                           \
    _Pragma("unroll") for (int i_ = 0; i_ < 4; ++i_) {                       \
      const int rr_ = (mh) * 128 + wr * 64 + i_ * 16 + l16;                  \
      a_[i_] = ds_read16(lds_addr(&sA[buf][rr_ * 64 + cc_ * 8]));            \
    }                                                                        \
  } while (0)

#define LDB4(buf, kk)                                                        \
  do {                                                                       \
    const int cc_ = ((kk) * 4 + quad) ^ (l16 & 7);                           \
    _Pragma("unroll") for (int i_ = 0; i_ < 4; ++i_) {                       \
      const int rr_ = wc * 64 + i_ * 16 + l16;                               \
      b_[i_] = ds_read16(lds_addr(&sB[buf][rr_ * 64 + cc_ * 8]));            \
    }                                                                        \
  } while (0)

#define MM16(mh)                                                             \
  do {                                                                       \
    __builtin_amdgcn_s_setprio(1);                                           \
    _Pragma("unroll") for (int i_ = 0; i_ < 4; ++i_)                         \
    _Pragma("unroll") for (int n_ = 0; n_ < 4; ++n_)                         \
        acc[(mh) * 4 + i_][n_] = __builtin_amdgcn_mfma_f32_16x16x32_bf16(    \
            a_[i_], b_[n_], acc[(mh) * 4 + i_][n_], 0, 0, 0);                \
    __builtin_amdgcn_s_setprio(0);                                           \
  } while (0)

template <int OUT_BF16>
__global__ __launch_bounds__(512, 2) void gemm_bt8(
    const unsigned short* __restrict__ A, const unsigned short* __restrict__ BT,
    const float* __restrict__ bias, void* __restrict__ Cout,
    unsigned short* __restrict__ vTout,
    int M, int N, int K) {
  __shared__ __align__(16) unsigned short sA[2][256 * 64];
  __shared__ __align__(16) unsigned short sB[2][256 * 64];
  (void)M;

  const int tid = threadIdx.x, w = tid >> 6, lane = tid & 63;
  const int quad = lane >> 4, l16 = lane & 15;
  const int wr = w >> 2, wc = w & 3;   // wave -> (2M x 4N) grid

  // bijective XCD-aware block swizzle (m204 variant)
  const int nwgx = gridDim.x;
  const int nwg = nwgx * gridDim.y;
  const int wg = blockIdx.y * nwgx + blockIdx.x;
  const int q8 = nwg >> 3, r8 = nwg & 7;
  const int xcd = wg & 7, loc = wg >> 3;
  const int swz =
      (xcd < r8 ? xcd * (q8 + 1) : r8 * (q8 + 1) + (xcd - r8) * q8) + loc;
  const int m0 = (swz / nwgx) * 256;
  const int n0 = (swz % nwgx) * 256;

  const int c0 = tid, c1 = tid + 512;
  const int r0c = c0 >> 3, s0c = (c0 & 7) ^ (r0c & 7);
  const int r1c = c1 >> 3, s1c = (c1 & 7) ^ (r1c & 7);
  const unsigned short* gA0 = A + (size_t)(m0 + r0c) * K + s0c * 8;
  const unsigned short* gA1 = A + (size_t)(m0 + r1c) * K + s1c * 8;
  const unsigned short* gB0 = BT + (size_t)(n0 + r0c) * K + s0c * 8;
  const unsigned short* gB1 = BT + (size_t)(n0 + r1c) * K + s1c * 8;

  f32x4 acc[8][4] = {};
  bf16x8 a_[4], b_[4];

  const int NT = K >> 6;   // K-tiles (BK=64); must be even
  const int NI = NT >> 1;  // iterations (2 tiles each)

  // prologue: tile0 full -> buf0; tile1 {B-lo,A-lo} -> buf1; confirm tile0.
  STAGE_B(0, 0, 0); STAGE_A(0, 0, 0);
  STAGE_B(0, 1, 0); STAGE_A(0, 1, 0);
  STAGE_B(1, 0, 1); STAGE_A(1, 0, 1);
  WAIT_VM4;
  BARRIER8;

  for (int i = 0; i < NI; ++i) {
    const int t1 = 2 * i + 1;
    const int tn0 = 2 * i + 2, tn1 = 2 * i + 3;
    const bool last = (i == NI - 1);

    // ph0: buf0 (mh0,kk0) | stage t1 B-hi,A-hi
    LDB4(0, 0); LDA4(0, 0, 0);
    STAGE_B(1, 1, t1); STAGE_A(1, 1, t1);
    BARRIER8; WAIT_LGKM0; SCHED0; MM16(0); BARRIER8;

    // ph1: buf0 (mh1,kk0)
    LDA4(0, 1, 0);
    BARRIER8; WAIT_LGKM0; SCHED0; MM16(1); BARRIER8;

    // ph2: buf0 (mh0,kk1)
    LDB4(0, 1); LDA4(0, 0, 1);
    BARRIER8; WAIT_LGKM0; SCHED0; MM16(0); BARRIER8;

    // ph3: buf0 (mh1,kk1) | stage tn0 B-lo,A-lo | confirm buf1 (t1)
    LDA4(0, 1, 1);
    if (!last) {
      STAGE_B(0, 0, tn0); STAGE_A(0, 0, tn0);
      WAIT_VM4;
    } else {
      WAIT_VM0;
    }
    BARRIER8; WAIT_LGKM0; SCHED0; MM16(1); BARRIER8;

    // ph4: buf1 (mh0,kk0) | stage tn0 B-hi,A-hi
    LDB4(1, 0); LDA4(1, 0, 0);
    if (!last) { STAGE_B(0, 1, tn0); STAGE_A(0, 1, tn0); }
    BARRIER8; WAIT_LGKM0; SCHED0; MM16(0); BARRIER8;

    // ph5: buf1 (mh1,kk0)
    LDA4(1, 1, 0);
    BARRIER8; WAIT_LGKM0; SCHED0; MM16(1); BARRIER8;

    // ph6: buf1 (mh0,kk1)
    LDB4(1, 1); LDA4(1, 0, 1);
    BARRIER8; WAIT_LGKM0; SCHED0; MM16(0); BARRIER8;

    // ph7: buf1 (mh1,kk1) | stage tn1 B-lo,A-lo | confirm buf0 (tn0)
    LDA4(1, 1, 1);
    if (!last) {
      STAGE_B(1, 0, tn1); STAGE_A(1, 0, tn1);
      WAIT_VM4;
    }
    BARRIER8; WAIT_LGKM0; SCHED0; MM16(1); BARRIER8;
  }

  // epilogue: C/D layout row = quad*4+reg, col = l16; A-half mh at +mh*128
  if (OUT_BF16 && n0 >= 4096) {
    // V region -> vT[(b*16+h)*128 + d][t]; vcol = col-4096 = h*128+d;
    // 4 consecutive rows (t) = one aligned u16x4 store.
#pragma unroll
    for (int mi = 0; mi < 8; ++mi) {
      const int mh = mi >> 2, i2 = mi & 3;
      const int grow = m0 + mh * 128 + wr * 64 + i2 * 16 + quad * 4;
      const int bb = grow >> 11, tt = grow & 2047;
      unsigned short* vbase = vTout + (size_t)bb * 2048 * 2048 + tt;
#pragma unroll
      for (int ni = 0; ni < 4; ++ni) {
        const int col = n0 + wc * 64 + ni * 16 + l16;
        const float bv = bias[col];
        const int vcol = col - 4096;
        u16x4 pk;
#pragma unroll
        for (int rr = 0; rr < 4; ++rr) pk[rr] = f2bf(acc[mi][ni][rr] + bv);
        *(u16x4*)&vbase[(size_t)vcol * 2048] = pk;
      }
    }
  } else {
#pragma unroll
    for (int mi = 0; mi < 8; ++mi) {
      const int mh = mi >> 2, i2 = mi & 3;
      int row = m0 + mh * 128 + wr * 64 + i2 * 16 + quad * 4;
#pragma unroll
      for (int ni = 0; ni < 4; ++ni) {
        int col = n0 + wc * 64 + ni * 16 + l16;
        float bv = bias[col];
#pragma unroll
        for (int rr = 0; rr < 4; ++rr) {
          float v = acc[mi][ni][rr] + bv;
          if (OUT_BF16)
            ((unsigned short*)Cout)[(size_t)(row + rr) * N + col] = f2bf(v);
          else
            ((float*)Cout)[(size_t)(row + rr) * N + col] = v;
        }
      }
    }
  }
}

#undef STAGE_A
#undef STAGE_B
#undef LDA4
#undef LDB4
#undef MM16

// ---------------------------------------------------------------------------
// GEMM 128x128 double-buffered (proj). BK=64, 4 waves, 64 KiB LDS.
// R7: legacy m97 structure upgraded with the R3 asm-ds_read trick:
//  - all 16 fragment ds_reads issued at iteration top (asm, no compiler drains)
//  - lgkmcnt(8) -> 16 MFMA (kk0); lgkmcnt(0) + BARRIER (architectural WAR:
//    every wave's reads complete) -> stage t+2 into the now-dead buffer
//  - 16 MFMA (kk1); vmcnt(8) confirms t+1's loads issued a FULL ITERATION
//    (~800cyc) earlier -- never a just-issued load; BARRIER.
// 2 barriers/K-tile (vs legacy's 2 + per-tile vmcnt(0) drain of fresh loads).
// ---------------------------------------------------------------------------
template <int OUT_BF16>
__global__ __launch_bounds__(256) void gemm_db(
    const unsigned short* __restrict__ A, const unsigned short* __restrict__ BT,
    const float* __restrict__ bias, void* __restrict__ Cout,
    int M, int N, int K) {
  __shared__ __align__(16) unsigned short sA[2][128 * 64];
  __shared__ __align__(16) unsigned short sB[2][128 * 64];

  const int tid = threadIdx.x, w = tid >> 6, lane = tid & 63;
  const int quad = lane >> 4, l16 = lane & 15;
  const int m0 = blockIdx.y * 128, n0 = blockIdx.x * 128;
  const int wr = w >> 1, wc = w & 1;

  const unsigned short* gA[4];
  const unsigned short* gB[4];
  unsigned aOff[4];
#pragma unroll
  for (int i = 0; i < 4; i++) {
    int c = w * 256 + i * 64 + lane;
    int row = c >> 3, scol = (c & 7) ^ (row & 7);
    gA[i] = A + (size_t)(m0 + row) * K + scol * 8;
    gB[i] = BT + (size_t)(n0 + row) * K + scol * 8;
    aOff[i] = (unsigned)((w * 256 + i * 64) * 8);
  }

  f32x4 acc[4][4] = {};
  const int NT = K >> 6;   // 32

  // prologue: t0 -> buf0, t1 -> buf1; confirm t0 (leave t1's 8 in flight).
#pragma unroll
  for (int i = 0; i < 4; i++) { gld16(&sA[0][aOff[i]], gA[i]); gld16(&sB[0][aOff[i]], gB[i]); }
#pragma unroll
  for (int i = 0; i < 4; i++) { gld16(&sA[1][aOff[i]], gA[i] + 64); gld16(&sB[1][aOff[i]], gB[i] + 64); }
  WAIT_VM8;
  BARRIER8;

  bf16x8 a0_[4], b0_[4], a1_[4], b1_[4];
  for (int t = 0; t < NT; ++t) {
    const int c = t & 1;
    const int cc0 = quad ^ (l16 & 7);
    const int cc1 = (4 + quad) ^ (l16 & 7);
    // issue all 16 fragment reads (kk0 first 8, kk1 next 8; DS retires in order)
#pragma unroll
    for (int i = 0; i < 4; i++)
      b0_[i] = ds_read16(lds_addr(&sB[c][(wc * 64 + i * 16 + l16) * 64 + cc0 * 8]));
#pragma unroll
    for (int i = 0; i < 4; i++)
      a0_[i] = ds_read16(lds_addr(&sA[c][(wr * 64 + i * 16 + l16) * 64 + cc0 * 8]));
#pragma unroll
    for (int i = 0; i < 4; i++)
      b1_[i] = ds_read16(lds_addr(&sB[c][(wc * 64 + i * 16 + l16) * 64 + cc1 * 8]));
#pragma unroll
    for (int i = 0; i < 4; i++)
      a1_[i] = ds_read16(lds_addr(&sA[c][(wr * 64 + i * 16 + l16) * 64 + cc1 * 8]));

    WAIT_LGKM8; SCHED0;
    __builtin_amdgcn_s_setprio(1);
#pragma unroll
    for (int mi = 0; mi < 4; mi++)
#pragma unroll
      for (int ni = 0; ni < 4; ni++)
        acc[mi][ni] = __builtin_amdgcn_mfma_f32_16x16x32_bf16(
            a0_[mi], b0_[ni], acc[mi][ni], 0, 0, 0);
    __builtin_amdgcn_s_setprio(0);

    WAIT_LGKM0; SCHED0;
    BARRIER8;   // all waves' 16 reads of buf c complete -> buf c dead

    if (t + 2 < NT) {
#pragma unroll
      for (int i = 0; i < 4; i++) {
        gld16(&sA[c][aOff[i]], gA[i] + (size_t)(t + 2) * 64);
        gld16(&sB[c][aOff[i]], gB[i] + (size_t)(t + 2) * 64);
      }
    }

    __builtin_amdgcn_s_setprio(1);
#pragma unroll
    for (int mi = 0; mi < 4; mi++)
#pragma unroll
      for (int ni = 0; ni < 4; ni++)
        acc[mi][ni] = __builtin_amdgcn_mfma_f32_16x16x32_bf16(
            a1_[mi], b1_[ni], acc[mi][ni], 0, 0, 0);
    __builtin_amdgcn_s_setprio(0);

    if (t + 2 < NT) {
      WAIT_VM8;            // confirm t+1 (issued last iteration); t+2 stays in flight
    } else if (t + 1 < NT) {
      WAIT_VM0;            // last prefetched tile
    }
    BARRIER8;
  }

  // epilogue: C/D layout row = quad*4+reg, col = l16
#pragma unroll
  for (int mi = 0; mi < 4; mi++) {
    int row = m0 + wr * 64 + mi * 16 + quad * 4;
#pragma unroll
    for (int ni = 0; ni < 4; ni++) {
      int col = n0 + wc * 64 + ni * 16 + l16;
      float bv = bias[col];
#pragma unroll
      for (int r = 0; r < 4; r++) {
        float v = acc[mi][ni][r] + bv;
        if (OUT_BF16)
          ((unsigned short*)Cout)[(size_t)(row + r) * N + col] = f2bf(v);
        else
          ((float*)Cout)[(size_t)(row + r) * N + col] = v;
      }
    }
  }
}

// ---------------------------------------------------------------------------
// Flash attention (causal), S^T formulation. (unchanged from R5/R6.)
// ---------------------------------------------------------------------------
__global__ __launch_bounds__(256) void flash_attn(
    const unsigned short* __restrict__ qkv, const unsigned short* __restrict__ vT,
    unsigned short* __restrict__ yout) {
  __shared__ __align__(16) unsigned short sK[2][64 * 128];    // [t_k][d], swizzle &15
  __shared__ __align__(16) unsigned short sVT[2][128 * 64];   // [d][t_k], swizzle &7
  __shared__ __align__(16) unsigned short sP[4 * 16 * 64];    // per-wave P[q][k], chunk swizzle &7

  const int tid = threadIdx.x, w = tid >> 6, lane = tid & 63;
  const int quad = lane >> 4, l16 = lane & 15;
  const int id = blockIdx.x;
  const int g = id & 31;           // (b,h) group -> XCD g%8
  const int qp = id >> 5;          // 0..15
  const int b = g >> 4, h = g & 15;
  const int T = 2048, CC = 6144, HD = 128;
  const float qscale = 0.12753257252f;  // (1/sqrt(128)) * log2(e)

  const unsigned short* gK = qkv + (size_t)(b * T) * CC + 2048 + h * HD;
  const unsigned short* gV = vT + (size_t)(b * 16 + h) * HD * T;
  unsigned short* pw = sP + w * 16 * 64;

  const unsigned short* kSrc[4];
  const unsigned short* vSrc[4];
  unsigned short* kDst[4];
  unsigned short* vDst[4];
#pragma unroll
  for (int i = 0; i < 4; i++) {
    int c = w * 256 + i * 64 + lane;
    int kR = c >> 4, kC = (c & 15) ^ (kR & 15);
    int vR = c >> 3, vC = (c & 7) ^ (vR & 7);
    kSrc[i] = gK + (size_t)kR * CC + kC * 8;
    vSrc[i] = gV + (size_t)vR * T + vC * 8;
    kDst[i] = (unsigned short*)sK + (size_t)(w * 256 + i * 64) * 8;
    vDst[i] = (unsigned short*)sVT + (size_t)(w * 256 + i * 64) * 8;
  }
  const int KBUF = 64 * 128, VBUF = 128 * 64;

  const int qtA = qp, qtB = 31 - qp;
  int qt = qtA, kt = 0;

  bf16x8 qf[4];
  float m_old, l_sum;
  f32x4 o[8] = {};
  {
    const size_t qrow = (size_t)(b * T + qt * 64 + w * 16 + l16) * CC + h * HD;
#pragma unroll
    for (int kb = 0; kb < 4; kb++) {
      bf16x8 raw = *(const bf16x8*)&qkv[qrow + kb * 32 + quad * 8];
      bf16x8 sc;
#pragma unroll
      for (int j = 0; j < 8; j++) sc[j] = (__bf16)((float)raw[j] * qscale);
      qf[kb] = sc;
    }
  }
  m_old = -1e30f; l_sum = 0.f;

#pragma unroll
  for (int i = 0; i < 4; i++) {
    gld16(kDst[i], kSrc[i]);
    gld16(vDst[i], vSrc[i]);
  }

  const int total = qtA + qtB + 2;   // = 33
  for (int it = 0; it < total; ++it) {
    __syncthreads();                 // buf[it&1] staged (vmcnt drained here)
    const int cur = it & 1;
    const bool segEnd = (kt == qt);

    // prefetch next tile into the other buffer (overlapped)
    if (it + 1 < total) {
      const int nkt = segEnd ? 0 : kt + 1;
      const int nb_ = (it + 1) & 1;
      const size_t kOff = (size_t)nkt * 64 * CC;
      const int vOff = nkt * 64;
#pragma unroll
      for (int i = 0; i < 4; i++) {
        gld16(kDst[i] + (size_t)nb_ * KBUF, kSrc[i] + kOff);
        gld16(vDst[i] + (size_t)nb_ * VBUF, vSrc[i] + vOff);
      }
    }

    const unsigned short* sKc = (const unsigned short*)sK + (size_t)cur * KBUF;
    const unsigned short* sVc = (const unsigned short*)sVT + (size_t)cur * VBUF;

    // S^T = K Q^T, 2-deep lgkm-pipelined over dc (K-frag column blocks)
    f32x4 s4[4] = {};
    bf16x8 kf[4], kg[4];
#pragma unroll
    for (int kb = 0; kb < 4; kb++) {
      int rr = kb * 16 + l16;
      int cc = quad ^ l16;   // dc = 0
      kf[kb] = ds_read16(lds_addr(&sKc[rr * 128 + cc * 8]));
    }
#pragma unroll
    for (int dc = 0; dc < 4; dc++) {
      if (dc < 3) {
#pragma unroll
        for (int kb = 0; kb < 4; kb++) {
          int rr = kb * 16 + l16;
          int cc = ((dc + 1) * 4 + quad) ^ l16;
          kg[kb] = ds_read16(lds_addr(&sKc[rr * 128 + cc * 8]));
        }
        WAIT_LGKM4;
      } else {
        WAIT_LGKM0;
      }
      SCHED0;
      __builtin_amdgcn_s_setprio(1);
#pragma unroll
      for (int kb = 0; kb < 4; kb++)
        s4[kb] = __builtin_amdgcn_mfma_f32_16x16x32_bf16(kf[kb], qf[dc], s4[kb], 0, 0, 0);
      __builtin_amdgcn_s_setprio(0);
      if (dc < 3) {
#pragma unroll
        for (int kb = 0; kb < 4; kb++) kf[kb] = kg[kb];
      }
    }

    // causal mask (diagonal tile only): k_local > q_local
    float sv[4][4];
#pragma unroll
    for (int kb = 0; kb < 4; kb++)
#pragma unroll
      for (int r = 0; r < 4; r++) {
        float v = s4[kb][r];
        if (segEnd) {
          if (kb * 16 + quad * 4 + r > w * 16 + l16) v = -1e30f;
        }
        sv[kb][r] = v;
      }

    // online softmax with defer-max (T13): skip O-rescale when no growth > 8
    float mx = sv[0][0];
#pragma unroll
    for (int kb = 0; kb < 4; kb++)
#pragma unroll
      for (int r = 0; r < 4; r++) mx = fmaxf(mx, sv[kb][r]);
    mx = fmaxf(mx, __shfl_xor(mx, 16));
    mx = fmaxf(mx, __shfl_xor(mx, 32));
    float m_new = fmaxf(m_old, mx);
    const bool nogrow = (__all(mx <= m_old + 8.0f) != 0);
    if (nogrow) m_new = m_old;
    float ssum = 0.f;
#pragma unroll
    for (int kb = 0; kb < 4; kb++)
#pragma unroll
      for (int r = 0; r < 4; r++) {
        float p = exp2f(sv[kb][r] - m_new);
        sv[kb][r] = p;
        ssum += p;
      }
    ssum += __shfl_xor(ssum, 16);
    ssum += __shfl_xor(ssum, 32);
    if (nogrow) {
      l_sum += ssum;
    } else {
      float a = exp2f(m_old - m_new);
      float ar[4];
#pragma unroll
      for (int r = 0; r < 4; r++)
        ar[r] = __shfl(a, (lane & 48) + quad * 4 + r);
#pragma unroll
      for (int nb = 0; nb < 8; nb++)
#pragma unroll
        for (int r = 0; r < 4; r++) o[nb][r] *= ar[r];
      l_sum = l_sum * a + ssum;
    }
    m_old = m_new;

    // P store: 4x ds_write_b64 (asm) into per-wave P[q][k]
#pragma unroll
    for (int kb = 0; kb < 4; kb++) {
      u16x4 pk;
#pragma unroll
      for (int r = 0; r < 4; r++) pk[r] = f2bf(sv[kb][r]);
      int c = kb * 2 + (quad >> 1);
      int cp = c ^ (l16 & 7);
      ds_write8(lds_addr(&pw[l16 * 64 + cp * 8 + (quad & 1) * 4]), pk);
    }
    WAIT_LGKM0;   // P writes complete (per-wave region; no barrier needed)
    SCHED0;

    // O += P V, 2-deep counted-lgkmcnt pipeline (DS retires in order)
    {
      const int x7 = l16 & 7;
      const int ccP0 = quad ^ x7, ccP1 = (4 + quad) ^ x7;
      bf16x8 pf0, pf1, vA[4], vB[4];
      pf0 = ds_read16(lds_addr(&pw[l16 * 64 + ccP0 * 8]));
#pragma unroll
      for (int j = 0; j < 4; j++) {
        int rr = j * 16 + l16;
        vA[j] = ds_read16(lds_addr(&sVc[rr * 64 + ccP0 * 8]));
      }
#pragma unroll
      for (int j = 0; j < 4; j++) {
        int rr = (4 + j) * 16 + l16;
        vB[j] = ds_read16(lds_addr(&sVc[rr * 64 + ccP0 * 8]));
      }
      WAIT_LGKM4; SCHED0;           // pf0+vA done; vB(4) in flight
      __builtin_amdgcn_s_setprio(1);
#pragma unroll
      for (int j = 0; j < 4; j++)
        o[j] = __builtin_amdgcn_mfma_f32_16x16x32_bf16(pf0, vA[j], o[j], 0, 0, 0);
      __builtin_amdgcn_s_setprio(0);
      pf1 = ds_read16(lds_addr(&pw[l16 * 64 + ccP1 * 8]));
#pragma unroll
      for (int j = 0; j < 4; j++) {
        int rr = j * 16 + l16;
        vA[j] = ds_read16(lds_addr(&sVc[rr * 64 + ccP1 * 8]));
      }
      WAIT_LGKM5; SCHED0;           // vB done; pf1+vA(5) in flight
      __builtin_amdgcn_s_setprio(1);
#pragma unroll
      for (int j = 0; j < 4; j++)
        o[4 + j] = __builtin_amdgcn_mfma_f32_16x16x32_bf16(pf0, vB[j], o[4 + j], 0, 0, 0);
      __builtin_amdgcn_s_setprio(0);
#pragma unroll
      for (int j = 0; j < 4; j++) {
        int rr = (4 + j) * 16 + l16;
        vB[j] = ds_read16(lds_addr(&sVc[rr * 64 + ccP1 * 8]));
      }
      WAIT_LGKM4; SCHED0;           // pf1+vA done; vB(4) in flight
      __builtin_amdgcn_s_setprio(1);
#pragma unroll
      for (int j = 0; j < 4; j++)
        o[j] = __builtin_amdgcn_mfma_f32_16x16x32_bf16(pf1, vA[j], o[j], 0, 0, 0);
      __builtin_amdgcn_s_setprio(0);
      WAIT_LGKM0; SCHED0;
      __builtin_amdgcn_s_setprio(1);
#pragma unroll
      for (int j = 0; j < 4; j++)
        o[4 + j] = __builtin_amdgcn_mfma_f32_16x16x32_bf16(pf1, vB[j], o[4 + j], 0, 0, 0);
      __builtin_amdgcn_s_setprio(0);
    }

    if (segEnd) {
      // epilogue: inv l_sum broadcast like alpha; O rows q = quad*4+r
      float linv = 1.0f / l_sum;
#pragma unroll
      for (int r = 0; r < 4; r++) {
        float ir = __shfl(linv, (lane & 48) + quad * 4 + r);
        size_t orow = (size_t)(b * T + qt * 64 + w * 16 + quad * 4 + r) * 2048 + h * HD;
#pragma unroll
        for (int nb = 0; nb < 8; nb++)
          yout[orow + nb * 16 + l16] = f2bf(o[nb][r] * ir);
      }
      if (it + 1 < total) {
        qt = qtB;
        const size_t qrow = (size_t)(b * T + qt * 64 + w * 16 + l16) * CC + h * HD;
#pragma unroll
        for (int kb = 0; kb < 4; kb++) {
          bf16x8 raw = *(const bf16x8*)&qkv[qrow + kb * 32 + quad * 8];
          bf16x8 sc;
#pragma unroll
          for (int j = 0; j < 8; j++) sc[j] = (__bf16)((float)raw[j] * qscale);
          qf[kb] = sc;
        }
        m_old = -1e30f; l_sum = 0.f;
#pragma unroll
        for (int nb = 0; nb < 8; nb++) o[nb] = (f32x4){0.f, 0.f, 0.f, 0.f};
      }
      kt = 0;
    } else {
      kt++;
    }
  }
}

// ---------------------------------------------------------------------------
extern "C" void kernel_launch(void* const* d_in, const int* in_sizes, int n_in,
                              void* d_out, int out_size, void* d_ws, size_t ws_size,
                              hipStream_t stream) {
  const float* x      = (const float*)d_in[0];   // (2,2048,2048)
  const float* W_attn = (const float*)d_in[1];   // (2048,6144)
  const float* b_attn = (const float*)d_in[2];   // (6144,)
  const float* W_proj = (const float*)d_in[3];   // (2048,2048)
  const float* b_proj = (const float*)d_in[4];   // (2048,)
  float* out = (float*)d_out;                    // (2,2048,2048) fp32

  char* ws = (char*)d_ws;
  unsigned short* x_bf  = (unsigned short*)(ws);              // 16 MiB
  unsigned short* WaT   = (unsigned short*)(ws + 16777216);   // 24 MiB
  unsigned short* WpT   = (unsigned short*)(ws + 41943040);   // 8 MiB
  unsigned short* qkv   = (unsigned short*)(ws + 50331648);   // 48 MiB (V region unused)
  unsigned short* vT    = (unsigned short*)(ws + 100663296);  // 16 MiB
  unsigned short* y_att = (unsigned short*)(ws + 117440512);  // 16 MiB
  // total 128 MiB

  // fused preprocessing: cvt + both weight transposes in one launch
  prep_k<<<5120, 256, 0, stream>>>(x, W_attn, W_proj, x_bf, WaT, WpT);
  // QKV GEMM: 256^2 8-phase, grid 24x16 = 384 WGs; V tiles write vT directly
  gemm_bt8<1><<<dim3(24, 16), 512, 0, stream>>>(x_bf, WaT, b_attn, qkv, vT, 4096, 6144, 2048);
  flash_attn<<<dim3(512), 256, 0, stream>>>(qkv, vT, y_att);
  // proj GEMM: 128^2 double-buffered, grid 16x32 = 512 WGs = 2/CU exact
  gemm_db<0><<<dim3(16, 32), 256, 0, stream>>>(y_att, WpT, b_proj, out, 4096, 2048, 2048);
}